// Round 7
// baseline (1677.505 us; speedup 1.0000x reference)
//
#include <hip/hip_runtime.h>
#include <math.h>

#define T_OBS 8
#define PRED_LEN 12
#define NSC 512
#define NPED 64
#define NTOT (NSC*NPED)
#define EPS 1e-5

// ---- ws double-region offsets (in doubles) ----
#define O_PWIH   25600    // pred wih [320][2]
#define O_PBD    26240    // pred bih+bhh+Cb [320]
#define O_PCW    26560    // Cw[r] [320]
#define O_PGW    26880    // gw0[80], gw1[80]
#define O_PSC    27040    // Cgw0, Cgw1, Cbw0+bout0, Cbw1+bout1
#define O_PINV   27048    // invg[80], b[80]
#define O_TWIH   27208    // traj wih [128][2]
#define O_TWHHT  27464    // traj whh^T [32 k][128 r]
#define O_TB     31560    // traj bih+bhh [128]
#define O_GWIHT  31688    // graph wih^T [32 k][128 r]
#define O_GW2    35784    // graph whh^T g-folded [32 k][128 r]
#define O_GBD    39880    // graph bih+bhh+gCb [128]
#define O_GCW    40008    // gCw[r] [128]
#define O_GLNG   40136
#define O_GLNB   40168
#define O_GINV   40200    // ginvg[32], gb[32]
#define O_W0     40264    // gat w0 [4][32][16]
#define O_A0S    42312
#define O_A0D    42376
#define O_B0     42440
#define O_W1     42456    // gat w1 [64][32]
#define O_A1S    44504
#define O_A1D    44536
#define O_B1     44568
#define D_TOTAL  44600
// float region (offsets in floats, from wsf = (float*)(wsd + D_TOTAL))
#define OF_PW2P  0        // pred whh^T g-folded fp32 PACKED [80 k][8 wv][40 j4]
#define F_TOTAL  25600

// ---------- fast fp64 math (validated bit-identical absmax R3-R6) ----------
__device__ __forceinline__ double fast_exp(double x){
  x = fmin(fmax(x, -708.0), 708.0);
  const double L2E  = 1.4426950408889634074;
  const double LN2H = 6.93147180369123816490e-01;
  const double LN2L = 1.90821492927058770002e-10;
  double t = x*L2E;
  double n = rint(t);
  int ni = (int)n;
  double r = __builtin_fma(-n, LN2H, x);
  r = __builtin_fma(-n, LN2L, r);
  double p = 2.08767569878681e-09;
  p = __builtin_fma(p, r, 2.505210838544172e-08);
  p = __builtin_fma(p, r, 2.755731922398589e-07);
  p = __builtin_fma(p, r, 2.755731922398589e-06);
  p = __builtin_fma(p, r, 2.480158730158730e-05);
  p = __builtin_fma(p, r, 1.984126984126984e-04);
  p = __builtin_fma(p, r, 1.388888888888889e-03);
  p = __builtin_fma(p, r, 8.333333333333333e-03);
  p = __builtin_fma(p, r, 4.166666666666667e-02);
  p = __builtin_fma(p, r, 1.666666666666667e-01);
  p = __builtin_fma(p, r, 0.5);
  p = __builtin_fma(p, r, 1.0);
  p = __builtin_fma(p, r, 1.0);
  double s = __hiloint2double((ni + 1023) << 20, 0);
  return p*s;
}
__device__ __forceinline__ double fast_rcp(double d){
#if __has_builtin(__builtin_amdgcn_rcp)
  double r = __builtin_amdgcn_rcp(d);
#else
  double r = 1.0/d;
#endif
  double e = __builtin_fma(-d, r, 1.0); r = __builtin_fma(r, e, r);
  e = __builtin_fma(-d, r, 1.0); r = __builtin_fma(r, e, r);
  e = __builtin_fma(-d, r, 1.0); r = __builtin_fma(r, e, r);
  return r;
}
__device__ __forceinline__ double fast_rsqrt(double d){
#if __has_builtin(__builtin_amdgcn_rsq)
  double r = __builtin_amdgcn_rsq(d);
#else
  double r = 1.0/sqrt(d);
#endif
  double hr = 0.5*d;
  r = r*__builtin_fma(-hr*r, r, 1.5);
  r = r*__builtin_fma(-hr*r, r, 1.5);
  r = r*__builtin_fma(-hr*r, r, 1.5);
  return r;
}
__device__ __forceinline__ double fsig(double x){
  double xc = fmin(fmax(x, -40.0), 40.0);
  return fast_rcp(1.0 + fast_exp(-xc));
}
__device__ __forceinline__ double ftanh(double x){
  double xc = fmin(fmax(x, -20.0), 20.0);
  return __builtin_fma(-2.0, fast_rcp(1.0 + fast_exp(2.0*xc)), 1.0);
}
// ---------- fp32 fast gates (k_pred only) ----------
__device__ __forceinline__ float fsig32(float x){
  x = fminf(fmaxf(x, -30.f), 30.f);
  return 1.0f/(1.0f + __expf(-x));
}
__device__ __forceinline__ float ftanh32(float x){
  x = fminf(fmaxf(x, -15.f), 15.f);
  return 1.0f - 2.0f/(1.0f + __expf(2.f*x));
}

// ---------------- prep ----------------
__global__ void k_prep(
    const float* __restrict__ pwhh, const float* __restrict__ pwih,
    const float* __restrict__ pbih, const float* __restrict__ pbhh,
    const float* __restrict__ plng, const float* __restrict__ plnb,
    const float* __restrict__ pwout, const float* __restrict__ pbout,
    const float* __restrict__ twih, const float* __restrict__ twhh,
    const float* __restrict__ tbih, const float* __restrict__ tbhh,
    const float* __restrict__ gwih, const float* __restrict__ gwhh,
    const float* __restrict__ gbih, const float* __restrict__ gbhh,
    const float* __restrict__ glng, const float* __restrict__ glnb,
    const float* __restrict__ w0, const float* __restrict__ a0s,
    const float* __restrict__ a0d, const float* __restrict__ b0,
    const float* __restrict__ w1, const float* __restrict__ a1s,
    const float* __restrict__ a1d, const float* __restrict__ b1,
    double* __restrict__ wsd, float* __restrict__ wsf)
{
  int i = blockIdx.x*256 + threadIdx.x;
  // pred packed fp32: w2p[(k*8+wv)*40 + j*4+g] = whh[g*80+wv*10+j][k] * g[k]
  if (i < 25600){
    int kk = i/320, rem = i - kk*320;
    int wv = rem/40, j4 = rem - wv*40;
    int j = j4>>2, g = j4&3;
    int r = g*80 + wv*10 + j;
    wsf[OF_PW2P + i] = (float)((double)pwhh[r*80 + kk] * (double)plng[kk]);
  }
  if (i < 640)  wsd[O_PWIH + i] = (double)pwih[i];
  if (i < 320){
    double s = 0, sb = 0;
    for (int k = 0; k < 80; ++k){
      double w = (double)pwhh[i*80 + k];
      s  += w*(double)plng[k];
      sb += w*(double)plnb[k];
    }
    wsd[O_PCW + i] = s;
    wsd[O_PBD + i] = (double)pbih[i] + (double)pbhh[i] + sb;
  }
  if (i < 160){
    if (i < 80) wsd[O_PGW + i] = (double)plng[i]*(double)pwout[i];
    else        wsd[O_PGW + i] = (double)plng[i-80]*(double)pwout[80 + (i-80)];
  }
  if (i < 4){
    double s = 0;
    if (i == 0){ for (int u = 0; u < 80; ++u) s += (double)plng[u]*(double)pwout[u]; }
    if (i == 1){ for (int u = 0; u < 80; ++u) s += (double)plng[u]*(double)pwout[80+u]; }
    if (i == 2){ for (int u = 0; u < 80; ++u) s += (double)plnb[u]*(double)pwout[u]; s += (double)pbout[0]; }
    if (i == 3){ for (int u = 0; u < 80; ++u) s += (double)plnb[u]*(double)pwout[80+u]; s += (double)pbout[1]; }
    wsd[O_PSC + i] = s;
  }
  if (i < 160){
    if (i < 80) wsd[O_PINV + i] = 1.0/(double)plng[i];
    else        wsd[O_PINV + i] = (double)plnb[i-80];
  }
  if (i < 256) wsd[O_TWIH + i] = (double)twih[i];
  if (i < 4096){
    int r = i>>5, k = i&31;
    wsd[O_TWHHT + k*128 + r] = (double)twhh[i];
    wsd[O_GWIHT + k*128 + r] = (double)gwih[i];
    wsd[O_GW2   + k*128 + r] = (double)gwhh[i]*(double)glng[k];
  }
  if (i < 128){
    wsd[O_TB + i] = (double)tbih[i] + (double)tbhh[i];
    double s = 0, sb = 0;
    for (int k = 0; k < 32; ++k){
      double w = (double)gwhh[i*32 + k];
      s  += w*(double)glng[k];
      sb += w*(double)glnb[k];
    }
    wsd[O_GCW + i] = s;
    wsd[O_GBD + i] = (double)gbih[i] + (double)gbhh[i] + sb;
  }
  if (i < 32){
    wsd[O_GLNG + i] = (double)glng[i]; wsd[O_GLNB + i] = (double)glnb[i];
    wsd[O_GINV + i] = 1.0/(double)glng[i];
    wsd[O_GINV + 32 + i] = (double)glnb[i];
    wsd[O_A1S + i] = (double)a1s[i]; wsd[O_A1D + i] = (double)a1d[i];
    wsd[O_B1 + i] = (double)b1[i];
  }
  if (i < 2048){ wsd[O_W0 + i] = (double)w0[i]; wsd[O_W1 + i] = (double)w1[i]; }
  if (i < 64){ wsd[O_A0S + i] = (double)a0s[i]; wsd[O_A0D + i] = (double)a0d[i]; }
  if (i < 16) wsd[O_B0 + i] = (double)b0[i];
}

// ---------------- K1: traj LSTM (unchanged from R6) ----------------
__global__ __launch_bounds__(256) void k_traj(
    const float* __restrict__ obs, const float* __restrict__ h0,
    const float* __restrict__ c0, const double* __restrict__ wsd,
    float* __restrict__ traj_hs)
{
  __shared__ double hdl[2][2048];
  const double* wih  = wsd + O_TWIH;
  const double* whhT = wsd + O_TWHHT;
  const double* bd   = wsd + O_TB;
  const int tid = threadIdx.x, lane = tid & 63;
  const int wv = __builtin_amdgcn_readfirstlane(tid >> 6);
  const int ub = wv*8;
  const int ped0 = blockIdx.x*64, ped = ped0 + lane;
  for (int idx = tid; idx < 2048; idx += 256){
    int f = idx>>6, p = idx&63;
    hdl[0][idx] = (double)h0[(ped0+p)*32 + f];
  }
  double c[8];
  #pragma unroll
  for (int j = 0; j < 8; ++j) c[j] = (double)c0[ped*32 + ub + j];
  __syncthreads();

  for (int t = 0; t < T_OBS; ++t){
    const int p = t & 1;
    double x0 = (double)obs[((size_t)t*NTOT + ped)*2 + 0];
    double x1 = (double)obs[((size_t)t*NTOT + ped)*2 + 1];
    double acc[32];
    #pragma unroll
    for (int j = 0; j < 8; ++j){
      #pragma unroll
      for (int g = 0; g < 4; ++g){
        int r = g*32 + ub + j;
        acc[j*4+g] = bd[r] + wih[r*2+0]*x0 + wih[r*2+1]*x1;
      }
    }
    for (int k = 0; k < 32; ++k){
      double hk = hdl[p][k*64 + lane];
      const double* wh = whhT + k*128;
      #pragma unroll
      for (int j = 0; j < 8; ++j){
        #pragma unroll
        for (int g = 0; g < 4; ++g) acc[j*4+g] += wh[g*32 + ub + j]*hk;
      }
    }
    #pragma unroll
    for (int j = 0; j < 8; ++j){
      double ig = fsig(acc[j*4+0]);
      double fg = fsig(acc[j*4+1]);
      double gg = ftanh(acc[j*4+2]);
      double og = fsig(acc[j*4+3]);
      c[j] = fg*c[j] + ig*gg;
      double hn = og*ftanh(c[j]);
      hdl[p^1][(ub+j)*64 + lane] = hn;
      traj_hs[((size_t)t*NTOT + ped)*32 + ub + j] = (float)hn;
    }
    __syncthreads();
  }
}

// ---------------- K2: GAT encoder (unchanged from R6) ----------------
__global__ __launch_bounds__(256) void k_gat(
    const float* __restrict__ ths, const double* __restrict__ wsd,
    float* __restrict__ gout)
{
  __shared__ float xA[64*65];
  __shared__ float hpB[64*68];
  __shared__ double as0[256], ad0[256];
  __shared__ double as1[64], ad1[64], mn[64], rs[64];
  __shared__ float zS[256];

  const double* w0  = wsd + O_W0;
  const double* a0s = wsd + O_A0S;
  const double* a0d = wsd + O_A0D;
  const double* b0  = wsd + O_B0;
  const double* w1  = wsd + O_W1;
  const double* a1s = wsd + O_A1S;
  const double* a1d = wsd + O_A1D;
  const double* b1  = wsd + O_B1;

  const int tid = threadIdx.x;
  const int sb = blockIdx.x >> 3, tb = blockIdx.x & 7;
  const int n = tid & 63;
  const int q = __builtin_amdgcn_readfirstlane(tid >> 6);

  const float* xin = ths + ((size_t)tb*NTOT + sb*64)*32;
  for (int idx = tid; idx < 2048; idx += 256)
    xA[(idx>>5)*65 + (idx&31)] = xin[idx];
  __syncthreads();
  if (tid < 32){
    double s1 = 0, s2 = 0;
    for (int p = 0; p < 64; ++p){ double v = xA[p*65+tid]; s1 += v; s2 += v*v; }
    double mu = s1*(1.0/64.0), va = s2*(1.0/64.0) - mu*mu;
    mn[tid] = mu; rs[tid] = fast_rsqrt(va + EPS);
  }
  __syncthreads();
  for (int idx = tid; idx < 2048; idx += 256){
    int p = idx>>5, f = idx&31;
    xA[p*65+f] = (float)(((double)xA[p*65+f] - mn[f])*rs[f]);
  }
  __syncthreads();
  { // hp0 (fp64) + attn dots (fp64), store hp0 fp32
    double acc[16];
    #pragma unroll
    for (int o = 0; o < 16; ++o) acc[o] = 0;
    for (int f = 0; f < 32; ++f){
      double xv = (double)xA[n*65+f];
      const double* wr = w0 + (q*32+f)*16;
      #pragma unroll
      for (int o = 0; o < 16; ++o) acc[o] += xv*wr[o];
    }
    double sa = 0, sd = 0;
    #pragma unroll
    for (int o = 0; o < 16; ++o){
      sa += acc[o]*a0s[q*16+o];
      sd += acc[o]*a0d[q*16+o];
      hpB[n*68 + q*16 + o] = (float)acc[o];
    }
    as0[q*64+n] = sa; ad0[q*64+n] = sd;
  }
  __syncthreads();
  { // attn L0: fp32 exp (const shift cancels), fp32 aggregate, ELU fp32
    float arow = (float)as0[q*64+n];
    float num[16];
    #pragma unroll
    for (int o = 0; o < 16; ++o) num[o] = 0.f;
    float Z = 0.f;
    for (int m2 = 0; m2 < 64; ++m2){
      float e = arow + (float)ad0[q*64+m2];
      float lr = e > 0.f ? e : 0.2f*e;
      float pv = __expf(lr - 30.0f);
      Z += pv;
      const float4* h4 = (const float4*)&hpB[m2*68 + q*16];
      #pragma unroll
      for (int o4 = 0; o4 < 4; ++o4){
        float4 v = h4[o4];
        num[o4*4+0] += pv*v.x; num[o4*4+1] += pv*v.y;
        num[o4*4+2] += pv*v.z; num[o4*4+3] += pv*v.w;
      }
    }
    float iZ = 1.0f/Z;
    #pragma unroll
    for (int o = 0; o < 16; ++o){
      float y = num[o]*iZ + (float)b0[o];
      xA[n*65 + q*16 + o] = y > 0.f ? y : __expf(y)-1.0f;
    }
  }
  __syncthreads();
  if (tid < 64){
    double s1 = 0, s2 = 0;
    for (int p = 0; p < 64; ++p){ double v = xA[p*65+tid]; s1 += v; s2 += v*v; }
    double mu = s1*(1.0/64.0), va = s2*(1.0/64.0) - mu*mu;
    mn[tid] = mu; rs[tid] = fast_rsqrt(va + EPS);
  }
  __syncthreads();
  for (int idx = tid; idx < 4096; idx += 256){
    int p = idx>>6, f = idx&63;
    xA[p*65+f] = (float)(((double)xA[p*65+f] - mn[f])*rs[f]);
  }
  __syncthreads();
  { // hp1 (fp64 compute, fp32 store)
    double a8[8];
    #pragma unroll
    for (int j = 0; j < 8; ++j) a8[j] = 0;
    for (int f = 0; f < 64; ++f){
      double xv = (double)xA[n*65+f];
      const double* wr = w1 + f*32 + q*8;
      #pragma unroll
      for (int j = 0; j < 8; ++j) a8[j] += xv*wr[j];
    }
    #pragma unroll
    for (int j = 0; j < 8; ++j) hpB[n*68 + q*8 + j] = (float)a8[j];
  }
  __syncthreads();
  { // as1/ad1 partials
    double sa = 0, sd = 0;
    #pragma unroll
    for (int o = 0; o < 8; ++o){
      double v = (double)hpB[n*68 + q*8 + o];
      sa += v*a1s[q*8+o]; sd += v*a1d[q*8+o];
    }
    as0[q*64+n] = sa; ad0[q*64+n] = sd;
  }
  __syncthreads();
  if (tid < 128){
    int n2 = tid & 63;
    if (tid < 64) as1[n2] = as0[n2]+as0[64+n2]+as0[128+n2]+as0[192+n2];
    else          ad1[n2] = ad0[n2]+ad0[64+n2]+ad0[128+n2]+ad0[192+n2];
  }
  __syncthreads();
  { // L1 softmax probs fp32
    float arow = (float)as1[n];
    float zp = 0.f;
    for (int m2 = q*16; m2 < q*16+16; ++m2){
      float e = arow + (float)ad1[m2];
      float lr = e > 0.f ? e : 0.2f*e;
      float pv = __expf(lr - 30.0f);
      zp += pv;
      xA[n*65+m2] = pv;
    }
    zS[q*64+n] = zp;
  }
  __syncthreads();
  { // aggregate L1 fp32, write gin as [t][scene][f][ped]
    float Z = zS[n]+zS[64+n]+zS[128+n]+zS[192+n];
    float iZ = 1.0f/Z;
    float a8[8];
    #pragma unroll
    for (int j = 0; j < 8; ++j) a8[j] = 0.f;
    for (int m2 = 0; m2 < 64; ++m2){
      float av = xA[n*65+m2];
      const float4* h4 = (const float4*)&hpB[m2*68 + q*8];
      float4 v0 = h4[0], v1 = h4[1];
      a8[0] += av*v0.x; a8[1] += av*v0.y; a8[2] += av*v0.z; a8[3] += av*v0.w;
      a8[4] += av*v1.x; a8[5] += av*v1.y; a8[6] += av*v1.z; a8[7] += av*v1.w;
    }
    float* go = gout + ((size_t)(tb*NSC + sb)*32)*64;
    #pragma unroll
    for (int j = 0; j < 8; ++j)
      go[(q*8+j)*64 + n] = a8[j]*iZ + (float)b1[q*8+j];
  }
}

// ---------------- K3: graph LSTM + folded LN (unchanged from R6) ----------------
__global__ __launch_bounds__(256) void k_graph(
    const float* __restrict__ gin, const float* __restrict__ h0,
    const float* __restrict__ c0, const double* __restrict__ wsd,
    float* __restrict__ gh)
{
  __shared__ double hdl[2][2048];
  __shared__ double xld[2][2048];
  __shared__ double ps[256], pq[256];
  const double* wihT = wsd + O_GWIHT;
  const double* w2   = wsd + O_GW2;
  const double* bdp  = wsd + O_GBD;
  const double* gCw  = wsd + O_GCW;
  const double* lng  = wsd + O_GLNG;
  const double* lnb  = wsd + O_GLNB;
  const double* ginv = wsd + O_GINV;
  const int tid = threadIdx.x, lane = tid & 63;
  const int wv = __builtin_amdgcn_readfirstlane(tid >> 6);
  const int ub = wv*8;
  const int sb = blockIdx.x, ped0 = sb*64, ped = ped0 + lane;
  for (int idx = tid; idx < 2048; idx += 256){
    int f = idx>>6, p = idx&63;
    hdl[0][idx] = ((double)h0[(ped0+p)*32 + f] - ginv[32+f]) * ginv[f];
  }
  {
    const float* gb0p = gin + (size_t)(0*NSC + sb)*2048;
    for (int idx = tid; idx < 2048; idx += 256) xld[0][idx] = (double)gb0p[idx];
  }
  double c[8];
  #pragma unroll
  for (int j = 0; j < 8; ++j) c[j] = (double)c0[ped*32 + ub + j];
  double mu = 0.0, ri = 1.0;
  __syncthreads();

  for (int t = 0; t < T_OBS; ++t){
    const int p = t & 1;
    if (t < T_OBS-1){
      const float* gbn = gin + (size_t)((t+1)*NSC + sb)*2048;
      for (int idx = tid; idx < 2048; idx += 256) xld[p^1][idx] = (double)gbn[idx];
    }
    double accX[32], accH[32];
    #pragma unroll
    for (int j4 = 0; j4 < 32; ++j4){ accX[j4] = 0; accH[j4] = 0; }
    for (int k = 0; k < 32; ++k){
      double xk = xld[p][k*64 + lane];
      double hk = hdl[p][k*64 + lane];
      const double* wi = wihT + k*128;
      const double* wh = w2   + k*128;
      #pragma unroll
      for (int j = 0; j < 8; ++j){
        #pragma unroll
        for (int g = 0; g < 4; ++g){
          accX[j*4+g] += wi[g*32 + ub + j]*xk;
          accH[j*4+g] += wh[g*32 + ub + j]*hk;
        }
      }
    }
    double hp[8]; double s1 = 0, s2 = 0;
    #pragma unroll
    for (int j = 0; j < 8; ++j){
      double pre[4];
      #pragma unroll
      for (int g = 0; g < 4; ++g){
        int r = g*32 + ub + j;
        pre[g] = bdp[r] + accX[j*4+g] + ri*__builtin_fma(-mu, gCw[r], accH[j*4+g]);
      }
      double ig = fsig(pre[0]);
      double fg = fsig(pre[1]);
      double gg = ftanh(pre[2]);
      double og = fsig(pre[3]);
      c[j] = fg*c[j] + ig*gg;
      hp[j] = og*ftanh(c[j]);
      s1 += hp[j]; s2 += hp[j]*hp[j];
      hdl[p^1][(ub+j)*64 + lane] = hp[j];
    }
    ps[wv*64+lane] = s1; pq[wv*64+lane] = s2;
    __syncthreads();
    double sa = ps[lane]+ps[64+lane]+ps[128+lane]+ps[192+lane];
    double sq = pq[lane]+pq[64+lane]+pq[128+lane]+pq[192+lane];
    mu = sa*(1.0/32.0);
    double va = sq*(1.0/32.0) - mu*mu;
    ri = fast_rsqrt(va + EPS);
    if (t == T_OBS-1){
      #pragma unroll
      for (int j = 0; j < 8; ++j){
        int u = ub + j;
        gh[ped*32 + u] = (float)((hp[j]-mu)*ri*lng[u] + lnb[u]);
      }
    }
  }
}

// ---------------- K4: pred LSTM — VMEM packed fp32 weights + fp32 gates ----------------
__global__ __launch_bounds__(512) void k_pred(
    const float* __restrict__ traj_hs, const float* __restrict__ gh,
    const float* __restrict__ zn, const float* __restrict__ obs,
    const double* __restrict__ wsd, const float* __restrict__ w2p,
    const float* __restrict__ als, float* __restrict__ out)
{
  __shared__ float hd[5120];                  // h (pre-LN rep) fp32
  __shared__ double ps[512], pq[512];
  __shared__ float pw0[512], pw1[512];
  const double* wih  = wsd + O_PWIH;
  const double* bdp  = wsd + O_PBD;
  const double* pCw  = wsd + O_PCW;
  const double* gw   = wsd + O_PGW;
  const double* psc  = wsd + O_PSC;
  const double* pinv = wsd + O_PINV;
  const int tid = threadIdx.x, lane = tid & 63;
  const int wv = __builtin_amdgcn_readfirstlane(tid >> 6);
  const int ub = wv*10;
  const int scene = blockIdx.x, ped0 = scene*64, ped = ped0 + lane;

  // opaque zero: defeats uniform-address scalarization -> forces VMEM loads
  int vz; asm volatile("v_mov_b32 %0, 0" : "=v"(vz));
  const float4* __restrict__ wp4 = ((const float4*)w2p) + vz;

  for (int idx = tid; idx < 5120; idx += 512){
    int f = idx>>6, p = idx&63;
    float v;
    if (f < 32)      v = traj_hs[((size_t)7*NTOT + ped0 + p)*32 + f];
    else if (f < 64) v = gh[(ped0+p)*32 + (f-32)];
    else             v = zn[scene*16 + (f-64)];
    hd[idx] = (float)(((double)v - pinv[80+f]) * pinv[f]);
  }
  // constant log_std / std outputs (independent of the loop)
  {
    const int M = PRED_LEN*NTOT*2;
    float l0 = als[0], l1 = als[1];
    float e0 = (float)fast_exp((double)l0), e1 = (float)fast_exp((double)l1);
    for (int i = tid; i < PRED_LEN*64*2; i += 512){
      int t = i >> 7; int rem = i & 127; int p2 = rem >> 1; int ch = rem & 1;
      int gi = (t*NTOT + ped0 + p2)*2 + ch;
      out[M + gi]   = ch ? l1 : l0;
      out[2*M + gi] = ch ? e1 : e0;
    }
  }
  double c[10];
  #pragma unroll
  for (int j = 0; j < 10; ++j) c[j] = 0.0;
  double x0 = (double)obs[((size_t)7*NTOT + ped)*2 + 0];
  double x1 = (double)obs[((size_t)7*NTOT + ped)*2 + 1];
  double mu = 0.0, ri = 1.0, invri = 1.0;
  const double Cgw0 = psc[0], Cgw1 = psc[1], Cbw0 = psc[2], Cbw1 = psc[3];
  // hoist head weights (fp32)
  float gwf0[10], gwf1[10];
  #pragma unroll
  for (int j = 0; j < 10; ++j){ gwf0[j] = (float)gw[ub+j]; gwf1[j] = (float)gw[80+ub+j]; }
  __syncthreads();

  for (int t = 0; t < PRED_LEN; ++t){
    // hoisted init (scaled by invri so final pre = ri*acc)
    float accg[40];
    #pragma unroll
    for (int j = 0; j < 10; ++j){
      #pragma unroll
      for (int g = 0; g < 4; ++g){
        int r = g*80 + ub + j;
        accg[j*4+g] = (float)(__builtin_fma(bdp[r] + wih[r*2+0]*x0 + wih[r*2+1]*x1,
                                            invri, -mu*pCw[r]));
      }
    }
    // fp32 GEMV, weights via vector loads (VMEM pipelined)
    #pragma unroll 4
    for (int k = 0; k < 80; ++k){
      float hk = hd[k*64 + lane];
      const float4* w4 = wp4 + (size_t)(k*8 + wv)*10;
      #pragma unroll
      for (int q4 = 0; q4 < 10; ++q4){
        float4 w = w4[q4];
        accg[q4*4+0] += w.x*hk;
        accg[q4*4+1] += w.y*hk;
        accg[q4*4+2] += w.z*hk;
        accg[q4*4+3] += w.w*hk;
      }
    }
    float rif = (float)ri;
    float hp32[10]; double s1 = 0, s2 = 0; float sw0 = 0.f, sw1 = 0.f;
    #pragma unroll
    for (int j = 0; j < 10; ++j){
      float ig = fsig32(rif*accg[j*4+0]);
      float fg = fsig32(rif*accg[j*4+1]);
      float gg = ftanh32(rif*accg[j*4+2]);
      float og = fsig32(rif*accg[j*4+3]);
      c[j] = (double)fg*c[j] + (double)(ig*gg);
      float h32 = og*ftanh32((float)c[j]);
      hp32[j] = h32;
      s1 += (double)h32; s2 += (double)(h32*h32);
      sw0 += h32*gwf0[j]; sw1 += h32*gwf1[j];
    }
    __syncthreads();                 // all GEMV reads of hd done
    #pragma unroll
    for (int j = 0; j < 10; ++j) hd[(ub+j)*64 + lane] = hp32[j];
    ps[wv*64+lane] = s1; pq[wv*64+lane] = s2;
    pw0[wv*64+lane] = sw0; pw1[wv*64+lane] = sw1;
    __syncthreads();                 // writes visible
    double sa = 0, sq = 0, t0 = 0, t1 = 0;
    #pragma unroll
    for (int w = 0; w < 8; ++w){
      sa += ps[w*64+lane]; sq += pq[w*64+lane];
      t0 += (double)pw0[w*64+lane]; t1 += (double)pw1[w*64+lane];
    }
    mu = sa*(1.0/80.0);
    double va = sq*(1.0/80.0) - mu*mu;
    ri = fast_rsqrt(va + EPS);
    invri = (va + EPS)*ri;           // = 1/ri
    x0 = ri*__builtin_fma(-mu, Cgw0, t0) + Cbw0;
    x1 = ri*__builtin_fma(-mu, Cgw1, t1) + Cbw1;
    if (wv == 0){
      out[((size_t)t*NTOT + ped)*2 + 0] = (float)x0;
      out[((size_t)t*NTOT + ped)*2 + 1] = (float)x1;
    }
  }
}

extern "C" void kernel_launch(void* const* d_in, const int* in_sizes, int n_in,
                              void* d_out, int out_size, void* d_ws, size_t ws_size,
                              hipStream_t stream)
{
  const float* obs   = (const float*)d_in[0];
  const float* zn    = (const float*)d_in[2];
  const float* th0   = (const float*)d_in[3];
  const float* tc0   = (const float*)d_in[4];
  const float* gh0   = (const float*)d_in[5];
  const float* gc0   = (const float*)d_in[6];
  const float* gw0   = (const float*)d_in[7];
  const float* gas0  = (const float*)d_in[8];
  const float* gad0  = (const float*)d_in[9];
  const float* gb0   = (const float*)d_in[10];
  const float* gw1   = (const float*)d_in[11];
  const float* gas1  = (const float*)d_in[12];
  const float* gad1  = (const float*)d_in[13];
  const float* gb1   = (const float*)d_in[14];
  const float* twih  = (const float*)d_in[15];
  const float* twhh  = (const float*)d_in[16];
  const float* tbih  = (const float*)d_in[17];
  const float* tbhh  = (const float*)d_in[18];
  const float* gwih  = (const float*)d_in[19];
  const float* gwhh  = (const float*)d_in[20];
  const float* gbih  = (const float*)d_in[21];
  const float* gbhh  = (const float*)d_in[22];
  const float* glng  = (const float*)d_in[23];
  const float* glnb  = (const float*)d_in[24];
  const float* pwih  = (const float*)d_in[25];
  const float* pwhh  = (const float*)d_in[26];
  const float* pbih  = (const float*)d_in[27];
  const float* pbhh  = (const float*)d_in[28];
  const float* plng  = (const float*)d_in[29];
  const float* plnb  = (const float*)d_in[30];
  const float* poww  = (const float*)d_in[31];
  const float* pob   = (const float*)d_in[32];
  const float* als   = (const float*)d_in[33];

  float* out = (float*)d_out;
  double* wsd = (double*)d_ws;
  float* wsf = (float*)(wsd + D_TOTAL);             // fp32 region
  float* w2p     = wsf + OF_PW2P;                   // packed [80][8][40]
  float* traj_hs = wsf + F_TOTAL;                   // [8][NTOT][32]
  float* gin     = traj_hs + (size_t)8*NTOT*32;     // [8][NSC][32][64]
  float* gh      = gin + (size_t)8*NTOT*32;         // [NTOT][32]

  k_prep<<<dim3(104), dim3(256), 0, stream>>>(
      pwhh, pwih, pbih, pbhh, plng, plnb, poww, pob,
      twih, twhh, tbih, tbhh, gwih, gwhh, gbih, gbhh, glng, glnb,
      gw0, gas0, gad0, gb0, gw1, gas1, gad1, gb1, wsd, wsf);
  k_traj<<<dim3(512), dim3(256), 0, stream>>>(obs, th0, tc0, wsd, traj_hs);
  k_gat<<<dim3(4096), dim3(256), 0, stream>>>(traj_hs, wsd, gin);
  k_graph<<<dim3(512), dim3(256), 0, stream>>>(gin, gh0, gc0, wsd, gh);
  k_pred<<<dim3(512), dim3(512), 0, stream>>>(traj_hs, gh, zn, obs, wsd, w2p, als, out);
}

// Round 8
// 1242.568 us; speedup vs baseline: 1.3500x; 1.3500x over previous
//
#include <hip/hip_runtime.h>
#include <math.h>

#define T_OBS 8
#define PRED_LEN 12
#define NSC 512
#define NPED 64
#define NTOT (NSC*NPED)
#define EPS 1e-5

typedef float f32x2 __attribute__((ext_vector_type(2)));
typedef float f32x4 __attribute__((ext_vector_type(4)));

// ---- ws double-region offsets (in doubles) ----
#define O_PWIH   25600    // pred wih [320][2]
#define O_PBD    26240    // pred bih+bhh+Cb [320]
#define O_PCW    26560    // Cw[r] [320]
#define O_PGW    26880    // gw0[80], gw1[80]
#define O_PSC    27040    // Cgw0, Cgw1, Cbw0+bout0, Cbw1+bout1
#define O_PINV   27048    // invg[80], b[80]
#define O_TWIH   27208    // traj wih [128][2]
#define O_TWHHT  27464    // traj whh^T [32 k][128 r]
#define O_TB     31560    // traj bih+bhh [128]
#define O_GWIHT  31688    // graph wih^T [32 k][128 r]
#define O_GW2    35784    // graph whh^T g-folded [32 k][128 r]
#define O_GBD    39880    // graph bih+bhh+gCb [128]
#define O_GCW    40008    // gCw[r] [128]
#define O_GLNG   40136
#define O_GLNB   40168
#define O_GINV   40200    // ginvg[32], gb[32]
#define O_W0     40264    // gat w0 [4][32][16]
#define O_A0S    42312
#define O_A0D    42376
#define O_B0     42440
#define O_W1     42456    // gat w1 [64][32]
#define O_A1S    44504
#define O_A1D    44536
#define O_B1     44568
#define D_TOTAL  44600
// float region (offsets in floats, from wsf = (float*)(wsd + D_TOTAL))
#define OF_PW2P  0        // pred whh^T g-folded fp32 PACKED [80 k][8 wv][40 j4]
#define OF_PBDF  25600    // fp32 bih+bhh+Cb [320]
#define OF_PCWF  25920    // fp32 Cw [320]
#define OF_PWIHF 26240    // fp32 wih [320][2]
#define F_TOTAL  26880

// ---------- fast fp64 math (validated bit-identical absmax R3-R7) ----------
__device__ __forceinline__ double fast_exp(double x){
  x = fmin(fmax(x, -708.0), 708.0);
  const double L2E  = 1.4426950408889634074;
  const double LN2H = 6.93147180369123816490e-01;
  const double LN2L = 1.90821492927058770002e-10;
  double t = x*L2E;
  double n = rint(t);
  int ni = (int)n;
  double r = __builtin_fma(-n, LN2H, x);
  r = __builtin_fma(-n, LN2L, r);
  double p = 2.08767569878681e-09;
  p = __builtin_fma(p, r, 2.505210838544172e-08);
  p = __builtin_fma(p, r, 2.755731922398589e-07);
  p = __builtin_fma(p, r, 2.755731922398589e-06);
  p = __builtin_fma(p, r, 2.480158730158730e-05);
  p = __builtin_fma(p, r, 1.984126984126984e-04);
  p = __builtin_fma(p, r, 1.388888888888889e-03);
  p = __builtin_fma(p, r, 8.333333333333333e-03);
  p = __builtin_fma(p, r, 4.166666666666667e-02);
  p = __builtin_fma(p, r, 1.666666666666667e-01);
  p = __builtin_fma(p, r, 0.5);
  p = __builtin_fma(p, r, 1.0);
  p = __builtin_fma(p, r, 1.0);
  double s = __hiloint2double((ni + 1023) << 20, 0);
  return p*s;
}
__device__ __forceinline__ double fast_rcp(double d){
#if __has_builtin(__builtin_amdgcn_rcp)
  double r = __builtin_amdgcn_rcp(d);
#else
  double r = 1.0/d;
#endif
  double e = __builtin_fma(-d, r, 1.0); r = __builtin_fma(r, e, r);
  e = __builtin_fma(-d, r, 1.0); r = __builtin_fma(r, e, r);
  e = __builtin_fma(-d, r, 1.0); r = __builtin_fma(r, e, r);
  return r;
}
__device__ __forceinline__ double fast_rsqrt(double d){
#if __has_builtin(__builtin_amdgcn_rsq)
  double r = __builtin_amdgcn_rsq(d);
#else
  double r = 1.0/sqrt(d);
#endif
  double hr = 0.5*d;
  r = r*__builtin_fma(-hr*r, r, 1.5);
  r = r*__builtin_fma(-hr*r, r, 1.5);
  r = r*__builtin_fma(-hr*r, r, 1.5);
  return r;
}
__device__ __forceinline__ double fsig(double x){
  double xc = fmin(fmax(x, -40.0), 40.0);
  return fast_rcp(1.0 + fast_exp(-xc));
}
__device__ __forceinline__ double ftanh(double x){
  double xc = fmin(fmax(x, -20.0), 20.0);
  return __builtin_fma(-2.0, fast_rcp(1.0 + fast_exp(2.0*xc)), 1.0);
}
// ---------- fp32 fast gates (k_pred only) ----------
__device__ __forceinline__ float fsig32(float x){
  x = fminf(fmaxf(x, -30.f), 30.f);
  return 1.0f/(1.0f + __expf(-x));
}
__device__ __forceinline__ float ftanh32(float x){
  x = fminf(fmaxf(x, -15.f), 15.f);
  return 1.0f - 2.0f/(1.0f + __expf(2.f*x));
}
// packed dual-fp32 FMA (CDNA VOP3P): a += w*h elementwise on 2 lanes
__device__ __forceinline__ void pk_fma(f32x2 &a, f32x2 w, f32x2 h){
  asm("v_pk_fma_f32 %0, %1, %2, %0" : "+v"(a) : "v"(w), "v"(h));
}

// ---------------- prep ----------------
__global__ void k_prep(
    const float* __restrict__ pwhh, const float* __restrict__ pwih,
    const float* __restrict__ pbih, const float* __restrict__ pbhh,
    const float* __restrict__ plng, const float* __restrict__ plnb,
    const float* __restrict__ pwout, const float* __restrict__ pbout,
    const float* __restrict__ twih, const float* __restrict__ twhh,
    const float* __restrict__ tbih, const float* __restrict__ tbhh,
    const float* __restrict__ gwih, const float* __restrict__ gwhh,
    const float* __restrict__ gbih, const float* __restrict__ gbhh,
    const float* __restrict__ glng, const float* __restrict__ glnb,
    const float* __restrict__ w0, const float* __restrict__ a0s,
    const float* __restrict__ a0d, const float* __restrict__ b0,
    const float* __restrict__ w1, const float* __restrict__ a1s,
    const float* __restrict__ a1d, const float* __restrict__ b1,
    double* __restrict__ wsd, float* __restrict__ wsf)
{
  int i = blockIdx.x*256 + threadIdx.x;
  // pred packed fp32: w2p[(k*8+wv)*40 + j*4+g] = whh[g*80+wv*10+j][k] * g[k]
  if (i < 25600){
    int kk = i/320, rem = i - kk*320;
    int wv = rem/40, j4 = rem - wv*40;
    int j = j4>>2, g = j4&3;
    int r = g*80 + wv*10 + j;
    wsf[OF_PW2P + i] = (float)((double)pwhh[r*80 + kk] * (double)plng[kk]);
  }
  if (i < 640){
    wsd[O_PWIH + i] = (double)pwih[i];
    wsf[OF_PWIHF + i] = pwih[i];
  }
  if (i < 320){
    double s = 0, sb = 0;
    for (int k = 0; k < 80; ++k){
      double w = (double)pwhh[i*80 + k];
      s  += w*(double)plng[k];
      sb += w*(double)plnb[k];
    }
    wsd[O_PCW + i] = s;
    wsd[O_PBD + i] = (double)pbih[i] + (double)pbhh[i] + sb;
    wsf[OF_PCWF + i] = (float)s;
    wsf[OF_PBDF + i] = (float)((double)pbih[i] + (double)pbhh[i] + sb);
  }
  if (i < 160){
    if (i < 80) wsd[O_PGW + i] = (double)plng[i]*(double)pwout[i];
    else        wsd[O_PGW + i] = (double)plng[i-80]*(double)pwout[80 + (i-80)];
  }
  if (i < 4){
    double s = 0;
    if (i == 0){ for (int u = 0; u < 80; ++u) s += (double)plng[u]*(double)pwout[u]; }
    if (i == 1){ for (int u = 0; u < 80; ++u) s += (double)plng[u]*(double)pwout[80+u]; }
    if (i == 2){ for (int u = 0; u < 80; ++u) s += (double)plnb[u]*(double)pwout[u]; s += (double)pbout[0]; }
    if (i == 3){ for (int u = 0; u < 80; ++u) s += (double)plnb[u]*(double)pwout[80+u]; s += (double)pbout[1]; }
    wsd[O_PSC + i] = s;
  }
  if (i < 160){
    if (i < 80) wsd[O_PINV + i] = 1.0/(double)plng[i];
    else        wsd[O_PINV + i] = (double)plnb[i-80];
  }
  if (i < 256) wsd[O_TWIH + i] = (double)twih[i];
  if (i < 4096){
    int r = i>>5, k = i&31;
    wsd[O_TWHHT + k*128 + r] = (double)twhh[i];
    wsd[O_GWIHT + k*128 + r] = (double)gwih[i];
    wsd[O_GW2   + k*128 + r] = (double)gwhh[i]*(double)glng[k];
  }
  if (i < 128){
    wsd[O_TB + i] = (double)tbih[i] + (double)tbhh[i];
    double s = 0, sb = 0;
    for (int k = 0; k < 32; ++k){
      double w = (double)gwhh[i*32 + k];
      s  += w*(double)glng[k];
      sb += w*(double)glnb[k];
    }
    wsd[O_GCW + i] = s;
    wsd[O_GBD + i] = (double)gbih[i] + (double)gbhh[i] + sb;
  }
  if (i < 32){
    wsd[O_GLNG + i] = (double)glng[i]; wsd[O_GLNB + i] = (double)glnb[i];
    wsd[O_GINV + i] = 1.0/(double)glng[i];
    wsd[O_GINV + 32 + i] = (double)glnb[i];
    wsd[O_A1S + i] = (double)a1s[i]; wsd[O_A1D + i] = (double)a1d[i];
    wsd[O_B1 + i] = (double)b1[i];
  }
  if (i < 2048){ wsd[O_W0 + i] = (double)w0[i]; wsd[O_W1 + i] = (double)w1[i]; }
  if (i < 64){ wsd[O_A0S + i] = (double)a0s[i]; wsd[O_A0D + i] = (double)a0d[i]; }
  if (i < 16) wsd[O_B0 + i] = (double)b0[i];
}

// ---------------- K1: traj LSTM (unchanged from R6) ----------------
__global__ __launch_bounds__(256) void k_traj(
    const float* __restrict__ obs, const float* __restrict__ h0,
    const float* __restrict__ c0, const double* __restrict__ wsd,
    float* __restrict__ traj_hs)
{
  __shared__ double hdl[2][2048];
  const double* wih  = wsd + O_TWIH;
  const double* whhT = wsd + O_TWHHT;
  const double* bd   = wsd + O_TB;
  const int tid = threadIdx.x, lane = tid & 63;
  const int wv = __builtin_amdgcn_readfirstlane(tid >> 6);
  const int ub = wv*8;
  const int ped0 = blockIdx.x*64, ped = ped0 + lane;
  for (int idx = tid; idx < 2048; idx += 256){
    int f = idx>>6, p = idx&63;
    hdl[0][idx] = (double)h0[(ped0+p)*32 + f];
  }
  double c[8];
  #pragma unroll
  for (int j = 0; j < 8; ++j) c[j] = (double)c0[ped*32 + ub + j];
  __syncthreads();

  for (int t = 0; t < T_OBS; ++t){
    const int p = t & 1;
    double x0 = (double)obs[((size_t)t*NTOT + ped)*2 + 0];
    double x1 = (double)obs[((size_t)t*NTOT + ped)*2 + 1];
    double acc[32];
    #pragma unroll
    for (int j = 0; j < 8; ++j){
      #pragma unroll
      for (int g = 0; g < 4; ++g){
        int r = g*32 + ub + j;
        acc[j*4+g] = bd[r] + wih[r*2+0]*x0 + wih[r*2+1]*x1;
      }
    }
    for (int k = 0; k < 32; ++k){
      double hk = hdl[p][k*64 + lane];
      const double* wh = whhT + k*128;
      #pragma unroll
      for (int j = 0; j < 8; ++j){
        #pragma unroll
        for (int g = 0; g < 4; ++g) acc[j*4+g] += wh[g*32 + ub + j]*hk;
      }
    }
    #pragma unroll
    for (int j = 0; j < 8; ++j){
      double ig = fsig(acc[j*4+0]);
      double fg = fsig(acc[j*4+1]);
      double gg = ftanh(acc[j*4+2]);
      double og = fsig(acc[j*4+3]);
      c[j] = fg*c[j] + ig*gg;
      double hn = og*ftanh(c[j]);
      hdl[p^1][(ub+j)*64 + lane] = hn;
      traj_hs[((size_t)t*NTOT + ped)*32 + ub + j] = (float)hn;
    }
    __syncthreads();
  }
}

// ---------------- K2: GAT encoder (unchanged from R6) ----------------
__global__ __launch_bounds__(256) void k_gat(
    const float* __restrict__ ths, const double* __restrict__ wsd,
    float* __restrict__ gout)
{
  __shared__ float xA[64*65];
  __shared__ float hpB[64*68];
  __shared__ double as0[256], ad0[256];
  __shared__ double as1[64], ad1[64], mn[64], rs[64];
  __shared__ float zS[256];

  const double* w0  = wsd + O_W0;
  const double* a0s = wsd + O_A0S;
  const double* a0d = wsd + O_A0D;
  const double* b0  = wsd + O_B0;
  const double* w1  = wsd + O_W1;
  const double* a1s = wsd + O_A1S;
  const double* a1d = wsd + O_A1D;
  const double* b1  = wsd + O_B1;

  const int tid = threadIdx.x;
  const int sb = blockIdx.x >> 3, tb = blockIdx.x & 7;
  const int n = tid & 63;
  const int q = __builtin_amdgcn_readfirstlane(tid >> 6);

  const float* xin = ths + ((size_t)tb*NTOT + sb*64)*32;
  for (int idx = tid; idx < 2048; idx += 256)
    xA[(idx>>5)*65 + (idx&31)] = xin[idx];
  __syncthreads();
  if (tid < 32){
    double s1 = 0, s2 = 0;
    for (int p = 0; p < 64; ++p){ double v = xA[p*65+tid]; s1 += v; s2 += v*v; }
    double mu = s1*(1.0/64.0), va = s2*(1.0/64.0) - mu*mu;
    mn[tid] = mu; rs[tid] = fast_rsqrt(va + EPS);
  }
  __syncthreads();
  for (int idx = tid; idx < 2048; idx += 256){
    int p = idx>>5, f = idx&31;
    xA[p*65+f] = (float)(((double)xA[p*65+f] - mn[f])*rs[f]);
  }
  __syncthreads();
  { // hp0 (fp64) + attn dots (fp64), store hp0 fp32
    double acc[16];
    #pragma unroll
    for (int o = 0; o < 16; ++o) acc[o] = 0;
    for (int f = 0; f < 32; ++f){
      double xv = (double)xA[n*65+f];
      const double* wr = w0 + (q*32+f)*16;
      #pragma unroll
      for (int o = 0; o < 16; ++o) acc[o] += xv*wr[o];
    }
    double sa = 0, sd = 0;
    #pragma unroll
    for (int o = 0; o < 16; ++o){
      sa += acc[o]*a0s[q*16+o];
      sd += acc[o]*a0d[q*16+o];
      hpB[n*68 + q*16 + o] = (float)acc[o];
    }
    as0[q*64+n] = sa; ad0[q*64+n] = sd;
  }
  __syncthreads();
  { // attn L0: fp32 exp (const shift cancels), fp32 aggregate, ELU fp32
    float arow = (float)as0[q*64+n];
    float num[16];
    #pragma unroll
    for (int o = 0; o < 16; ++o) num[o] = 0.f;
    float Z = 0.f;
    for (int m2 = 0; m2 < 64; ++m2){
      float e = arow + (float)ad0[q*64+m2];
      float lr = e > 0.f ? e : 0.2f*e;
      float pv = __expf(lr - 30.0f);
      Z += pv;
      const float4* h4 = (const float4*)&hpB[m2*68 + q*16];
      #pragma unroll
      for (int o4 = 0; o4 < 4; ++o4){
        float4 v = h4[o4];
        num[o4*4+0] += pv*v.x; num[o4*4+1] += pv*v.y;
        num[o4*4+2] += pv*v.z; num[o4*4+3] += pv*v.w;
      }
    }
    float iZ = 1.0f/Z;
    #pragma unroll
    for (int o = 0; o < 16; ++o){
      float y = num[o]*iZ + (float)b0[o];
      xA[n*65 + q*16 + o] = y > 0.f ? y : __expf(y)-1.0f;
    }
  }
  __syncthreads();
  if (tid < 64){
    double s1 = 0, s2 = 0;
    for (int p = 0; p < 64; ++p){ double v = xA[p*65+tid]; s1 += v; s2 += v*v; }
    double mu = s1*(1.0/64.0), va = s2*(1.0/64.0) - mu*mu;
    mn[tid] = mu; rs[tid] = fast_rsqrt(va + EPS);
  }
  __syncthreads();
  for (int idx = tid; idx < 4096; idx += 256){
    int p = idx>>6, f = idx&63;
    xA[p*65+f] = (float)(((double)xA[p*65+f] - mn[f])*rs[f]);
  }
  __syncthreads();
  { // hp1 (fp64 compute, fp32 store)
    double a8[8];
    #pragma unroll
    for (int j = 0; j < 8; ++j) a8[j] = 0;
    for (int f = 0; f < 64; ++f){
      double xv = (double)xA[n*65+f];
      const double* wr = w1 + f*32 + q*8;
      #pragma unroll
      for (int j = 0; j < 8; ++j) a8[j] += xv*wr[j];
    }
    #pragma unroll
    for (int j = 0; j < 8; ++j) hpB[n*68 + q*8 + j] = (float)a8[j];
  }
  __syncthreads();
  { // as1/ad1 partials
    double sa = 0, sd = 0;
    #pragma unroll
    for (int o = 0; o < 8; ++o){
      double v = (double)hpB[n*68 + q*8 + o];
      sa += v*a1s[q*8+o]; sd += v*a1d[q*8+o];
    }
    as0[q*64+n] = sa; ad0[q*64+n] = sd;
  }
  __syncthreads();
  if (tid < 128){
    int n2 = tid & 63;
    if (tid < 64) as1[n2] = as0[n2]+as0[64+n2]+as0[128+n2]+as0[192+n2];
    else          ad1[n2] = ad0[n2]+ad0[64+n2]+ad0[128+n2]+ad0[192+n2];
  }
  __syncthreads();
  { // L1 softmax probs fp32
    float arow = (float)as1[n];
    float zp = 0.f;
    for (int m2 = q*16; m2 < q*16+16; ++m2){
      float e = arow + (float)ad1[m2];
      float lr = e > 0.f ? e : 0.2f*e;
      float pv = __expf(lr - 30.0f);
      zp += pv;
      xA[n*65+m2] = pv;
    }
    zS[q*64+n] = zp;
  }
  __syncthreads();
  { // aggregate L1 fp32, write gin as [t][scene][f][ped]
    float Z = zS[n]+zS[64+n]+zS[128+n]+zS[192+n];
    float iZ = 1.0f/Z;
    float a8[8];
    #pragma unroll
    for (int j = 0; j < 8; ++j) a8[j] = 0.f;
    for (int m2 = 0; m2 < 64; ++m2){
      float av = xA[n*65+m2];
      const float4* h4 = (const float4*)&hpB[m2*68 + q*8];
      float4 v0 = h4[0], v1 = h4[1];
      a8[0] += av*v0.x; a8[1] += av*v0.y; a8[2] += av*v0.z; a8[3] += av*v0.w;
      a8[4] += av*v1.x; a8[5] += av*v1.y; a8[6] += av*v1.z; a8[7] += av*v1.w;
    }
    float* go = gout + ((size_t)(tb*NSC + sb)*32)*64;
    #pragma unroll
    for (int j = 0; j < 8; ++j)
      go[(q*8+j)*64 + n] = a8[j]*iZ + (float)b1[q*8+j];
  }
}

// ---------------- K3: graph LSTM + folded LN (unchanged from R6) ----------------
__global__ __launch_bounds__(256) void k_graph(
    const float* __restrict__ gin, const float* __restrict__ h0,
    const float* __restrict__ c0, const double* __restrict__ wsd,
    float* __restrict__ gh)
{
  __shared__ double hdl[2][2048];
  __shared__ double xld[2][2048];
  __shared__ double ps[256], pq[256];
  const double* wihT = wsd + O_GWIHT;
  const double* w2   = wsd + O_GW2;
  const double* bdp  = wsd + O_GBD;
  const double* gCw  = wsd + O_GCW;
  const double* lng  = wsd + O_GLNG;
  const double* lnb  = wsd + O_GLNB;
  const double* ginv = wsd + O_GINV;
  const int tid = threadIdx.x, lane = tid & 63;
  const int wv = __builtin_amdgcn_readfirstlane(tid >> 6);
  const int ub = wv*8;
  const int sb = blockIdx.x, ped0 = sb*64, ped = ped0 + lane;
  for (int idx = tid; idx < 2048; idx += 256){
    int f = idx>>6, p = idx&63;
    hdl[0][idx] = ((double)h0[(ped0+p)*32 + f] - ginv[32+f]) * ginv[f];
  }
  {
    const float* gb0p = gin + (size_t)(0*NSC + sb)*2048;
    for (int idx = tid; idx < 2048; idx += 256) xld[0][idx] = (double)gb0p[idx];
  }
  double c[8];
  #pragma unroll
  for (int j = 0; j < 8; ++j) c[j] = (double)c0[ped*32 + ub + j];
  double mu = 0.0, ri = 1.0;
  __syncthreads();

  for (int t = 0; t < T_OBS; ++t){
    const int p = t & 1;
    if (t < T_OBS-1){
      const float* gbn = gin + (size_t)((t+1)*NSC + sb)*2048;
      for (int idx = tid; idx < 2048; idx += 256) xld[p^1][idx] = (double)gbn[idx];
    }
    double accX[32], accH[32];
    #pragma unroll
    for (int j4 = 0; j4 < 32; ++j4){ accX[j4] = 0; accH[j4] = 0; }
    for (int k = 0; k < 32; ++k){
      double xk = xld[p][k*64 + lane];
      double hk = hdl[p][k*64 + lane];
      const double* wi = wihT + k*128;
      const double* wh = w2   + k*128;
      #pragma unroll
      for (int j = 0; j < 8; ++j){
        #pragma unroll
        for (int g = 0; g < 4; ++g){
          accX[j*4+g] += wi[g*32 + ub + j]*xk;
          accH[j*4+g] += wh[g*32 + ub + j]*hk;
        }
      }
    }
    double hp[8]; double s1 = 0, s2 = 0;
    #pragma unroll
    for (int j = 0; j < 8; ++j){
      double pre[4];
      #pragma unroll
      for (int g = 0; g < 4; ++g){
        int r = g*32 + ub + j;
        pre[g] = bdp[r] + accX[j*4+g] + ri*__builtin_fma(-mu, gCw[r], accH[j*4+g]);
      }
      double ig = fsig(pre[0]);
      double fg = fsig(pre[1]);
      double gg = ftanh(pre[2]);
      double og = fsig(pre[3]);
      c[j] = fg*c[j] + ig*gg;
      hp[j] = og*ftanh(c[j]);
      s1 += hp[j]; s2 += hp[j]*hp[j];
      hdl[p^1][(ub+j)*64 + lane] = hp[j];
    }
    ps[wv*64+lane] = s1; pq[wv*64+lane] = s2;
    __syncthreads();
    double sa = ps[lane]+ps[64+lane]+ps[128+lane]+ps[192+lane];
    double sq = pq[lane]+pq[64+lane]+pq[128+lane]+pq[192+lane];
    mu = sa*(1.0/32.0);
    double va = sq*(1.0/32.0) - mu*mu;
    ri = fast_rsqrt(va + EPS);
    if (t == T_OBS-1){
      #pragma unroll
      for (int j = 0; j < 8; ++j){
        int u = ub + j;
        gh[ped*32 + u] = (float)((hp[j]-mu)*ri*lng[u] + lnb[u]);
      }
    }
  }
}

// ---------------- K4: pred LSTM — LDS-staged weights + v_pk_fma_f32 ----------------
__global__ __launch_bounds__(512) void k_pred(
    const float* __restrict__ traj_hs, const float* __restrict__ gh,
    const float* __restrict__ zn, const float* __restrict__ obs,
    const double* __restrict__ wsd, const float* __restrict__ wsf,
    const float* __restrict__ als, float* __restrict__ out)
{
  __shared__ float hd[5120];                  // h (pre-LN rep) fp32
  __shared__ float wbuf[2][2560];             // double-buffered weight chunks (8 k each)
  __shared__ double ps[512], pq[512];
  __shared__ float pw0[512], pw1[512];
  const float*  w2p  = wsf + OF_PW2P;
  const float*  bdf  = wsf + OF_PBDF;
  const float*  cwf  = wsf + OF_PCWF;
  const float*  wihf = wsf + OF_PWIHF;
  const double* gw   = wsd + O_PGW;
  const double* psc  = wsd + O_PSC;
  const double* pinv = wsd + O_PINV;
  const int tid = threadIdx.x, lane = tid & 63;
  const int wv = __builtin_amdgcn_readfirstlane(tid >> 6);
  const int ub = wv*10;
  const int scene = blockIdx.x, ped0 = scene*64, ped = ped0 + lane;

  for (int idx = tid; idx < 5120; idx += 512){
    int f = idx>>6, p = idx&63;
    float v;
    if (f < 32)      v = traj_hs[((size_t)7*NTOT + ped0 + p)*32 + f];
    else if (f < 64) v = gh[(ped0+p)*32 + (f-32)];
    else             v = zn[scene*16 + (f-64)];
    hd[idx] = (float)(((double)v - pinv[80+f]) * pinv[f]);
  }
  // constant log_std / std outputs (independent of the loop)
  {
    const int M = PRED_LEN*NTOT*2;
    float l0 = als[0], l1 = als[1];
    float e0 = (float)fast_exp((double)l0), e1 = (float)fast_exp((double)l1);
    for (int i = tid; i < PRED_LEN*64*2; i += 512){
      int t = i >> 7; int rem = i & 127; int p2 = rem >> 1; int ch = rem & 1;
      int gi = (t*NTOT + ped0 + p2)*2 + ch;
      out[M + gi]   = ch ? l1 : l0;
      out[2*M + gi] = ch ? e1 : e0;
    }
  }
  double c[10];
  #pragma unroll
  for (int j = 0; j < 10; ++j) c[j] = 0.0;
  double x0 = (double)obs[((size_t)7*NTOT + ped)*2 + 0];
  double x1 = (double)obs[((size_t)7*NTOT + ped)*2 + 1];
  double mu = 0.0, ri = 1.0, invri = 1.0;
  const double Cgw0 = psc[0], Cgw1 = psc[1], Cbw0 = psc[2], Cbw1 = psc[3];
  float gwf0[10], gwf1[10];
  #pragma unroll
  for (int j = 0; j < 10; ++j){ gwf0[j] = (float)gw[ub+j]; gwf1[j] = (float)gw[80+ub+j]; }

  // prologue: stage chunk 0 into wbuf[0]
  float wreg[5];
  #pragma unroll
  for (int i = 0; i < 5; ++i) wreg[i] = w2p[i*512 + tid];
  __syncthreads();                 // hd init visible (and wbuf free)
  #pragma unroll
  for (int i = 0; i < 5; ++i) wbuf[0][i*512 + tid] = wreg[i];
  __syncthreads();

  for (int t = 0; t < PRED_LEN; ++t){
    // fp32 gate-init, scaled by invri so final pre = ri*acc
    float x0f = (float)x0, x1f = (float)x1;
    float muf = (float)mu, invrif = (float)invri;
    f32x2 acc2[20];
    #pragma unroll
    for (int j = 0; j < 10; ++j){
      #pragma unroll
      for (int g = 0; g < 4; ++g){
        int r = g*80 + ub + j;
        float base = fmaf(wihf[r*2+1], x1f, fmaf(wihf[r*2+0], x0f, bdf[r]));
        float val = fmaf(base, invrif, -muf*cwf[r]);
        int idx = j*4+g;
        acc2[idx>>1][idx&1] = val;
      }
    }
    // 10 chunks of 8 k-slices, double-buffered through LDS
    for (int cch = 0; cch < 10; ++cch){
      const int nc = (cch < 9) ? cch+1 : 0;
      const bool stage = (cch < 9) || (t < PRED_LEN-1);
      if (stage){
        const float* src = w2p + nc*2560;
        #pragma unroll
        for (int i = 0; i < 5; ++i) wreg[i] = src[i*512 + tid];
      }
      const float* wb = wbuf[cch & 1];
      #pragma unroll
      for (int kk = 0; kk < 8; ++kk){
        int k = cch*8 + kk;
        float hk = hd[k*64 + lane];
        f32x2 h2; h2[0] = hk; h2[1] = hk;
        const f32x4* w4 = (const f32x4*)&wb[kk*320 + ub*4];
        #pragma unroll
        for (int q4 = 0; q4 < 10; ++q4){
          f32x4 w = w4[q4];
          f32x2 wlo; wlo[0] = w[0]; wlo[1] = w[1];
          f32x2 whi; whi[0] = w[2]; whi[1] = w[3];
          pk_fma(acc2[q4*2+0], wlo, h2);
          pk_fma(acc2[q4*2+1], whi, h2);
        }
      }
      __syncthreads();             // all waves done reading chunk cch (and earlier)
      if (stage){
        float* dst = wbuf[nc & 1];
        #pragma unroll
        for (int i = 0; i < 5; ++i) dst[i*512 + tid] = wreg[i];
      }
      __syncthreads();             // chunk nc visible
    }
    // gates (fp32) + fp64 c-state
    float rif = (float)ri;
    float hp32[10]; double s1 = 0, s2 = 0; float sw0 = 0.f, sw1 = 0.f;
    #pragma unroll
    for (int j = 0; j < 10; ++j){
      float pg0 = acc2[(j*4+0)>>1][(j*4+0)&1];
      float pg1 = acc2[(j*4+1)>>1][(j*4+1)&1];
      float pg2 = acc2[(j*4+2)>>1][(j*4+2)&1];
      float pg3 = acc2[(j*4+3)>>1][(j*4+3)&1];
      float ig = fsig32(rif*pg0);
      float fg = fsig32(rif*pg1);
      float gg = ftanh32(rif*pg2);
      float og = fsig32(rif*pg3);
      c[j] = (double)fg*c[j] + (double)(ig*gg);
      float h32 = og*ftanh32((float)c[j]);
      hp32[j] = h32;
      s1 += (double)h32; s2 += (double)(h32*h32);
      sw0 += h32*gwf0[j]; sw1 += h32*gwf1[j];
    }
    // hd reads all done (chunk-9 barriers); write new h directly
    #pragma unroll
    for (int j = 0; j < 10; ++j) hd[(ub+j)*64 + lane] = hp32[j];
    ps[wv*64+lane] = s1; pq[wv*64+lane] = s2;
    pw0[wv*64+lane] = sw0; pw1[wv*64+lane] = sw1;
    __syncthreads();               // writes visible
    double sa = 0, sq = 0, t0 = 0, t1 = 0;
    #pragma unroll
    for (int w = 0; w < 8; ++w){
      sa += ps[w*64+lane]; sq += pq[w*64+lane];
      t0 += (double)pw0[w*64+lane]; t1 += (double)pw1[w*64+lane];
    }
    mu = sa*(1.0/80.0);
    double va = sq*(1.0/80.0) - mu*mu;
    ri = fast_rsqrt(va + EPS);
    invri = (va + EPS)*ri;         // = 1/ri
    x0 = ri*__builtin_fma(-mu, Cgw0, t0) + Cbw0;
    x1 = ri*__builtin_fma(-mu, Cgw1, t1) + Cbw1;
    if (wv == 0){
      out[((size_t)t*NTOT + ped)*2 + 0] = (float)x0;
      out[((size_t)t*NTOT + ped)*2 + 1] = (float)x1;
    }
  }
}

extern "C" void kernel_launch(void* const* d_in, const int* in_sizes, int n_in,
                              void* d_out, int out_size, void* d_ws, size_t ws_size,
                              hipStream_t stream)
{
  const float* obs   = (const float*)d_in[0];
  const float* zn    = (const float*)d_in[2];
  const float* th0   = (const float*)d_in[3];
  const float* tc0   = (const float*)d_in[4];
  const float* gh0   = (const float*)d_in[5];
  const float* gc0   = (const float*)d_in[6];
  const float* gw0   = (const float*)d_in[7];
  const float* gas0  = (const float*)d_in[8];
  const float* gad0  = (const float*)d_in[9];
  const float* gb0   = (const float*)d_in[10];
  const float* gw1   = (const float*)d_in[11];
  const float* gas1  = (const float*)d_in[12];
  const float* gad1  = (const float*)d_in[13];
  const float* gb1   = (const float*)d_in[14];
  const float* twih  = (const float*)d_in[15];
  const float* twhh  = (const float*)d_in[16];
  const float* tbih  = (const float*)d_in[17];
  const float* tbhh  = (const float*)d_in[18];
  const float* gwih  = (const float*)d_in[19];
  const float* gwhh  = (const float*)d_in[20];
  const float* gbih  = (const float*)d_in[21];
  const float* gbhh  = (const float*)d_in[22];
  const float* glng  = (const float*)d_in[23];
  const float* glnb  = (const float*)d_in[24];
  const float* pwih  = (const float*)d_in[25];
  const float* pwhh  = (const float*)d_in[26];
  const float* pbih  = (const float*)d_in[27];
  const float* pbhh  = (const float*)d_in[28];
  const float* plng  = (const float*)d_in[29];
  const float* plnb  = (const float*)d_in[30];
  const float* poww  = (const float*)d_in[31];
  const float* pob   = (const float*)d_in[32];
  const float* als   = (const float*)d_in[33];

  float* out = (float*)d_out;
  double* wsd = (double*)d_ws;
  float* wsf = (float*)(wsd + D_TOTAL);             // fp32 region
  float* traj_hs = wsf + F_TOTAL;                   // [8][NTOT][32]
  float* gin     = traj_hs + (size_t)8*NTOT*32;     // [8][NSC][32][64]
  float* gh      = gin + (size_t)8*NTOT*32;         // [NTOT][32]

  k_prep<<<dim3(104), dim3(256), 0, stream>>>(
      pwhh, pwih, pbih, pbhh, plng, plnb, poww, pob,
      twih, twhh, tbih, tbhh, gwih, gwhh, gbih, gbhh, glng, glnb,
      gw0, gas0, gad0, gb0, gw1, gas1, gad1, gb1, wsd, wsf);
  k_traj<<<dim3(512), dim3(256), 0, stream>>>(obs, th0, tc0, wsd, traj_hs);
  k_gat<<<dim3(4096), dim3(256), 0, stream>>>(traj_hs, wsd, gin);
  k_graph<<<dim3(512), dim3(256), 0, stream>>>(gin, gh0, gc0, wsd, gh);
  k_pred<<<dim3(512), dim3(512), 0, stream>>>(traj_hs, gh, zn, obs, wsd, wsf, als, out);
}

// Round 9
// 1202.094 us; speedup vs baseline: 1.3955x; 1.0337x over previous
//
#include <hip/hip_runtime.h>
#include <math.h>

#define T_OBS 8
#define PRED_LEN 12
#define NSC 512
#define NPED 64
#define NTOT (NSC*NPED)
#define EPS 1e-5

typedef float f32x2 __attribute__((ext_vector_type(2)));
typedef float f32x4 __attribute__((ext_vector_type(4)));

// ---- ws double-region offsets (in doubles) ----
#define O_PWIH   25600    // pred wih [320][2]
#define O_PBD    26240    // pred bih+bhh+Cb [320]
#define O_PCW    26560    // Cw[r] [320]
#define O_PGW    26880    // gw0[80], gw1[80]
#define O_PSC    27040    // Cgw0, Cgw1, Cbw0+bout0, Cbw1+bout1
#define O_PINV   27048    // invg[80], b[80]
#define O_TWIH   27208    // traj wih [128][2]
#define O_TWHHT  27464    // traj whh^T [32 k][128 r]
#define O_TB     31560    // traj bih+bhh [128]
#define O_GWIHT  31688    // graph wih^T [32 k][128 r]
#define O_GW2    35784    // graph whh^T g-folded [32 k][128 r]
#define O_GBD    39880    // graph bih+bhh+gCb [128]
#define O_GCW    40008    // gCw[r] [128]
#define O_GLNG   40136
#define O_GLNB   40168
#define O_GINV   40200    // ginvg[32], gb[32]
#define O_W0     40264    // gat w0 [4][32][16]
#define O_A0S    42312
#define O_A0D    42376
#define O_B0     42440
#define O_W1     42456    // gat w1 [64][32]
#define O_A1S    44504
#define O_A1D    44536
#define O_B1     44568
#define D_TOTAL  44600
// float region (offsets in floats, from wsf = (float*)(wsd + D_TOTAL))
#define OF_PW2P  0        // pred whh^T g-folded fp32 PACKED [80 k][8 wv][40 j4]
#define OF_PBDF  25600    // fp32 bih+bhh+Cb [320]
#define OF_PCWF  25920    // fp32 Cw [320]
#define OF_PWIHF 26240    // fp32 wih [320][2]
#define F_TOTAL  26880

// dynamic-LDS byte size for k_pred:
// ps(4096) + pq(4096) + wlds(102400) + hd(20480) + pw0(2048) + pw1(2048)
#define PRED_LDS_BYTES 135168

// ---------- fast fp64 math (validated bit-identical absmax R3-R8) ----------
__device__ __forceinline__ double fast_exp(double x){
  x = fmin(fmax(x, -708.0), 708.0);
  const double L2E  = 1.4426950408889634074;
  const double LN2H = 6.93147180369123816490e-01;
  const double LN2L = 1.90821492927058770002e-10;
  double t = x*L2E;
  double n = rint(t);
  int ni = (int)n;
  double r = __builtin_fma(-n, LN2H, x);
  r = __builtin_fma(-n, LN2L, r);
  double p = 2.08767569878681e-09;
  p = __builtin_fma(p, r, 2.505210838544172e-08);
  p = __builtin_fma(p, r, 2.755731922398589e-07);
  p = __builtin_fma(p, r, 2.755731922398589e-06);
  p = __builtin_fma(p, r, 2.480158730158730e-05);
  p = __builtin_fma(p, r, 1.984126984126984e-04);
  p = __builtin_fma(p, r, 1.388888888888889e-03);
  p = __builtin_fma(p, r, 8.333333333333333e-03);
  p = __builtin_fma(p, r, 4.166666666666667e-02);
  p = __builtin_fma(p, r, 1.666666666666667e-01);
  p = __builtin_fma(p, r, 0.5);
  p = __builtin_fma(p, r, 1.0);
  p = __builtin_fma(p, r, 1.0);
  double s = __hiloint2double((ni + 1023) << 20, 0);
  return p*s;
}
__device__ __forceinline__ double fast_rcp(double d){
#if __has_builtin(__builtin_amdgcn_rcp)
  double r = __builtin_amdgcn_rcp(d);
#else
  double r = 1.0/d;
#endif
  double e = __builtin_fma(-d, r, 1.0); r = __builtin_fma(r, e, r);
  e = __builtin_fma(-d, r, 1.0); r = __builtin_fma(r, e, r);
  e = __builtin_fma(-d, r, 1.0); r = __builtin_fma(r, e, r);
  return r;
}
__device__ __forceinline__ double fast_rsqrt(double d){
#if __has_builtin(__builtin_amdgcn_rsq)
  double r = __builtin_amdgcn_rsq(d);
#else
  double r = 1.0/sqrt(d);
#endif
  double hr = 0.5*d;
  r = r*__builtin_fma(-hr*r, r, 1.5);
  r = r*__builtin_fma(-hr*r, r, 1.5);
  r = r*__builtin_fma(-hr*r, r, 1.5);
  return r;
}
__device__ __forceinline__ double fsig(double x){
  double xc = fmin(fmax(x, -40.0), 40.0);
  return fast_rcp(1.0 + fast_exp(-xc));
}
__device__ __forceinline__ double ftanh(double x){
  double xc = fmin(fmax(x, -20.0), 20.0);
  return __builtin_fma(-2.0, fast_rcp(1.0 + fast_exp(2.0*xc)), 1.0);
}
// ---------- fp32 fast gates (k_pred only) ----------
__device__ __forceinline__ float fsig32(float x){
  x = fminf(fmaxf(x, -30.f), 30.f);
  return 1.0f/(1.0f + __expf(-x));
}
__device__ __forceinline__ float ftanh32(float x){
  x = fminf(fmaxf(x, -15.f), 15.f);
  return 1.0f - 2.0f/(1.0f + __expf(2.f*x));
}
// packed dual-fp32 FMA (CDNA VOP3P): a += w*h elementwise on 2 lanes
__device__ __forceinline__ void pk_fma(f32x2 &a, f32x2 w, f32x2 h){
  asm("v_pk_fma_f32 %0, %1, %2, %0" : "+v"(a) : "v"(w), "v"(h));
}

// ---------------- prep ----------------
__global__ void k_prep(
    const float* __restrict__ pwhh, const float* __restrict__ pwih,
    const float* __restrict__ pbih, const float* __restrict__ pbhh,
    const float* __restrict__ plng, const float* __restrict__ plnb,
    const float* __restrict__ pwout, const float* __restrict__ pbout,
    const float* __restrict__ twih, const float* __restrict__ twhh,
    const float* __restrict__ tbih, const float* __restrict__ tbhh,
    const float* __restrict__ gwih, const float* __restrict__ gwhh,
    const float* __restrict__ gbih, const float* __restrict__ gbhh,
    const float* __restrict__ glng, const float* __restrict__ glnb,
    const float* __restrict__ w0, const float* __restrict__ a0s,
    const float* __restrict__ a0d, const float* __restrict__ b0,
    const float* __restrict__ w1, const float* __restrict__ a1s,
    const float* __restrict__ a1d, const float* __restrict__ b1,
    double* __restrict__ wsd, float* __restrict__ wsf)
{
  int i = blockIdx.x*256 + threadIdx.x;
  // pred packed fp32: w2p[(k*8+wv)*40 + j*4+g] = whh[g*80+wv*10+j][k] * g[k]
  if (i < 25600){
    int kk = i/320, rem = i - kk*320;
    int wv = rem/40, j4 = rem - wv*40;
    int j = j4>>2, g = j4&3;
    int r = g*80 + wv*10 + j;
    wsf[OF_PW2P + i] = (float)((double)pwhh[r*80 + kk] * (double)plng[kk]);
  }
  if (i < 640){
    wsd[O_PWIH + i] = (double)pwih[i];
    wsf[OF_PWIHF + i] = pwih[i];
  }
  if (i < 320){
    double s = 0, sb = 0;
    for (int k = 0; k < 80; ++k){
      double w = (double)pwhh[i*80 + k];
      s  += w*(double)plng[k];
      sb += w*(double)plnb[k];
    }
    wsd[O_PCW + i] = s;
    wsd[O_PBD + i] = (double)pbih[i] + (double)pbhh[i] + sb;
    wsf[OF_PCWF + i] = (float)s;
    wsf[OF_PBDF + i] = (float)((double)pbih[i] + (double)pbhh[i] + sb);
  }
  if (i < 160){
    if (i < 80) wsd[O_PGW + i] = (double)plng[i]*(double)pwout[i];
    else        wsd[O_PGW + i] = (double)plng[i-80]*(double)pwout[80 + (i-80)];
  }
  if (i < 4){
    double s = 0;
    if (i == 0){ for (int u = 0; u < 80; ++u) s += (double)plng[u]*(double)pwout[u]; }
    if (i == 1){ for (int u = 0; u < 80; ++u) s += (double)plng[u]*(double)pwout[80+u]; }
    if (i == 2){ for (int u = 0; u < 80; ++u) s += (double)plnb[u]*(double)pwout[u]; s += (double)pbout[0]; }
    if (i == 3){ for (int u = 0; u < 80; ++u) s += (double)plnb[u]*(double)pwout[80+u]; s += (double)pbout[1]; }
    wsd[O_PSC + i] = s;
  }
  if (i < 160){
    if (i < 80) wsd[O_PINV + i] = 1.0/(double)plng[i];
    else        wsd[O_PINV + i] = (double)plnb[i-80];
  }
  if (i < 256) wsd[O_TWIH + i] = (double)twih[i];
  if (i < 4096){
    int r = i>>5, k = i&31;
    wsd[O_TWHHT + k*128 + r] = (double)twhh[i];
    wsd[O_GWIHT + k*128 + r] = (double)gwih[i];
    wsd[O_GW2   + k*128 + r] = (double)gwhh[i]*(double)glng[k];
  }
  if (i < 128){
    wsd[O_TB + i] = (double)tbih[i] + (double)tbhh[i];
    double s = 0, sb = 0;
    for (int k = 0; k < 32; ++k){
      double w = (double)gwhh[i*32 + k];
      s  += w*(double)glng[k];
      sb += w*(double)glnb[k];
    }
    wsd[O_GCW + i] = s;
    wsd[O_GBD + i] = (double)gbih[i] + (double)gbhh[i] + sb;
  }
  if (i < 32){
    wsd[O_GLNG + i] = (double)glng[i]; wsd[O_GLNB + i] = (double)glnb[i];
    wsd[O_GINV + i] = 1.0/(double)glng[i];
    wsd[O_GINV + 32 + i] = (double)glnb[i];
    wsd[O_A1S + i] = (double)a1s[i]; wsd[O_A1D + i] = (double)a1d[i];
    wsd[O_B1 + i] = (double)b1[i];
  }
  if (i < 2048){ wsd[O_W0 + i] = (double)w0[i]; wsd[O_W1 + i] = (double)w1[i]; }
  if (i < 64){ wsd[O_A0S + i] = (double)a0s[i]; wsd[O_A0D + i] = (double)a0d[i]; }
  if (i < 16) wsd[O_B0 + i] = (double)b0[i];
}

// ---------------- K1: traj LSTM (unchanged from R8) ----------------
__global__ __launch_bounds__(256) void k_traj(
    const float* __restrict__ obs, const float* __restrict__ h0,
    const float* __restrict__ c0, const double* __restrict__ wsd,
    float* __restrict__ traj_hs)
{
  __shared__ double hdl[2][2048];
  const double* wih  = wsd + O_TWIH;
  const double* whhT = wsd + O_TWHHT;
  const double* bd   = wsd + O_TB;
  const int tid = threadIdx.x, lane = tid & 63;
  const int wv = __builtin_amdgcn_readfirstlane(tid >> 6);
  const int ub = wv*8;
  const int ped0 = blockIdx.x*64, ped = ped0 + lane;
  for (int idx = tid; idx < 2048; idx += 256){
    int f = idx>>6, p = idx&63;
    hdl[0][idx] = (double)h0[(ped0+p)*32 + f];
  }
  double c[8];
  #pragma unroll
  for (int j = 0; j < 8; ++j) c[j] = (double)c0[ped*32 + ub + j];
  __syncthreads();

  for (int t = 0; t < T_OBS; ++t){
    const int p = t & 1;
    double x0 = (double)obs[((size_t)t*NTOT + ped)*2 + 0];
    double x1 = (double)obs[((size_t)t*NTOT + ped)*2 + 1];
    double acc[32];
    #pragma unroll
    for (int j = 0; j < 8; ++j){
      #pragma unroll
      for (int g = 0; g < 4; ++g){
        int r = g*32 + ub + j;
        acc[j*4+g] = bd[r] + wih[r*2+0]*x0 + wih[r*2+1]*x1;
      }
    }
    for (int k = 0; k < 32; ++k){
      double hk = hdl[p][k*64 + lane];
      const double* wh = whhT + k*128;
      #pragma unroll
      for (int j = 0; j < 8; ++j){
        #pragma unroll
        for (int g = 0; g < 4; ++g) acc[j*4+g] += wh[g*32 + ub + j]*hk;
      }
    }
    #pragma unroll
    for (int j = 0; j < 8; ++j){
      double ig = fsig(acc[j*4+0]);
      double fg = fsig(acc[j*4+1]);
      double gg = ftanh(acc[j*4+2]);
      double og = fsig(acc[j*4+3]);
      c[j] = fg*c[j] + ig*gg;
      double hn = og*ftanh(c[j]);
      hdl[p^1][(ub+j)*64 + lane] = hn;
      traj_hs[((size_t)t*NTOT + ped)*32 + ub + j] = (float)hn;
    }
    __syncthreads();
  }
}

// ---------------- K2: GAT encoder (unchanged from R8) ----------------
__global__ __launch_bounds__(256) void k_gat(
    const float* __restrict__ ths, const double* __restrict__ wsd,
    float* __restrict__ gout)
{
  __shared__ float xA[64*65];
  __shared__ float hpB[64*68];
  __shared__ double as0[256], ad0[256];
  __shared__ double as1[64], ad1[64], mn[64], rs[64];
  __shared__ float zS[256];

  const double* w0  = wsd + O_W0;
  const double* a0s = wsd + O_A0S;
  const double* a0d = wsd + O_A0D;
  const double* b0  = wsd + O_B0;
  const double* w1  = wsd + O_W1;
  const double* a1s = wsd + O_A1S;
  const double* a1d = wsd + O_A1D;
  const double* b1  = wsd + O_B1;

  const int tid = threadIdx.x;
  const int sb = blockIdx.x >> 3, tb = blockIdx.x & 7;
  const int n = tid & 63;
  const int q = __builtin_amdgcn_readfirstlane(tid >> 6);

  const float* xin = ths + ((size_t)tb*NTOT + sb*64)*32;
  for (int idx = tid; idx < 2048; idx += 256)
    xA[(idx>>5)*65 + (idx&31)] = xin[idx];
  __syncthreads();
  if (tid < 32){
    double s1 = 0, s2 = 0;
    for (int p = 0; p < 64; ++p){ double v = xA[p*65+tid]; s1 += v; s2 += v*v; }
    double mu = s1*(1.0/64.0), va = s2*(1.0/64.0) - mu*mu;
    mn[tid] = mu; rs[tid] = fast_rsqrt(va + EPS);
  }
  __syncthreads();
  for (int idx = tid; idx < 2048; idx += 256){
    int p = idx>>5, f = idx&31;
    xA[p*65+f] = (float)(((double)xA[p*65+f] - mn[f])*rs[f]);
  }
  __syncthreads();
  { // hp0 (fp64) + attn dots (fp64), store hp0 fp32
    double acc[16];
    #pragma unroll
    for (int o = 0; o < 16; ++o) acc[o] = 0;
    for (int f = 0; f < 32; ++f){
      double xv = (double)xA[n*65+f];
      const double* wr = w0 + (q*32+f)*16;
      #pragma unroll
      for (int o = 0; o < 16; ++o) acc[o] += xv*wr[o];
    }
    double sa = 0, sd = 0;
    #pragma unroll
    for (int o = 0; o < 16; ++o){
      sa += acc[o]*a0s[q*16+o];
      sd += acc[o]*a0d[q*16+o];
      hpB[n*68 + q*16 + o] = (float)acc[o];
    }
    as0[q*64+n] = sa; ad0[q*64+n] = sd;
  }
  __syncthreads();
  { // attn L0: fp32 exp (const shift cancels), fp32 aggregate, ELU fp32
    float arow = (float)as0[q*64+n];
    float num[16];
    #pragma unroll
    for (int o = 0; o < 16; ++o) num[o] = 0.f;
    float Z = 0.f;
    for (int m2 = 0; m2 < 64; ++m2){
      float e = arow + (float)ad0[q*64+m2];
      float lr = e > 0.f ? e : 0.2f*e;
      float pv = __expf(lr - 30.0f);
      Z += pv;
      const float4* h4 = (const float4*)&hpB[m2*68 + q*16];
      #pragma unroll
      for (int o4 = 0; o4 < 4; ++o4){
        float4 v = h4[o4];
        num[o4*4+0] += pv*v.x; num[o4*4+1] += pv*v.y;
        num[o4*4+2] += pv*v.z; num[o4*4+3] += pv*v.w;
      }
    }
    float iZ = 1.0f/Z;
    #pragma unroll
    for (int o = 0; o < 16; ++o){
      float y = num[o]*iZ + (float)b0[o];
      xA[n*65 + q*16 + o] = y > 0.f ? y : __expf(y)-1.0f;
    }
  }
  __syncthreads();
  if (tid < 64){
    double s1 = 0, s2 = 0;
    for (int p = 0; p < 64; ++p){ double v = xA[p*65+tid]; s1 += v; s2 += v*v; }
    double mu = s1*(1.0/64.0), va = s2*(1.0/64.0) - mu*mu;
    mn[tid] = mu; rs[tid] = fast_rsqrt(va + EPS);
  }
  __syncthreads();
  for (int idx = tid; idx < 4096; idx += 256){
    int p = idx>>6, f = idx&63;
    xA[p*65+f] = (float)(((double)xA[p*65+f] - mn[f])*rs[f]);
  }
  __syncthreads();
  { // hp1 (fp64 compute, fp32 store)
    double a8[8];
    #pragma unroll
    for (int j = 0; j < 8; ++j) a8[j] = 0;
    for (int f = 0; f < 64; ++f){
      double xv = (double)xA[n*65+f];
      const double* wr = w1 + f*32 + q*8;
      #pragma unroll
      for (int j = 0; j < 8; ++j) a8[j] += xv*wr[j];
    }
    #pragma unroll
    for (int j = 0; j < 8; ++j) hpB[n*68 + q*8 + j] = (float)a8[j];
  }
  __syncthreads();
  { // as1/ad1 partials
    double sa = 0, sd = 0;
    #pragma unroll
    for (int o = 0; o < 8; ++o){
      double v = (double)hpB[n*68 + q*8 + o];
      sa += v*a1s[q*8+o]; sd += v*a1d[q*8+o];
    }
    as0[q*64+n] = sa; ad0[q*64+n] = sd;
  }
  __syncthreads();
  if (tid < 128){
    int n2 = tid & 63;
    if (tid < 64) as1[n2] = as0[n2]+as0[64+n2]+as0[128+n2]+as0[192+n2];
    else          ad1[n2] = ad0[n2]+ad0[64+n2]+ad0[128+n2]+ad0[192+n2];
  }
  __syncthreads();
  { // L1 softmax probs fp32
    float arow = (float)as1[n];
    float zp = 0.f;
    for (int m2 = q*16; m2 < q*16+16; ++m2){
      float e = arow + (float)ad1[m2];
      float lr = e > 0.f ? e : 0.2f*e;
      float pv = __expf(lr - 30.0f);
      zp += pv;
      xA[n*65+m2] = pv;
    }
    zS[q*64+n] = zp;
  }
  __syncthreads();
  { // aggregate L1 fp32, write gin as [t][scene][f][ped]
    float Z = zS[n]+zS[64+n]+zS[128+n]+zS[192+n];
    float iZ = 1.0f/Z;
    float a8[8];
    #pragma unroll
    for (int j = 0; j < 8; ++j) a8[j] = 0.f;
    for (int m2 = 0; m2 < 64; ++m2){
      float av = xA[n*65+m2];
      const float4* h4 = (const float4*)&hpB[m2*68 + q*8];
      float4 v0 = h4[0], v1 = h4[1];
      a8[0] += av*v0.x; a8[1] += av*v0.y; a8[2] += av*v0.z; a8[3] += av*v0.w;
      a8[4] += av*v1.x; a8[5] += av*v1.y; a8[6] += av*v1.z; a8[7] += av*v1.w;
    }
    float* go = gout + ((size_t)(tb*NSC + sb)*32)*64;
    #pragma unroll
    for (int j = 0; j < 8; ++j)
      go[(q*8+j)*64 + n] = a8[j]*iZ + (float)b1[q*8+j];
  }
}

// ---------------- K3: graph LSTM + folded LN (unchanged from R8) ----------------
__global__ __launch_bounds__(256) void k_graph(
    const float* __restrict__ gin, const float* __restrict__ h0,
    const float* __restrict__ c0, const double* __restrict__ wsd,
    float* __restrict__ gh)
{
  __shared__ double hdl[2][2048];
  __shared__ double xld[2][2048];
  __shared__ double ps[256], pq[256];
  const double* wihT = wsd + O_GWIHT;
  const double* w2   = wsd + O_GW2;
  const double* bdp  = wsd + O_GBD;
  const double* gCw  = wsd + O_GCW;
  const double* lng  = wsd + O_GLNG;
  const double* lnb  = wsd + O_GLNB;
  const double* ginv = wsd + O_GINV;
  const int tid = threadIdx.x, lane = tid & 63;
  const int wv = __builtin_amdgcn_readfirstlane(tid >> 6);
  const int ub = wv*8;
  const int sb = blockIdx.x, ped0 = sb*64, ped = ped0 + lane;
  for (int idx = tid; idx < 2048; idx += 256){
    int f = idx>>6, p = idx&63;
    hdl[0][idx] = ((double)h0[(ped0+p)*32 + f] - ginv[32+f]) * ginv[f];
  }
  {
    const float* gb0p = gin + (size_t)(0*NSC + sb)*2048;
    for (int idx = tid; idx < 2048; idx += 256) xld[0][idx] = (double)gb0p[idx];
  }
  double c[8];
  #pragma unroll
  for (int j = 0; j < 8; ++j) c[j] = (double)c0[ped*32 + ub + j];
  double mu = 0.0, ri = 1.0;
  __syncthreads();

  for (int t = 0; t < T_OBS; ++t){
    const int p = t & 1;
    if (t < T_OBS-1){
      const float* gbn = gin + (size_t)((t+1)*NSC + sb)*2048;
      for (int idx = tid; idx < 2048; idx += 256) xld[p^1][idx] = (double)gbn[idx];
    }
    double accX[32], accH[32];
    #pragma unroll
    for (int j4 = 0; j4 < 32; ++j4){ accX[j4] = 0; accH[j4] = 0; }
    for (int k = 0; k < 32; ++k){
      double xk = xld[p][k*64 + lane];
      double hk = hdl[p][k*64 + lane];
      const double* wi = wihT + k*128;
      const double* wh = w2   + k*128;
      #pragma unroll
      for (int j = 0; j < 8; ++j){
        #pragma unroll
        for (int g = 0; g < 4; ++g){
          accX[j*4+g] += wi[g*32 + ub + j]*xk;
          accH[j*4+g] += wh[g*32 + ub + j]*hk;
        }
      }
    }
    double hp[8]; double s1 = 0, s2 = 0;
    #pragma unroll
    for (int j = 0; j < 8; ++j){
      double pre[4];
      #pragma unroll
      for (int g = 0; g < 4; ++g){
        int r = g*32 + ub + j;
        pre[g] = bdp[r] + accX[j*4+g] + ri*__builtin_fma(-mu, gCw[r], accH[j*4+g]);
      }
      double ig = fsig(pre[0]);
      double fg = fsig(pre[1]);
      double gg = ftanh(pre[2]);
      double og = fsig(pre[3]);
      c[j] = fg*c[j] + ig*gg;
      hp[j] = og*ftanh(c[j]);
      s1 += hp[j]; s2 += hp[j]*hp[j];
      hdl[p^1][(ub+j)*64 + lane] = hp[j];
    }
    ps[wv*64+lane] = s1; pq[wv*64+lane] = s2;
    __syncthreads();
    double sa = ps[lane]+ps[64+lane]+ps[128+lane]+ps[192+lane];
    double sq = pq[lane]+pq[64+lane]+pq[128+lane]+pq[192+lane];
    mu = sa*(1.0/32.0);
    double va = sq*(1.0/32.0) - mu*mu;
    ri = fast_rsqrt(va + EPS);
    if (t == T_OBS-1){
      #pragma unroll
      for (int j = 0; j < 8; ++j){
        int u = ub + j;
        gh[ped*32 + u] = (float)((hp[j]-mu)*ri*lng[u] + lnb[u]);
      }
    }
  }
}

// ---------------- K4: pred LSTM — persistent-LDS weights, 2 barriers/step ----------------
__global__ __launch_bounds__(512) void k_pred(
    const float* __restrict__ traj_hs, const float* __restrict__ gh,
    const float* __restrict__ zn, const float* __restrict__ obs,
    const double* __restrict__ wsd, const float* __restrict__ wsf,
    const float* __restrict__ als, float* __restrict__ out)
{
  extern __shared__ char smem[];
  double* ps   = (double*)smem;          // [512]
  double* pq   = ps + 512;               // [512]
  float*  wlds = (float*)(pq + 512);     // [25600] persistent weights
  float*  hd   = wlds + 25600;           // [5120] h (pre-LN rep)
  float*  pw0  = hd + 5120;              // [512]
  float*  pw1  = pw0 + 512;              // [512]

  const float*  w2p  = wsf + OF_PW2P;
  const float*  bdf  = wsf + OF_PBDF;
  const float*  cwf  = wsf + OF_PCWF;
  const float*  wihf = wsf + OF_PWIHF;
  const double* gw   = wsd + O_PGW;
  const double* psc  = wsd + O_PSC;
  const double* pinv = wsd + O_PINV;
  const int tid = threadIdx.x, lane = tid & 63;
  const int wv = __builtin_amdgcn_readfirstlane(tid >> 6);
  const int ub = wv*10;
  const int scene = blockIdx.x, ped0 = scene*64, ped = ped0 + lane;

  // stage ALL weights into LDS once (step-invariant)
  for (int i = tid; i < 25600; i += 512) wlds[i] = w2p[i];
  for (int idx = tid; idx < 5120; idx += 512){
    int f = idx>>6, p = idx&63;
    float v;
    if (f < 32)      v = traj_hs[((size_t)7*NTOT + ped0 + p)*32 + f];
    else if (f < 64) v = gh[(ped0+p)*32 + (f-32)];
    else             v = zn[scene*16 + (f-64)];
    hd[idx] = (float)(((double)v - pinv[80+f]) * pinv[f]);
  }
  // constant log_std / std outputs (independent of the loop)
  {
    const int M = PRED_LEN*NTOT*2;
    float l0 = als[0], l1 = als[1];
    float e0 = (float)fast_exp((double)l0), e1 = (float)fast_exp((double)l1);
    for (int i = tid; i < PRED_LEN*64*2; i += 512){
      int t = i >> 7; int rem = i & 127; int p2 = rem >> 1; int ch = rem & 1;
      int gi = (t*NTOT + ped0 + p2)*2 + ch;
      out[M + gi]   = ch ? l1 : l0;
      out[2*M + gi] = ch ? e1 : e0;
    }
  }
  double c[10];
  #pragma unroll
  for (int j = 0; j < 10; ++j) c[j] = 0.0;
  double x0 = (double)obs[((size_t)7*NTOT + ped)*2 + 0];
  double x1 = (double)obs[((size_t)7*NTOT + ped)*2 + 1];
  double mu = 0.0, ri = 1.0, invri = 1.0;
  const double Cgw0 = psc[0], Cgw1 = psc[1], Cbw0 = psc[2], Cbw1 = psc[3];
  float gwf0[10], gwf1[10];
  #pragma unroll
  for (int j = 0; j < 10; ++j){ gwf0[j] = (float)gw[ub+j]; gwf1[j] = (float)gw[80+ub+j]; }
  __syncthreads();                 // weights + hd visible

  for (int t = 0; t < PRED_LEN; ++t){
    // fp32 gate-init, scaled by invri so final pre = ri*acc
    float x0f = (float)x0, x1f = (float)x1;
    float muf = (float)mu, invrif = (float)invri;
    f32x2 acc2[20];
    #pragma unroll
    for (int j = 0; j < 10; ++j){
      #pragma unroll
      for (int g = 0; g < 4; ++g){
        int r = g*80 + ub + j;
        float base = fmaf(wihf[r*2+1], x1f, fmaf(wihf[r*2+0], x0f, bdf[r]));
        float val = fmaf(base, invrif, -muf*cwf[r]);
        int idx = j*4+g;
        acc2[idx>>1][idx&1] = val;
      }
    }
    // pure GEMV from persistent LDS: no barriers, no staging
    #pragma unroll 4
    for (int k = 0; k < 80; ++k){
      float hk = hd[k*64 + lane];
      f32x2 h2; h2[0] = hk; h2[1] = hk;
      const f32x4* w4 = (const f32x4*)&wlds[k*320 + ub*4];
      #pragma unroll
      for (int q4 = 0; q4 < 10; ++q4){
        f32x4 w = w4[q4];
        f32x2 wlo; wlo[0] = w[0]; wlo[1] = w[1];
        f32x2 whi; whi[0] = w[2]; whi[1] = w[3];
        pk_fma(acc2[q4*2+0], wlo, h2);
        pk_fma(acc2[q4*2+1], whi, h2);
      }
    }
    // gates (fp32) + fp64 c-state
    float rif = (float)ri;
    float hp32[10]; double s1 = 0, s2 = 0; float sw0 = 0.f, sw1 = 0.f;
    #pragma unroll
    for (int j = 0; j < 10; ++j){
      float pg0 = acc2[(j*4+0)>>1][(j*4+0)&1];
      float pg1 = acc2[(j*4+1)>>1][(j*4+1)&1];
      float pg2 = acc2[(j*4+2)>>1][(j*4+2)&1];
      float pg3 = acc2[(j*4+3)>>1][(j*4+3)&1];
      float ig = fsig32(rif*pg0);
      float fg = fsig32(rif*pg1);
      float gg = ftanh32(rif*pg2);
      float og = fsig32(rif*pg3);
      c[j] = (double)fg*c[j] + (double)(ig*gg);
      float h32 = og*ftanh32((float)c[j]);
      hp32[j] = h32;
      s1 += (double)h32; s2 += (double)(h32*h32);
      sw0 += h32*gwf0[j]; sw1 += h32*gwf1[j];
    }
    __syncthreads();               // all GEMV reads of hd done
    #pragma unroll
    for (int j = 0; j < 10; ++j) hd[(ub+j)*64 + lane] = hp32[j];
    ps[wv*64+lane] = s1; pq[wv*64+lane] = s2;
    pw0[wv*64+lane] = sw0; pw1[wv*64+lane] = sw1;
    __syncthreads();               // writes visible
    double sa = 0, sq = 0, t0 = 0, t1 = 0;
    #pragma unroll
    for (int w = 0; w < 8; ++w){
      sa += ps[w*64+lane]; sq += pq[w*64+lane];
      t0 += (double)pw0[w*64+lane]; t1 += (double)pw1[w*64+lane];
    }
    mu = sa*(1.0/80.0);
    double va = sq*(1.0/80.0) - mu*mu;
    ri = fast_rsqrt(va + EPS);
    invri = (va + EPS)*ri;         // = 1/ri
    x0 = ri*__builtin_fma(-mu, Cgw0, t0) + Cbw0;
    x1 = ri*__builtin_fma(-mu, Cgw1, t1) + Cbw1;
    if (wv == 0){
      out[((size_t)t*NTOT + ped)*2 + 0] = (float)x0;
      out[((size_t)t*NTOT + ped)*2 + 1] = (float)x1;
    }
  }
}

extern "C" void kernel_launch(void* const* d_in, const int* in_sizes, int n_in,
                              void* d_out, int out_size, void* d_ws, size_t ws_size,
                              hipStream_t stream)
{
  const float* obs   = (const float*)d_in[0];
  const float* zn    = (const float*)d_in[2];
  const float* th0   = (const float*)d_in[3];
  const float* tc0   = (const float*)d_in[4];
  const float* gh0   = (const float*)d_in[5];
  const float* gc0   = (const float*)d_in[6];
  const float* gw0   = (const float*)d_in[7];
  const float* gas0  = (const float*)d_in[8];
  const float* gad0  = (const float*)d_in[9];
  const float* gb0   = (const float*)d_in[10];
  const float* gw1   = (const float*)d_in[11];
  const float* gas1  = (const float*)d_in[12];
  const float* gad1  = (const float*)d_in[13];
  const float* gb1   = (const float*)d_in[14];
  const float* twih  = (const float*)d_in[15];
  const float* twhh  = (const float*)d_in[16];
  const float* tbih  = (const float*)d_in[17];
  const float* tbhh  = (const float*)d_in[18];
  const float* gwih  = (const float*)d_in[19];
  const float* gwhh  = (const float*)d_in[20];
  const float* gbih  = (const float*)d_in[21];
  const float* gbhh  = (const float*)d_in[22];
  const float* glng  = (const float*)d_in[23];
  const float* glnb  = (const float*)d_in[24];
  const float* pwih  = (const float*)d_in[25];
  const float* pwhh  = (const float*)d_in[26];
  const float* pbih  = (const float*)d_in[27];
  const float* pbhh  = (const float*)d_in[28];
  const float* plng  = (const float*)d_in[29];
  const float* plnb  = (const float*)d_in[30];
  const float* poww  = (const float*)d_in[31];
  const float* pob   = (const float*)d_in[32];
  const float* als   = (const float*)d_in[33];

  float* out = (float*)d_out;
  double* wsd = (double*)d_ws;
  float* wsf = (float*)(wsd + D_TOTAL);             // fp32 region
  float* traj_hs = wsf + F_TOTAL;                   // [8][NTOT][32]
  float* gin     = traj_hs + (size_t)8*NTOT*32;     // [8][NSC][32][64]
  float* gh      = gin + (size_t)8*NTOT*32;         // [NTOT][32]

  // allow >64KB dynamic LDS for k_pred (host-side attribute, graph-capture safe)
  (void)hipFuncSetAttribute((const void*)k_pred,
                            hipFuncAttributeMaxDynamicSharedMemorySize,
                            PRED_LDS_BYTES);

  k_prep<<<dim3(104), dim3(256), 0, stream>>>(
      pwhh, pwih, pbih, pbhh, plng, plnb, poww, pob,
      twih, twhh, tbih, tbhh, gwih, gwhh, gbih, gbhh, glng, glnb,
      gw0, gas0, gad0, gb0, gw1, gas1, gad1, gb1, wsd, wsf);
  k_traj<<<dim3(512), dim3(256), 0, stream>>>(obs, th0, tc0, wsd, traj_hs);
  k_gat<<<dim3(4096), dim3(256), 0, stream>>>(traj_hs, wsd, gin);
  k_graph<<<dim3(512), dim3(256), 0, stream>>>(gin, gh0, gc0, wsd, gh);
  k_pred<<<dim3(512), dim3(512), PRED_LDS_BYTES, stream>>>(traj_hs, gh, zn, obs, wsd, wsf, als, out);
}

// Round 10
// 938.241 us; speedup vs baseline: 1.7879x; 1.2812x over previous
//
#include <hip/hip_runtime.h>
#include <math.h>

#define T_OBS 8
#define PRED_LEN 12
#define NSC 512
#define NPED 64
#define NTOT (NSC*NPED)
#define EPS 1e-5

typedef float f32x2 __attribute__((ext_vector_type(2)));
typedef float f32x4 __attribute__((ext_vector_type(4)));

// ---- ws double-region offsets (in doubles) ----
#define O_PWIH   25600    // pred wih [320][2]
#define O_PBD    26240    // pred bih+bhh+Cb [320]
#define O_PCW    26560    // Cw[r] [320]
#define O_PGW    26880    // gw0[80], gw1[80]
#define O_PSC    27040    // Cgw0, Cgw1, Cbw0+bout0, Cbw1+bout1
#define O_PINV   27048    // invg[80], b[80]
#define O_TWIH   27208    // traj wih [128][2]
#define O_TWHHT  27464    // traj whh^T [32 k][128 r]
#define O_TB     31560    // traj bih+bhh [128]
#define O_GWIHT  31688    // graph wih^T [32 k][128 r]
#define O_GW2    35784    // graph whh^T g-folded [32 k][128 r]
#define O_GBD    39880    // graph bih+bhh+gCb [128]
#define O_GCW    40008    // gCw[r] [128]
#define O_GLNG   40136
#define O_GLNB   40168
#define O_GINV   40200    // ginvg[32], gb[32]
#define O_W0     40264    // gat w0 [4][32][16]
#define O_A0S    42312
#define O_A0D    42376
#define O_B0     42440
#define O_W1     42456    // gat w1 [64][32]
#define O_A1S    44504
#define O_A1D    44536
#define O_B1     44568
#define D_TOTAL  44600
// float region (offsets in floats, from wsf = (float*)(wsd + D_TOTAL))
#define OF_PW2P  0        // pred whh^T g-folded fp32 PACKED [80 k][8 wv][40 j4]
#define OF_PBDF  25600    // fp32 bih+bhh+Cb [320]
#define OF_PCWF  25920    // fp32 Cw [320]
#define OF_PWIHF 26240    // fp32 wih [320][2]
#define F_TOTAL  26880

// dynamic-LDS for k_pred (2 scenes/block):
// wlds 25600f + hd 10240f + ps/pq/pw0/pw1 1024f each = 39936 floats = 159744 B
#define PRED_LDS_BYTES 159744

// ---------- fast fp64 math (validated bit-identical absmax R3-R9) ----------
__device__ __forceinline__ double fast_exp(double x){
  x = fmin(fmax(x, -708.0), 708.0);
  const double L2E  = 1.4426950408889634074;
  const double LN2H = 6.93147180369123816490e-01;
  const double LN2L = 1.90821492927058770002e-10;
  double t = x*L2E;
  double n = rint(t);
  int ni = (int)n;
  double r = __builtin_fma(-n, LN2H, x);
  r = __builtin_fma(-n, LN2L, r);
  double p = 2.08767569878681e-09;
  p = __builtin_fma(p, r, 2.505210838544172e-08);
  p = __builtin_fma(p, r, 2.755731922398589e-07);
  p = __builtin_fma(p, r, 2.755731922398589e-06);
  p = __builtin_fma(p, r, 2.480158730158730e-05);
  p = __builtin_fma(p, r, 1.984126984126984e-04);
  p = __builtin_fma(p, r, 1.388888888888889e-03);
  p = __builtin_fma(p, r, 8.333333333333333e-03);
  p = __builtin_fma(p, r, 4.166666666666667e-02);
  p = __builtin_fma(p, r, 1.666666666666667e-01);
  p = __builtin_fma(p, r, 0.5);
  p = __builtin_fma(p, r, 1.0);
  p = __builtin_fma(p, r, 1.0);
  double s = __hiloint2double((ni + 1023) << 20, 0);
  return p*s;
}
__device__ __forceinline__ double fast_rcp(double d){
#if __has_builtin(__builtin_amdgcn_rcp)
  double r = __builtin_amdgcn_rcp(d);
#else
  double r = 1.0/d;
#endif
  double e = __builtin_fma(-d, r, 1.0); r = __builtin_fma(r, e, r);
  e = __builtin_fma(-d, r, 1.0); r = __builtin_fma(r, e, r);
  e = __builtin_fma(-d, r, 1.0); r = __builtin_fma(r, e, r);
  return r;
}
__device__ __forceinline__ double fast_rsqrt(double d){
#if __has_builtin(__builtin_amdgcn_rsq)
  double r = __builtin_amdgcn_rsq(d);
#else
  double r = 1.0/sqrt(d);
#endif
  double hr = 0.5*d;
  r = r*__builtin_fma(-hr*r, r, 1.5);
  r = r*__builtin_fma(-hr*r, r, 1.5);
  r = r*__builtin_fma(-hr*r, r, 1.5);
  return r;
}
__device__ __forceinline__ double fsig(double x){
  double xc = fmin(fmax(x, -40.0), 40.0);
  return fast_rcp(1.0 + fast_exp(-xc));
}
__device__ __forceinline__ double ftanh(double x){
  double xc = fmin(fmax(x, -20.0), 20.0);
  return __builtin_fma(-2.0, fast_rcp(1.0 + fast_exp(2.0*xc)), 1.0);
}
// ---------- fp32 fast gates (k_pred only) ----------
__device__ __forceinline__ float fsig32(float x){
  x = fminf(fmaxf(x, -30.f), 30.f);
  return 1.0f/(1.0f + __expf(-x));
}
__device__ __forceinline__ float ftanh32(float x){
  x = fminf(fmaxf(x, -15.f), 15.f);
  return 1.0f - 2.0f/(1.0f + __expf(2.f*x));
}
// packed dual-fp32 FMA (CDNA VOP3P)
__device__ __forceinline__ void pk_fma(f32x2 &a, f32x2 w, f32x2 h){
  asm("v_pk_fma_f32 %0, %1, %2, %0" : "+v"(a) : "v"(w), "v"(h));
}

// ---------------- prep (unchanged from R9) ----------------
__global__ void k_prep(
    const float* __restrict__ pwhh, const float* __restrict__ pwih,
    const float* __restrict__ pbih, const float* __restrict__ pbhh,
    const float* __restrict__ plng, const float* __restrict__ plnb,
    const float* __restrict__ pwout, const float* __restrict__ pbout,
    const float* __restrict__ twih, const float* __restrict__ twhh,
    const float* __restrict__ tbih, const float* __restrict__ tbhh,
    const float* __restrict__ gwih, const float* __restrict__ gwhh,
    const float* __restrict__ gbih, const float* __restrict__ gbhh,
    const float* __restrict__ glng, const float* __restrict__ glnb,
    const float* __restrict__ w0, const float* __restrict__ a0s,
    const float* __restrict__ a0d, const float* __restrict__ b0,
    const float* __restrict__ w1, const float* __restrict__ a1s,
    const float* __restrict__ a1d, const float* __restrict__ b1,
    double* __restrict__ wsd, float* __restrict__ wsf)
{
  int i = blockIdx.x*256 + threadIdx.x;
  if (i < 25600){
    int kk = i/320, rem = i - kk*320;
    int wv = rem/40, j4 = rem - wv*40;
    int j = j4>>2, g = j4&3;
    int r = g*80 + wv*10 + j;
    wsf[OF_PW2P + i] = (float)((double)pwhh[r*80 + kk] * (double)plng[kk]);
  }
  if (i < 640){
    wsd[O_PWIH + i] = (double)pwih[i];
    wsf[OF_PWIHF + i] = pwih[i];
  }
  if (i < 320){
    double s = 0, sb = 0;
    for (int k = 0; k < 80; ++k){
      double w = (double)pwhh[i*80 + k];
      s  += w*(double)plng[k];
      sb += w*(double)plnb[k];
    }
    wsd[O_PCW + i] = s;
    wsd[O_PBD + i] = (double)pbih[i] + (double)pbhh[i] + sb;
    wsf[OF_PCWF + i] = (float)s;
    wsf[OF_PBDF + i] = (float)((double)pbih[i] + (double)pbhh[i] + sb);
  }
  if (i < 160){
    if (i < 80) wsd[O_PGW + i] = (double)plng[i]*(double)pwout[i];
    else        wsd[O_PGW + i] = (double)plng[i-80]*(double)pwout[80 + (i-80)];
  }
  if (i < 4){
    double s = 0;
    if (i == 0){ for (int u = 0; u < 80; ++u) s += (double)plng[u]*(double)pwout[u]; }
    if (i == 1){ for (int u = 0; u < 80; ++u) s += (double)plng[u]*(double)pwout[80+u]; }
    if (i == 2){ for (int u = 0; u < 80; ++u) s += (double)plnb[u]*(double)pwout[u]; s += (double)pbout[0]; }
    if (i == 3){ for (int u = 0; u < 80; ++u) s += (double)plnb[u]*(double)pwout[80+u]; s += (double)pbout[1]; }
    wsd[O_PSC + i] = s;
  }
  if (i < 160){
    if (i < 80) wsd[O_PINV + i] = 1.0/(double)plng[i];
    else        wsd[O_PINV + i] = (double)plnb[i-80];
  }
  if (i < 256) wsd[O_TWIH + i] = (double)twih[i];
  if (i < 4096){
    int r = i>>5, k = i&31;
    wsd[O_TWHHT + k*128 + r] = (double)twhh[i];
    wsd[O_GWIHT + k*128 + r] = (double)gwih[i];
    wsd[O_GW2   + k*128 + r] = (double)gwhh[i]*(double)glng[k];
  }
  if (i < 128){
    wsd[O_TB + i] = (double)tbih[i] + (double)tbhh[i];
    double s = 0, sb = 0;
    for (int k = 0; k < 32; ++k){
      double w = (double)gwhh[i*32 + k];
      s  += w*(double)glng[k];
      sb += w*(double)glnb[k];
    }
    wsd[O_GCW + i] = s;
    wsd[O_GBD + i] = (double)gbih[i] + (double)gbhh[i] + sb;
  }
  if (i < 32){
    wsd[O_GLNG + i] = (double)glng[i]; wsd[O_GLNB + i] = (double)glnb[i];
    wsd[O_GINV + i] = 1.0/(double)glng[i];
    wsd[O_GINV + 32 + i] = (double)glnb[i];
    wsd[O_A1S + i] = (double)a1s[i]; wsd[O_A1D + i] = (double)a1d[i];
    wsd[O_B1 + i] = (double)b1[i];
  }
  if (i < 2048){ wsd[O_W0 + i] = (double)w0[i]; wsd[O_W1 + i] = (double)w1[i]; }
  if (i < 64){ wsd[O_A0S + i] = (double)a0s[i]; wsd[O_A0D + i] = (double)a0d[i]; }
  if (i < 16) wsd[O_B0 + i] = (double)b0[i];
}

// ---------------- K1: traj LSTM (unchanged from R9) ----------------
__global__ __launch_bounds__(256) void k_traj(
    const float* __restrict__ obs, const float* __restrict__ h0,
    const float* __restrict__ c0, const double* __restrict__ wsd,
    float* __restrict__ traj_hs)
{
  __shared__ double hdl[2][2048];
  const double* wih  = wsd + O_TWIH;
  const double* whhT = wsd + O_TWHHT;
  const double* bd   = wsd + O_TB;
  const int tid = threadIdx.x, lane = tid & 63;
  const int wv = __builtin_amdgcn_readfirstlane(tid >> 6);
  const int ub = wv*8;
  const int ped0 = blockIdx.x*64, ped = ped0 + lane;
  for (int idx = tid; idx < 2048; idx += 256){
    int f = idx>>6, p = idx&63;
    hdl[0][idx] = (double)h0[(ped0+p)*32 + f];
  }
  double c[8];
  #pragma unroll
  for (int j = 0; j < 8; ++j) c[j] = (double)c0[ped*32 + ub + j];
  __syncthreads();

  for (int t = 0; t < T_OBS; ++t){
    const int p = t & 1;
    double x0 = (double)obs[((size_t)t*NTOT + ped)*2 + 0];
    double x1 = (double)obs[((size_t)t*NTOT + ped)*2 + 1];
    double acc[32];
    #pragma unroll
    for (int j = 0; j < 8; ++j){
      #pragma unroll
      for (int g = 0; g < 4; ++g){
        int r = g*32 + ub + j;
        acc[j*4+g] = bd[r] + wih[r*2+0]*x0 + wih[r*2+1]*x1;
      }
    }
    for (int k = 0; k < 32; ++k){
      double hk = hdl[p][k*64 + lane];
      const double* wh = whhT + k*128;
      #pragma unroll
      for (int j = 0; j < 8; ++j){
        #pragma unroll
        for (int g = 0; g < 4; ++g) acc[j*4+g] += wh[g*32 + ub + j]*hk;
      }
    }
    #pragma unroll
    for (int j = 0; j < 8; ++j){
      double ig = fsig(acc[j*4+0]);
      double fg = fsig(acc[j*4+1]);
      double gg = ftanh(acc[j*4+2]);
      double og = fsig(acc[j*4+3]);
      c[j] = fg*c[j] + ig*gg;
      double hn = og*ftanh(c[j]);
      hdl[p^1][(ub+j)*64 + lane] = hn;
      traj_hs[((size_t)t*NTOT + ped)*32 + ub + j] = (float)hn;
    }
    __syncthreads();
  }
}

// ---------------- K2: GAT encoder (unchanged from R9) ----------------
__global__ __launch_bounds__(256) void k_gat(
    const float* __restrict__ ths, const double* __restrict__ wsd,
    float* __restrict__ gout)
{
  __shared__ float xA[64*65];
  __shared__ float hpB[64*68];
  __shared__ double as0[256], ad0[256];
  __shared__ double as1[64], ad1[64], mn[64], rs[64];
  __shared__ float zS[256];

  const double* w0  = wsd + O_W0;
  const double* a0s = wsd + O_A0S;
  const double* a0d = wsd + O_A0D;
  const double* b0  = wsd + O_B0;
  const double* w1  = wsd + O_W1;
  const double* a1s = wsd + O_A1S;
  const double* a1d = wsd + O_A1D;
  const double* b1  = wsd + O_B1;

  const int tid = threadIdx.x;
  const int sb = blockIdx.x >> 3, tb = blockIdx.x & 7;
  const int n = tid & 63;
  const int q = __builtin_amdgcn_readfirstlane(tid >> 6);

  const float* xin = ths + ((size_t)tb*NTOT + sb*64)*32;
  for (int idx = tid; idx < 2048; idx += 256)
    xA[(idx>>5)*65 + (idx&31)] = xin[idx];
  __syncthreads();
  if (tid < 32){
    double s1 = 0, s2 = 0;
    for (int p = 0; p < 64; ++p){ double v = xA[p*65+tid]; s1 += v; s2 += v*v; }
    double mu = s1*(1.0/64.0), va = s2*(1.0/64.0) - mu*mu;
    mn[tid] = mu; rs[tid] = fast_rsqrt(va + EPS);
  }
  __syncthreads();
  for (int idx = tid; idx < 2048; idx += 256){
    int p = idx>>5, f = idx&31;
    xA[p*65+f] = (float)(((double)xA[p*65+f] - mn[f])*rs[f]);
  }
  __syncthreads();
  { // hp0 (fp64) + attn dots (fp64), store hp0 fp32
    double acc[16];
    #pragma unroll
    for (int o = 0; o < 16; ++o) acc[o] = 0;
    for (int f = 0; f < 32; ++f){
      double xv = (double)xA[n*65+f];
      const double* wr = w0 + (q*32+f)*16;
      #pragma unroll
      for (int o = 0; o < 16; ++o) acc[o] += xv*wr[o];
    }
    double sa = 0, sd = 0;
    #pragma unroll
    for (int o = 0; o < 16; ++o){
      sa += acc[o]*a0s[q*16+o];
      sd += acc[o]*a0d[q*16+o];
      hpB[n*68 + q*16 + o] = (float)acc[o];
    }
    as0[q*64+n] = sa; ad0[q*64+n] = sd;
  }
  __syncthreads();
  { // attn L0: fp32 exp, fp32 aggregate, ELU fp32
    float arow = (float)as0[q*64+n];
    float num[16];
    #pragma unroll
    for (int o = 0; o < 16; ++o) num[o] = 0.f;
    float Z = 0.f;
    for (int m2 = 0; m2 < 64; ++m2){
      float e = arow + (float)ad0[q*64+m2];
      float lr = e > 0.f ? e : 0.2f*e;
      float pv = __expf(lr - 30.0f);
      Z += pv;
      const float4* h4 = (const float4*)&hpB[m2*68 + q*16];
      #pragma unroll
      for (int o4 = 0; o4 < 4; ++o4){
        float4 v = h4[o4];
        num[o4*4+0] += pv*v.x; num[o4*4+1] += pv*v.y;
        num[o4*4+2] += pv*v.z; num[o4*4+3] += pv*v.w;
      }
    }
    float iZ = 1.0f/Z;
    #pragma unroll
    for (int o = 0; o < 16; ++o){
      float y = num[o]*iZ + (float)b0[o];
      xA[n*65 + q*16 + o] = y > 0.f ? y : __expf(y)-1.0f;
    }
  }
  __syncthreads();
  if (tid < 64){
    double s1 = 0, s2 = 0;
    for (int p = 0; p < 64; ++p){ double v = xA[p*65+tid]; s1 += v; s2 += v*v; }
    double mu = s1*(1.0/64.0), va = s2*(1.0/64.0) - mu*mu;
    mn[tid] = mu; rs[tid] = fast_rsqrt(va + EPS);
  }
  __syncthreads();
  for (int idx = tid; idx < 4096; idx += 256){
    int p = idx>>6, f = idx&63;
    xA[p*65+f] = (float)(((double)xA[p*65+f] - mn[f])*rs[f]);
  }
  __syncthreads();
  { // hp1 (fp64 compute, fp32 store)
    double a8[8];
    #pragma unroll
    for (int j = 0; j < 8; ++j) a8[j] = 0;
    for (int f = 0; f < 64; ++f){
      double xv = (double)xA[n*65+f];
      const double* wr = w1 + f*32 + q*8;
      #pragma unroll
      for (int j = 0; j < 8; ++j) a8[j] += xv*wr[j];
    }
    #pragma unroll
    for (int j = 0; j < 8; ++j) hpB[n*68 + q*8 + j] = (float)a8[j];
  }
  __syncthreads();
  { // as1/ad1 partials
    double sa = 0, sd = 0;
    #pragma unroll
    for (int o = 0; o < 8; ++o){
      double v = (double)hpB[n*68 + q*8 + o];
      sa += v*a1s[q*8+o]; sd += v*a1d[q*8+o];
    }
    as0[q*64+n] = sa; ad0[q*64+n] = sd;
  }
  __syncthreads();
  if (tid < 128){
    int n2 = tid & 63;
    if (tid < 64) as1[n2] = as0[n2]+as0[64+n2]+as0[128+n2]+as0[192+n2];
    else          ad1[n2] = ad0[n2]+ad0[64+n2]+ad0[128+n2]+ad0[192+n2];
  }
  __syncthreads();
  { // L1 softmax probs fp32
    float arow = (float)as1[n];
    float zp = 0.f;
    for (int m2 = q*16; m2 < q*16+16; ++m2){
      float e = arow + (float)ad1[m2];
      float lr = e > 0.f ? e : 0.2f*e;
      float pv = __expf(lr - 30.0f);
      zp += pv;
      xA[n*65+m2] = pv;
    }
    zS[q*64+n] = zp;
  }
  __syncthreads();
  { // aggregate L1 fp32, write gin as [t][scene][f][ped]
    float Z = zS[n]+zS[64+n]+zS[128+n]+zS[192+n];
    float iZ = 1.0f/Z;
    float a8[8];
    #pragma unroll
    for (int j = 0; j < 8; ++j) a8[j] = 0.f;
    for (int m2 = 0; m2 < 64; ++m2){
      float av = xA[n*65+m2];
      const float4* h4 = (const float4*)&hpB[m2*68 + q*8];
      float4 v0 = h4[0], v1 = h4[1];
      a8[0] += av*v0.x; a8[1] += av*v0.y; a8[2] += av*v0.z; a8[3] += av*v0.w;
      a8[4] += av*v1.x; a8[5] += av*v1.y; a8[6] += av*v1.z; a8[7] += av*v1.w;
    }
    float* go = gout + ((size_t)(tb*NSC + sb)*32)*64;
    #pragma unroll
    for (int j = 0; j < 8; ++j)
      go[(q*8+j)*64 + n] = a8[j]*iZ + (float)b1[q*8+j];
  }
}

// ---------------- K3: graph LSTM + folded LN (unchanged from R9) ----------------
__global__ __launch_bounds__(256) void k_graph(
    const float* __restrict__ gin, const float* __restrict__ h0,
    const float* __restrict__ c0, const double* __restrict__ wsd,
    float* __restrict__ gh)
{
  __shared__ double hdl[2][2048];
  __shared__ double xld[2][2048];
  __shared__ double ps[256], pq[256];
  const double* wihT = wsd + O_GWIHT;
  const double* w2   = wsd + O_GW2;
  const double* bdp  = wsd + O_GBD;
  const double* gCw  = wsd + O_GCW;
  const double* lng  = wsd + O_GLNG;
  const double* lnb  = wsd + O_GLNB;
  const double* ginv = wsd + O_GINV;
  const int tid = threadIdx.x, lane = tid & 63;
  const int wv = __builtin_amdgcn_readfirstlane(tid >> 6);
  const int ub = wv*8;
  const int sb = blockIdx.x, ped0 = sb*64, ped = ped0 + lane;
  for (int idx = tid; idx < 2048; idx += 256){
    int f = idx>>6, p = idx&63;
    hdl[0][idx] = ((double)h0[(ped0+p)*32 + f] - ginv[32+f]) * ginv[f];
  }
  {
    const float* gb0p = gin + (size_t)(0*NSC + sb)*2048;
    for (int idx = tid; idx < 2048; idx += 256) xld[0][idx] = (double)gb0p[idx];
  }
  double c[8];
  #pragma unroll
  for (int j = 0; j < 8; ++j) c[j] = (double)c0[ped*32 + ub + j];
  double mu = 0.0, ri = 1.0;
  __syncthreads();

  for (int t = 0; t < T_OBS; ++t){
    const int p = t & 1;
    if (t < T_OBS-1){
      const float* gbn = gin + (size_t)((t+1)*NSC + sb)*2048;
      for (int idx = tid; idx < 2048; idx += 256) xld[p^1][idx] = (double)gbn[idx];
    }
    double accX[32], accH[32];
    #pragma unroll
    for (int j4 = 0; j4 < 32; ++j4){ accX[j4] = 0; accH[j4] = 0; }
    for (int k = 0; k < 32; ++k){
      double xk = xld[p][k*64 + lane];
      double hk = hdl[p][k*64 + lane];
      const double* wi = wihT + k*128;
      const double* wh = w2   + k*128;
      #pragma unroll
      for (int j = 0; j < 8; ++j){
        #pragma unroll
        for (int g = 0; g < 4; ++g){
          accX[j*4+g] += wi[g*32 + ub + j]*xk;
          accH[j*4+g] += wh[g*32 + ub + j]*hk;
        }
      }
    }
    double hp[8]; double s1 = 0, s2 = 0;
    #pragma unroll
    for (int j = 0; j < 8; ++j){
      double pre[4];
      #pragma unroll
      for (int g = 0; g < 4; ++g){
        int r = g*32 + ub + j;
        pre[g] = bdp[r] + accX[j*4+g] + ri*__builtin_fma(-mu, gCw[r], accH[j*4+g]);
      }
      double ig = fsig(pre[0]);
      double fg = fsig(pre[1]);
      double gg = ftanh(pre[2]);
      double og = fsig(pre[3]);
      c[j] = fg*c[j] + ig*gg;
      hp[j] = og*ftanh(c[j]);
      s1 += hp[j]; s2 += hp[j]*hp[j];
      hdl[p^1][(ub+j)*64 + lane] = hp[j];
    }
    ps[wv*64+lane] = s1; pq[wv*64+lane] = s2;
    __syncthreads();
    double sa = ps[lane]+ps[64+lane]+ps[128+lane]+ps[192+lane];
    double sq = pq[lane]+pq[64+lane]+pq[128+lane]+pq[192+lane];
    mu = sa*(1.0/32.0);
    double va = sq*(1.0/32.0) - mu*mu;
    ri = fast_rsqrt(va + EPS);
    if (t == T_OBS-1){
      #pragma unroll
      for (int j = 0; j < 8; ++j){
        int u = ub + j;
        gh[ped*32 + u] = (float)((hp[j]-mu)*ri*lng[u] + lnb[u]);
      }
    }
  }
}

// ---------------- K4: pred LSTM — 2 scenes/block, persistent-LDS weights ----------------
__global__ __launch_bounds__(512) void k_pred(
    const float* __restrict__ traj_hs, const float* __restrict__ gh,
    const float* __restrict__ zn, const float* __restrict__ obs,
    const double* __restrict__ wsd, const float* __restrict__ wsf,
    const float* __restrict__ als, float* __restrict__ out)
{
  extern __shared__ char smem[];
  float* wlds = (float*)smem;            // [25600] persistent weights
  float* hd   = wlds + 25600;            // [80][2][64] h (pre-LN rep), 2 scenes
  float* ps   = hd + 10240;              // [8][2][64]
  float* pq   = ps + 1024;               // [8][2][64]
  float* pw0  = pq + 1024;               // [8][2][64]
  float* pw1  = pw0 + 1024;              // [8][2][64]

  const float*  w2p  = wsf + OF_PW2P;
  const float*  bdf  = wsf + OF_PBDF;
  const float*  cwf  = wsf + OF_PCWF;
  const float*  wihf = wsf + OF_PWIHF;
  const double* gw   = wsd + O_PGW;
  const double* psc  = wsd + O_PSC;
  const double* pinv = wsd + O_PINV;
  const int tid = threadIdx.x, lane = tid & 63;
  const int wv = __builtin_amdgcn_readfirstlane(tid >> 6);
  const int ub = wv*10;
  const int scA = blockIdx.x*2, scB = scA + 1;
  const int pedA = scA*64 + lane, pedB = scB*64 + lane;

  // stage weights once (step-invariant)
  for (int i = tid; i < 25600; i += 512) wlds[i] = w2p[i];
  // hd init: [k][s][p]
  for (int idx = tid; idx < 10240; idx += 512){
    int f = idx>>7, rem = idx&127, s = rem>>6, p = rem&63;
    int scene = scA + s;
    float v;
    if (f < 32)      v = traj_hs[((size_t)7*NTOT + scene*64 + p)*32 + f];
    else if (f < 64) v = gh[(scene*64+p)*32 + (f-32)];
    else             v = zn[scene*16 + (f-64)];
    hd[idx] = (float)(((double)v - pinv[80+f]) * pinv[f]);
  }
  // constant log_std / std outputs for both scenes
  {
    const int M = PRED_LEN*NTOT*2;
    float l0 = als[0], l1 = als[1];
    float e0 = (float)fast_exp((double)l0), e1 = (float)fast_exp((double)l1);
    for (int i = tid; i < PRED_LEN*128*2; i += 512){
      int t = i >> 8; int rem = i & 255; int p2 = rem >> 1; int ch = rem & 1;
      int gi = (t*NTOT + scA*64 + p2)*2 + ch;
      out[M + gi]   = ch ? l1 : l0;
      out[2*M + gi] = ch ? e1 : e0;
    }
  }
  double cA[10], cB[10];
  #pragma unroll
  for (int j = 0; j < 10; ++j){ cA[j] = 0.0; cB[j] = 0.0; }
  double x0A = (double)obs[((size_t)7*NTOT + pedA)*2 + 0];
  double x1A = (double)obs[((size_t)7*NTOT + pedA)*2 + 1];
  double x0B = (double)obs[((size_t)7*NTOT + pedB)*2 + 0];
  double x1B = (double)obs[((size_t)7*NTOT + pedB)*2 + 1];
  double muA = 0.0, riA = 1.0, invriA = 1.0;
  double muB = 0.0, riB = 1.0, invriB = 1.0;
  const double Cgw0 = psc[0], Cgw1 = psc[1], Cbw0 = psc[2], Cbw1 = psc[3];
  float gwf0[10], gwf1[10];
  #pragma unroll
  for (int j = 0; j < 10; ++j){ gwf0[j] = (float)gw[ub+j]; gwf1[j] = (float)gw[80+ub+j]; }
  __syncthreads();                 // weights + hd visible

  for (int t = 0; t < PRED_LEN; ++t){
    // fp32 gate-init for both scenes (scaled by invri so final pre = ri*acc)
    float x0Af = (float)x0A, x1Af = (float)x1A, muAf = (float)muA, ivAf = (float)invriA;
    float x0Bf = (float)x0B, x1Bf = (float)x1B, muBf = (float)muB, ivBf = (float)invriB;
    f32x2 accA[20], accB[20];
    #pragma unroll
    for (int j = 0; j < 10; ++j){
      #pragma unroll
      for (int g = 0; g < 4; ++g){
        int r = g*80 + ub + j;
        float w0r = wihf[r*2+0], w1r = wihf[r*2+1], br = bdf[r], cr = cwf[r];
        float baseA = fmaf(w1r, x1Af, fmaf(w0r, x0Af, br));
        float baseB = fmaf(w1r, x1Bf, fmaf(w0r, x0Bf, br));
        int idx = j*4+g;
        accA[idx>>1][idx&1] = fmaf(baseA, ivAf, -muAf*cr);
        accB[idx>>1][idx&1] = fmaf(baseB, ivBf, -muBf*cr);
      }
    }
    // GEMV: one weight read serves BOTH scenes
    #pragma unroll 4
    for (int k = 0; k < 80; ++k){
      float hkA = hd[k*128 + lane];
      float hkB = hd[k*128 + 64 + lane];
      f32x2 h2A; h2A[0] = hkA; h2A[1] = hkA;
      f32x2 h2B; h2B[0] = hkB; h2B[1] = hkB;
      const f32x4* w4 = (const f32x4*)&wlds[k*320 + ub*4];
      #pragma unroll
      for (int q4 = 0; q4 < 10; ++q4){
        f32x4 w = w4[q4];
        f32x2 wlo; wlo[0] = w[0]; wlo[1] = w[1];
        f32x2 whi; whi[0] = w[2]; whi[1] = w[3];
        pk_fma(accA[q4*2+0], wlo, h2A);
        pk_fma(accA[q4*2+1], whi, h2A);
        pk_fma(accB[q4*2+0], wlo, h2B);
        pk_fma(accB[q4*2+1], whi, h2B);
      }
    }
    // gates (fp32) + fp64 c-state, both scenes
    float riAf = (float)riA, riBf = (float)riB;
    float hpA[10], hpB2[10];
    float s1A = 0.f, s2A = 0.f, sw0A = 0.f, sw1A = 0.f;
    float s1B = 0.f, s2B = 0.f, sw0B = 0.f, sw1B = 0.f;
    #pragma unroll
    for (int j = 0; j < 10; ++j){
      float igA = fsig32(riAf*accA[(j*4+0)>>1][(j*4+0)&1]);
      float fgA = fsig32(riAf*accA[(j*4+1)>>1][(j*4+1)&1]);
      float ggA = ftanh32(riAf*accA[(j*4+2)>>1][(j*4+2)&1]);
      float ogA = fsig32(riAf*accA[(j*4+3)>>1][(j*4+3)&1]);
      cA[j] = (double)fgA*cA[j] + (double)(igA*ggA);
      float hA = ogA*ftanh32((float)cA[j]);
      hpA[j] = hA;
      s1A += hA; s2A += hA*hA; sw0A += hA*gwf0[j]; sw1A += hA*gwf1[j];

      float igB = fsig32(riBf*accB[(j*4+0)>>1][(j*4+0)&1]);
      float fgB = fsig32(riBf*accB[(j*4+1)>>1][(j*4+1)&1]);
      float ggB = ftanh32(riBf*accB[(j*4+2)>>1][(j*4+2)&1]);
      float ogB = fsig32(riBf*accB[(j*4+3)>>1][(j*4+3)&1]);
      cB[j] = (double)fgB*cB[j] + (double)(igB*ggB);
      float hB = ogB*ftanh32((float)cB[j]);
      hpB2[j] = hB;
      s1B += hB; s2B += hB*hB; sw0B += hB*gwf0[j]; sw1B += hB*gwf1[j];
    }
    __syncthreads();               // all GEMV reads of hd done
    #pragma unroll
    for (int j = 0; j < 10; ++j){
      hd[(ub+j)*128 + lane]      = hpA[j];
      hd[(ub+j)*128 + 64 + lane] = hpB2[j];
    }
    ps[wv*128 + lane] = s1A;  ps[wv*128 + 64 + lane] = s1B;
    pq[wv*128 + lane] = s2A;  pq[wv*128 + 64 + lane] = s2B;
    pw0[wv*128 + lane] = sw0A; pw0[wv*128 + 64 + lane] = sw0B;
    pw1[wv*128 + lane] = sw1A; pw1[wv*128 + 64 + lane] = sw1B;
    __syncthreads();               // writes visible
    double saA = 0, sqA = 0, t0A = 0, t1A = 0;
    double saB = 0, sqB = 0, t0B = 0, t1B = 0;
    #pragma unroll
    for (int w = 0; w < 8; ++w){
      saA += (double)ps[w*128 + lane];      sqA += (double)pq[w*128 + lane];
      t0A += (double)pw0[w*128 + lane];     t1A += (double)pw1[w*128 + lane];
      saB += (double)ps[w*128 + 64 + lane]; sqB += (double)pq[w*128 + 64 + lane];
      t0B += (double)pw0[w*128 + 64 + lane];t1B += (double)pw1[w*128 + 64 + lane];
    }
    muA = saA*(1.0/80.0);
    double vaA = sqA*(1.0/80.0) - muA*muA;
    riA = fast_rsqrt(vaA + EPS); invriA = (vaA + EPS)*riA;
    x0A = riA*__builtin_fma(-muA, Cgw0, t0A) + Cbw0;
    x1A = riA*__builtin_fma(-muA, Cgw1, t1A) + Cbw1;
    muB = saB*(1.0/80.0);
    double vaB = sqB*(1.0/80.0) - muB*muB;
    riB = fast_rsqrt(vaB + EPS); invriB = (vaB + EPS)*riB;
    x0B = riB*__builtin_fma(-muB, Cgw0, t0B) + Cbw0;
    x1B = riB*__builtin_fma(-muB, Cgw1, t1B) + Cbw1;
    if (wv == 0){
      out[((size_t)t*NTOT + pedA)*2 + 0] = (float)x0A;
      out[((size_t)t*NTOT + pedA)*2 + 1] = (float)x1A;
    } else if (wv == 1){
      out[((size_t)t*NTOT + pedB)*2 + 0] = (float)x0B;
      out[((size_t)t*NTOT + pedB)*2 + 1] = (float)x1B;
    }
  }
}

extern "C" void kernel_launch(void* const* d_in, const int* in_sizes, int n_in,
                              void* d_out, int out_size, void* d_ws, size_t ws_size,
                              hipStream_t stream)
{
  const float* obs   = (const float*)d_in[0];
  const float* zn    = (const float*)d_in[2];
  const float* th0   = (const float*)d_in[3];
  const float* tc0   = (const float*)d_in[4];
  const float* gh0   = (const float*)d_in[5];
  const float* gc0   = (const float*)d_in[6];
  const float* gw0   = (const float*)d_in[7];
  const float* gas0  = (const float*)d_in[8];
  const float* gad0  = (const float*)d_in[9];
  const float* gb0   = (const float*)d_in[10];
  const float* gw1   = (const float*)d_in[11];
  const float* gas1  = (const float*)d_in[12];
  const float* gad1  = (const float*)d_in[13];
  const float* gb1   = (const float*)d_in[14];
  const float* twih  = (const float*)d_in[15];
  const float* twhh  = (const float*)d_in[16];
  const float* tbih  = (const float*)d_in[17];
  const float* tbhh  = (const float*)d_in[18];
  const float* gwih  = (const float*)d_in[19];
  const float* gwhh  = (const float*)d_in[20];
  const float* gbih  = (const float*)d_in[21];
  const float* gbhh  = (const float*)d_in[22];
  const float* glng  = (const float*)d_in[23];
  const float* glnb  = (const float*)d_in[24];
  const float* pwih  = (const float*)d_in[25];
  const float* pwhh  = (const float*)d_in[26];
  const float* pbih  = (const float*)d_in[27];
  const float* pbhh  = (const float*)d_in[28];
  const float* plng  = (const float*)d_in[29];
  const float* plnb  = (const float*)d_in[30];
  const float* poww  = (const float*)d_in[31];
  const float* pob   = (const float*)d_in[32];
  const float* als   = (const float*)d_in[33];

  float* out = (float*)d_out;
  double* wsd = (double*)d_ws;
  float* wsf = (float*)(wsd + D_TOTAL);             // fp32 region
  float* traj_hs = wsf + F_TOTAL;                   // [8][NTOT][32]
  float* gin     = traj_hs + (size_t)8*NTOT*32;     // [8][NSC][32][64]
  float* gh      = gin + (size_t)8*NTOT*32;         // [NTOT][32]

  (void)hipFuncSetAttribute((const void*)k_pred,
                            hipFuncAttributeMaxDynamicSharedMemorySize,
                            PRED_LDS_BYTES);

  k_prep<<<dim3(104), dim3(256), 0, stream>>>(
      pwhh, pwih, pbih, pbhh, plng, plnb, poww, pob,
      twih, twhh, tbih, tbhh, gwih, gwhh, gbih, gbhh, glng, glnb,
      gw0, gas0, gad0, gb0, gw1, gas1, gad1, gb1, wsd, wsf);
  k_traj<<<dim3(512), dim3(256), 0, stream>>>(obs, th0, tc0, wsd, traj_hs);
  k_gat<<<dim3(4096), dim3(256), 0, stream>>>(traj_hs, wsd, gin);
  k_graph<<<dim3(512), dim3(256), 0, stream>>>(gin, gh0, gc0, wsd, gh);
  k_pred<<<dim3(256), dim3(512), PRED_LDS_BYTES, stream>>>(traj_hs, gh, zn, obs, wsd, wsf, als, out);
}

// Round 12
// 870.573 us; speedup vs baseline: 1.9269x; 1.0777x over previous
//
#include <hip/hip_runtime.h>
#include <math.h>

#define T_OBS 8
#define PRED_LEN 12
#define NSC 512
#define NPED 64
#define NTOT (NSC*NPED)
#define EPS 1e-5

typedef float f32x2 __attribute__((ext_vector_type(2)));
typedef float f32x4 __attribute__((ext_vector_type(4)));

// ---- wsd (fp64) offsets, in doubles ----
#define O_PGW    26880    // gw0[80], gw1[80]
#define O_PSC    27040    // Cgw0, Cgw1, Cbw0+bout0, Cbw1+bout1
#define O_PINV   27048    // invg[80], b[80]
#define O_GBD    39880    // graph bih+bhh+gCb [128]
#define O_GCW    40008    // gCw[r] [128]
#define O_GLNG   40136
#define O_GLNB   40168
#define O_GINV   40200    // ginvg[32], gb[32]
#define O_A0S    42312    // gat a0s fp64 [64]
#define O_A0D    42376
#define O_A1S    44504    // [32]
#define O_A1D    44536
#define D_TOTAL  44600
// ---- wsf (fp32) offsets, in floats ----
#define OF_PW2P   0        // pred whh^T g-folded fp32 PACKED [80 k][8 wv][40 j4]
#define OF_PBDF   25600    // fp32 bih+bhh+Cb [320]
#define OF_PCWF   25920    // fp32 Cw [320]
#define OF_PWIHF  26240    // fp32 wih [320][2]
#define OF_TWIHF  26880    // traj wih fp32 [128][2]
#define OF_TWHHTF 27136    // traj whh^T fp32 [32 k][128 r]
#define OF_TBF    31232    // traj bih+bhh fp32 [128]
#define OF_GWIHTF 31360    // graph wih^T fp32 [32][128]
#define OF_GW2F   35456    // graph whh^T g-folded fp32 [32][128]
#define OF_W0F    39936    // gat w0 fp32 [2048]
#define OF_B0F    42112    // gat b0 fp32 [16]
#define OF_W1F    42128    // gat w1 fp32 [2048]
#define OF_B1F    44240    // gat b1 fp32 [32]
#define F_TOTAL   44272

// dynamic-LDS for k_pred (2 scenes/block) — unchanged from R10
#define PRED_LDS_BYTES 159744

// ---------- fast fp64 math (validated bit-identical absmax R3-R10) ----------
__device__ __forceinline__ double fast_exp(double x){
  x = fmin(fmax(x, -708.0), 708.0);
  const double L2E  = 1.4426950408889634074;
  const double LN2H = 6.93147180369123816490e-01;
  const double LN2L = 1.90821492927058770002e-10;
  double t = x*L2E;
  double n = rint(t);
  int ni = (int)n;
  double r = __builtin_fma(-n, LN2H, x);
  r = __builtin_fma(-n, LN2L, r);
  double p = 2.08767569878681e-09;
  p = __builtin_fma(p, r, 2.505210838544172e-08);
  p = __builtin_fma(p, r, 2.755731922398589e-07);
  p = __builtin_fma(p, r, 2.755731922398589e-06);
  p = __builtin_fma(p, r, 2.480158730158730e-05);
  p = __builtin_fma(p, r, 1.984126984126984e-04);
  p = __builtin_fma(p, r, 1.388888888888889e-03);
  p = __builtin_fma(p, r, 8.333333333333333e-03);
  p = __builtin_fma(p, r, 4.166666666666667e-02);
  p = __builtin_fma(p, r, 1.666666666666667e-01);
  p = __builtin_fma(p, r, 0.5);
  p = __builtin_fma(p, r, 1.0);
  p = __builtin_fma(p, r, 1.0);
  double s = __hiloint2double((ni + 1023) << 20, 0);
  return p*s;
}
__device__ __forceinline__ double fast_rcp(double d){
#if __has_builtin(__builtin_amdgcn_rcp)
  double r = __builtin_amdgcn_rcp(d);
#else
  double r = 1.0/d;
#endif
  double e = __builtin_fma(-d, r, 1.0); r = __builtin_fma(r, e, r);
  e = __builtin_fma(-d, r, 1.0); r = __builtin_fma(r, e, r);
  e = __builtin_fma(-d, r, 1.0); r = __builtin_fma(r, e, r);
  return r;
}
__device__ __forceinline__ double fast_rsqrt(double d){
#if __has_builtin(__builtin_amdgcn_rsq)
  double r = __builtin_amdgcn_rsq(d);
#else
  double r = 1.0/sqrt(d);
#endif
  double hr = 0.5*d;
  r = r*__builtin_fma(-hr*r, r, 1.5);
  r = r*__builtin_fma(-hr*r, r, 1.5);
  r = r*__builtin_fma(-hr*r, r, 1.5);
  return r;
}
__device__ __forceinline__ double fsig(double x){
  double xc = fmin(fmax(x, -40.0), 40.0);
  return fast_rcp(1.0 + fast_exp(-xc));
}
__device__ __forceinline__ double ftanh(double x){
  double xc = fmin(fmax(x, -20.0), 20.0);
  return __builtin_fma(-2.0, fast_rcp(1.0 + fast_exp(2.0*xc)), 1.0);
}
// ---------- fp32 fast gates (k_pred only — validated at floor R7-R10) ----------
__device__ __forceinline__ float fsig32(float x){
  x = fminf(fmaxf(x, -30.f), 30.f);
  return 1.0f/(1.0f + __expf(-x));
}
__device__ __forceinline__ float ftanh32(float x){
  x = fminf(fmaxf(x, -15.f), 15.f);
  return 1.0f - 2.0f/(1.0f + __expf(2.f*x));
}
// packed dual-fp32 FMA (CDNA VOP3P)
__device__ __forceinline__ void pk_fma(f32x2 &a, f32x2 w, f32x2 h){
  asm("v_pk_fma_f32 %0, %1, %2, %0" : "+v"(a) : "v"(w), "v"(h));
}

// ---------------- prep: fp64 consts + fp32 weights ----------------
__global__ void k_prep(
    const float* __restrict__ pwhh, const float* __restrict__ pwih,
    const float* __restrict__ pbih, const float* __restrict__ pbhh,
    const float* __restrict__ plng, const float* __restrict__ plnb,
    const float* __restrict__ pwout, const float* __restrict__ pbout,
    const float* __restrict__ twih, const float* __restrict__ twhh,
    const float* __restrict__ tbih, const float* __restrict__ tbhh,
    const float* __restrict__ gwih, const float* __restrict__ gwhh,
    const float* __restrict__ gbih, const float* __restrict__ gbhh,
    const float* __restrict__ glng, const float* __restrict__ glnb,
    const float* __restrict__ w0, const float* __restrict__ a0s,
    const float* __restrict__ a0d, const float* __restrict__ b0,
    const float* __restrict__ w1, const float* __restrict__ a1s,
    const float* __restrict__ a1d, const float* __restrict__ b1,
    double* __restrict__ wsd, float* __restrict__ wsf)
{
  int i = blockIdx.x*256 + threadIdx.x;
  // pred packed fp32
  if (i < 25600){
    int kk = i/320, rem = i - kk*320;
    int wv = rem/40, j4 = rem - wv*40;
    int j = j4>>2, g = j4&3;
    int r = g*80 + wv*10 + j;
    wsf[OF_PW2P + i] = (float)((double)pwhh[r*80 + kk] * (double)plng[kk]);
  }
  if (i < 640) wsf[OF_PWIHF + i] = pwih[i];
  if (i < 320){
    double s = 0, sb = 0;
    for (int k = 0; k < 80; ++k){
      double w = (double)pwhh[i*80 + k];
      s  += w*(double)plng[k];
      sb += w*(double)plnb[k];
    }
    wsf[OF_PCWF + i] = (float)s;
    wsf[OF_PBDF + i] = (float)((double)pbih[i] + (double)pbhh[i] + sb);
  }
  if (i < 160){
    if (i < 80) wsd[O_PGW + i] = (double)plng[i]*(double)pwout[i];
    else        wsd[O_PGW + i] = (double)plng[i-80]*(double)pwout[80 + (i-80)];
  }
  if (i < 4){
    double s = 0;
    if (i == 0){ for (int u = 0; u < 80; ++u) s += (double)plng[u]*(double)pwout[u]; }
    if (i == 1){ for (int u = 0; u < 80; ++u) s += (double)plng[u]*(double)pwout[80+u]; }
    if (i == 2){ for (int u = 0; u < 80; ++u) s += (double)plnb[u]*(double)pwout[u]; s += (double)pbout[0]; }
    if (i == 3){ for (int u = 0; u < 80; ++u) s += (double)plnb[u]*(double)pwout[80+u]; s += (double)pbout[1]; }
    wsd[O_PSC + i] = s;
  }
  if (i < 160){
    if (i < 80) wsd[O_PINV + i] = 1.0/(double)plng[i];
    else        wsd[O_PINV + i] = (double)plnb[i-80];
  }
  // traj/graph fp32 weights
  if (i < 256) wsf[OF_TWIHF + i] = twih[i];
  if (i < 4096){
    int r = i>>5, k = i&31;
    wsf[OF_TWHHTF + k*128 + r] = twhh[i];
    wsf[OF_GWIHTF + k*128 + r] = gwih[i];
    wsf[OF_GW2F   + k*128 + r] = (float)((double)gwhh[i]*(double)glng[k]);
  }
  if (i < 128){
    wsf[OF_TBF + i] = (float)((double)tbih[i] + (double)tbhh[i]);
    double s = 0, sb = 0;
    for (int k = 0; k < 32; ++k){
      double w = (double)gwhh[i*32 + k];
      s  += w*(double)glng[k];
      sb += w*(double)glnb[k];
    }
    wsd[O_GCW + i] = s;
    wsd[O_GBD + i] = (double)gbih[i] + (double)gbhh[i] + sb;
  }
  if (i < 32){
    wsd[O_GLNG + i] = (double)glng[i]; wsd[O_GLNB + i] = (double)glnb[i];
    wsd[O_GINV + i] = 1.0/(double)glng[i];
    wsd[O_GINV + 32 + i] = (double)glnb[i];
    wsd[O_A1S + i] = (double)a1s[i]; wsd[O_A1D + i] = (double)a1d[i];
    wsf[OF_B1F + i] = b1[i];
  }
  if (i < 2048){ wsf[OF_W0F + i] = w0[i]; wsf[OF_W1F + i] = w1[i]; }
  if (i < 64){ wsd[O_A0S + i] = (double)a0s[i]; wsd[O_A0D + i] = (double)a0d[i]; }
  if (i < 16) wsf[OF_B0F + i] = b0[i];
}

// ---------------- K1: traj LSTM — fp32 GEMV, fp64 gates ----------------
__global__ __launch_bounds__(256) void k_traj(
    const float* __restrict__ obs, const float* __restrict__ h0,
    const float* __restrict__ c0, const double* __restrict__ wsd,
    const float* __restrict__ wsf, float* __restrict__ traj_hs)
{
  __shared__ float hdl[2][2048];
  const float* wih  = wsf + OF_TWIHF;
  const float* whhT = wsf + OF_TWHHTF;
  const float* bd   = wsf + OF_TBF;
  const int tid = threadIdx.x, lane = tid & 63;
  const int wv = __builtin_amdgcn_readfirstlane(tid >> 6);
  const int ub = wv*8;
  const int ped0 = blockIdx.x*64, ped = ped0 + lane;
  for (int idx = tid; idx < 2048; idx += 256){
    int f = idx>>6, p = idx&63;
    hdl[0][idx] = h0[(ped0+p)*32 + f];
  }
  double c[8];
  #pragma unroll
  for (int j = 0; j < 8; ++j) c[j] = (double)c0[ped*32 + ub + j];
  __syncthreads();

  for (int t = 0; t < T_OBS; ++t){
    const int p = t & 1;
    float x0 = obs[((size_t)t*NTOT + ped)*2 + 0];
    float x1 = obs[((size_t)t*NTOT + ped)*2 + 1];
    float acc[32];
    #pragma unroll
    for (int j = 0; j < 8; ++j){
      #pragma unroll
      for (int g = 0; g < 4; ++g){
        int r = g*32 + ub + j;
        acc[j*4+g] = fmaf(wih[r*2+1], x1, fmaf(wih[r*2+0], x0, bd[r]));
      }
    }
    for (int k = 0; k < 32; ++k){
      float hk = hdl[p][k*64 + lane];
      const float* wh = whhT + k*128;
      #pragma unroll
      for (int j = 0; j < 8; ++j){
        #pragma unroll
        for (int g = 0; g < 4; ++g) acc[j*4+g] = fmaf(wh[g*32 + ub + j], hk, acc[j*4+g]);
      }
    }
    #pragma unroll
    for (int j = 0; j < 8; ++j){
      double ig = fsig((double)acc[j*4+0]);
      double fg = fsig((double)acc[j*4+1]);
      double gg = ftanh((double)acc[j*4+2]);
      double og = fsig((double)acc[j*4+3]);
      c[j] = fg*c[j] + ig*gg;
      float hn = (float)(og*ftanh(c[j]));
      hdl[p^1][(ub+j)*64 + lane] = hn;
      traj_hs[((size_t)t*NTOT + ped)*32 + ub + j] = hn;
    }
    __syncthreads();
  }
}

// ---------------- K2: GAT — fp32 GEMVs, fp64 logit dots & stats ----------------
__global__ __launch_bounds__(256) void k_gat(
    const float* __restrict__ ths, const double* __restrict__ wsd,
    const float* __restrict__ wsf, float* __restrict__ gout)
{
  __shared__ float xA[64*65];
  __shared__ float hpB[64*68];
  __shared__ double as0[256], ad0[256];
  __shared__ double as1[64], ad1[64], mn[64], rs[64];
  __shared__ float zS[256];

  const float*  w0  = wsf + OF_W0F;
  const double* a0s = wsd + O_A0S;
  const double* a0d = wsd + O_A0D;
  const float*  b0  = wsf + OF_B0F;
  const float*  w1  = wsf + OF_W1F;
  const double* a1s = wsd + O_A1S;
  const double* a1d = wsd + O_A1D;
  const float*  b1  = wsf + OF_B1F;

  const int tid = threadIdx.x;
  const int sb = blockIdx.x >> 3, tb = blockIdx.x & 7;
  const int n = tid & 63;
  const int q = __builtin_amdgcn_readfirstlane(tid >> 6);

  const float* xin = ths + ((size_t)tb*NTOT + sb*64)*32;
  for (int idx = tid; idx < 2048; idx += 256)
    xA[(idx>>5)*65 + (idx&31)] = xin[idx];
  __syncthreads();
  if (tid < 32){
    double s1 = 0, s2 = 0;
    for (int p = 0; p < 64; ++p){ double v = xA[p*65+tid]; s1 += v; s2 += v*v; }
    double mu = s1*(1.0/64.0), va = s2*(1.0/64.0) - mu*mu;
    mn[tid] = mu; rs[tid] = fast_rsqrt(va + EPS);
  }
  __syncthreads();
  for (int idx = tid; idx < 2048; idx += 256){
    int p = idx>>5, f = idx&31;
    xA[p*65+f] = (float)(((double)xA[p*65+f] - mn[f])*rs[f]);
  }
  __syncthreads();
  { // hp0 fp32 GEMV + fp64 attn dots
    float acc[16];
    #pragma unroll
    for (int o = 0; o < 16; ++o) acc[o] = 0.f;
    for (int f = 0; f < 32; ++f){
      float xv = xA[n*65+f];
      const float* wr = w0 + (q*32+f)*16;
      #pragma unroll
      for (int o = 0; o < 16; ++o) acc[o] = fmaf(xv, wr[o], acc[o]);
    }
    double sa = 0, sd = 0;
    #pragma unroll
    for (int o = 0; o < 16; ++o){
      sa += (double)acc[o]*a0s[q*16+o];
      sd += (double)acc[o]*a0d[q*16+o];
      hpB[n*68 + q*16 + o] = acc[o];
    }
    as0[q*64+n] = sa; ad0[q*64+n] = sd;
  }
  __syncthreads();
  { // attn L0: fp32 exp (const shift cancels), aggregate, bias, ELU
    float arow = (float)as0[q*64+n];
    float num[16];
    #pragma unroll
    for (int o = 0; o < 16; ++o) num[o] = 0.f;
    float Z = 0.f;
    for (int m2 = 0; m2 < 64; ++m2){
      float e = arow + (float)ad0[q*64+m2];
      float lr = e > 0.f ? e : 0.2f*e;
      float pv = __expf(lr - 30.0f);
      Z += pv;
      const float4* h4 = (const float4*)&hpB[m2*68 + q*16];
      #pragma unroll
      for (int o4 = 0; o4 < 4; ++o4){
        float4 v = h4[o4];
        num[o4*4+0] += pv*v.x; num[o4*4+1] += pv*v.y;
        num[o4*4+2] += pv*v.z; num[o4*4+3] += pv*v.w;
      }
    }
    float iZ = 1.0f/Z;
    #pragma unroll
    for (int o = 0; o < 16; ++o){
      float y = num[o]*iZ + b0[o];
      xA[n*65 + q*16 + o] = y > 0.f ? y : __expf(y)-1.0f;
    }
  }
  __syncthreads();
  if (tid < 64){
    double s1 = 0, s2 = 0;
    for (int p = 0; p < 64; ++p){ double v = xA[p*65+tid]; s1 += v; s2 += v*v; }
    double mu = s1*(1.0/64.0), va = s2*(1.0/64.0) - mu*mu;
    mn[tid] = mu; rs[tid] = fast_rsqrt(va + EPS);
  }
  __syncthreads();
  for (int idx = tid; idx < 4096; idx += 256){
    int p = idx>>6, f = idx&63;
    xA[p*65+f] = (float)(((double)xA[p*65+f] - mn[f])*rs[f]);
  }
  __syncthreads();
  { // hp1 fp32 GEMV
    float a8[8];
    #pragma unroll
    for (int j = 0; j < 8; ++j) a8[j] = 0.f;
    for (int f = 0; f < 64; ++f){
      float xv = xA[n*65+f];
      const float* wr = w1 + f*32 + q*8;
      #pragma unroll
      for (int j = 0; j < 8; ++j) a8[j] = fmaf(xv, wr[j], a8[j]);
    }
    #pragma unroll
    for (int j = 0; j < 8; ++j) hpB[n*68 + q*8 + j] = a8[j];
  }
  __syncthreads();
  { // as1/ad1 partials (fp64 dots over fp32 hp)
    double sa = 0, sd = 0;
    #pragma unroll
    for (int o = 0; o < 8; ++o){
      double v = (double)hpB[n*68 + q*8 + o];
      sa += v*a1s[q*8+o]; sd += v*a1d[q*8+o];
    }
    as0[q*64+n] = sa; ad0[q*64+n] = sd;
  }
  __syncthreads();
  if (tid < 128){
    int n2 = tid & 63;
    if (tid < 64) as1[n2] = as0[n2]+as0[64+n2]+as0[128+n2]+as0[192+n2];
    else          ad1[n2] = ad0[n2]+ad0[64+n2]+ad0[128+n2]+ad0[192+n2];
  }
  __syncthreads();
  { // L1 softmax probs fp32
    float arow = (float)as1[n];
    float zp = 0.f;
    for (int m2 = q*16; m2 < q*16+16; ++m2){
      float e = arow + (float)ad1[m2];
      float lr = e > 0.f ? e : 0.2f*e;
      float pv = __expf(lr - 30.0f);
      zp += pv;
      xA[n*65+m2] = pv;
    }
    zS[q*64+n] = zp;
  }
  __syncthreads();
  { // aggregate L1 fp32, write gin as [t][scene][f][ped]
    float Z = zS[n]+zS[64+n]+zS[128+n]+zS[192+n];
    float iZ = 1.0f/Z;
    float a8[8];
    #pragma unroll
    for (int j = 0; j < 8; ++j) a8[j] = 0.f;
    for (int m2 = 0; m2 < 64; ++m2){
      float av = xA[n*65+m2];
      const float4* h4 = (const float4*)&hpB[m2*68 + q*8];
      float4 v0 = h4[0], v1 = h4[1];
      a8[0] += av*v0.x; a8[1] += av*v0.y; a8[2] += av*v0.z; a8[3] += av*v0.w;
      a8[4] += av*v1.x; a8[5] += av*v1.y; a8[6] += av*v1.z; a8[7] += av*v1.w;
    }
    float* go = gout + ((size_t)(tb*NSC + sb)*32)*64;
    #pragma unroll
    for (int j = 0; j < 8; ++j)
      go[(q*8+j)*64 + n] = a8[j]*iZ + b1[q*8+j];
  }
}

// ---------------- K3: graph LSTM — fp32 GEMVs, fp64 gates/LN ----------------
__global__ __launch_bounds__(256) void k_graph(
    const float* __restrict__ gin, const float* __restrict__ h0,
    const float* __restrict__ c0, const double* __restrict__ wsd,
    const float* __restrict__ wsf, float* __restrict__ gh)
{
  __shared__ float hdl[2][2048];
  __shared__ float xld[2][2048];
  __shared__ double ps[256], pq[256];
  const float*  wihT = wsf + OF_GWIHTF;
  const float*  w2   = wsf + OF_GW2F;
  const double* bdp  = wsd + O_GBD;
  const double* gCw  = wsd + O_GCW;
  const double* lng  = wsd + O_GLNG;
  const double* lnb  = wsd + O_GLNB;
  const double* ginv = wsd + O_GINV;
  const int tid = threadIdx.x, lane = tid & 63;
  const int wv = __builtin_amdgcn_readfirstlane(tid >> 6);
  const int ub = wv*8;
  const int sb = blockIdx.x, ped0 = sb*64, ped = ped0 + lane;
  for (int idx = tid; idx < 2048; idx += 256){
    int f = idx>>6, p = idx&63;
    hdl[0][idx] = (float)(((double)h0[(ped0+p)*32 + f] - ginv[32+f]) * ginv[f]);
  }
  {
    const float* gb0p = gin + (size_t)(0*NSC + sb)*2048;
    for (int idx = tid; idx < 2048; idx += 256) xld[0][idx] = gb0p[idx];
  }
  double c[8];
  #pragma unroll
  for (int j = 0; j < 8; ++j) c[j] = (double)c0[ped*32 + ub + j];
  double mu = 0.0, ri = 1.0;
  __syncthreads();

  for (int t = 0; t < T_OBS; ++t){
    const int p = t & 1;
    if (t < T_OBS-1){
      const float* gbn = gin + (size_t)((t+1)*NSC + sb)*2048;
      for (int idx = tid; idx < 2048; idx += 256) xld[p^1][idx] = gbn[idx];
    }
    float accX[32], accH[32];
    #pragma unroll
    for (int j4 = 0; j4 < 32; ++j4){ accX[j4] = 0.f; accH[j4] = 0.f; }
    for (int k = 0; k < 32; ++k){
      float xk = xld[p][k*64 + lane];
      float hk = hdl[p][k*64 + lane];
      const float* wi = wihT + k*128;
      const float* wh = w2   + k*128;
      #pragma unroll
      for (int j = 0; j < 8; ++j){
        #pragma unroll
        for (int g = 0; g < 4; ++g){
          accX[j*4+g] = fmaf(wi[g*32 + ub + j], xk, accX[j*4+g]);
          accH[j*4+g] = fmaf(wh[g*32 + ub + j], hk, accH[j*4+g]);
        }
      }
    }
    double hp[8]; double s1 = 0, s2 = 0;
    #pragma unroll
    for (int j = 0; j < 8; ++j){
      double pre[4];
      #pragma unroll
      for (int g = 0; g < 4; ++g){
        int r = g*32 + ub + j;
        pre[g] = bdp[r] + (double)accX[j*4+g]
               + ri*__builtin_fma(-mu, gCw[r], (double)accH[j*4+g]);
      }
      double ig = fsig(pre[0]);
      double fg = fsig(pre[1]);
      double gg = ftanh(pre[2]);
      double og = fsig(pre[3]);
      c[j] = fg*c[j] + ig*gg;
      hp[j] = og*ftanh(c[j]);
      s1 += hp[j]; s2 += hp[j]*hp[j];
      hdl[p^1][(ub+j)*64 + lane] = (float)hp[j];
    }
    ps[wv*64+lane] = s1; pq[wv*64+lane] = s2;
    __syncthreads();
    double sa = ps[lane]+ps[64+lane]+ps[128+lane]+ps[192+lane];
    double sq = pq[lane]+pq[64+lane]+pq[128+lane]+pq[192+lane];
    mu = sa*(1.0/32.0);
    double va = sq*(1.0/32.0) - mu*mu;
    ri = fast_rsqrt(va + EPS);
    if (t == T_OBS-1){
      #pragma unroll
      for (int j = 0; j < 8; ++j){
        int u = ub + j;
        gh[ped*32 + u] = (float)((hp[j]-mu)*ri*lng[u] + lnb[u]);
      }
    }
  }
}

// ---------------- K4: pred LSTM — 2 scenes/block, persistent-LDS weights (R10, unchanged) ----------------
__global__ __launch_bounds__(512) void k_pred(
    const float* __restrict__ traj_hs, const float* __restrict__ gh,
    const float* __restrict__ zn, const float* __restrict__ obs,
    const double* __restrict__ wsd, const float* __restrict__ wsf,
    const float* __restrict__ als, float* __restrict__ out)
{
  extern __shared__ char smem[];
  float* wlds = (float*)smem;            // [25600] persistent weights
  float* hd   = wlds + 25600;            // [80][2][64]
  float* ps   = hd + 10240;
  float* pq   = ps + 1024;
  float* pw0  = pq + 1024;
  float* pw1  = pw0 + 1024;

  const float*  w2p  = wsf + OF_PW2P;
  const float*  bdf  = wsf + OF_PBDF;
  const float*  cwf  = wsf + OF_PCWF;
  const float*  wihf = wsf + OF_PWIHF;
  const double* gw   = wsd + O_PGW;
  const double* psc  = wsd + O_PSC;
  const double* pinv = wsd + O_PINV;
  const int tid = threadIdx.x, lane = tid & 63;
  const int wv = __builtin_amdgcn_readfirstlane(tid >> 6);
  const int ub = wv*10;
  const int scA = blockIdx.x*2, scB = scA + 1;
  const int pedA = scA*64 + lane, pedB = scB*64 + lane;

  for (int i = tid; i < 25600; i += 512) wlds[i] = w2p[i];
  for (int idx = tid; idx < 10240; idx += 512){
    int f = idx>>7, rem = idx&127, s = rem>>6, p = rem&63;
    int scene = scA + s;
    float v;
    if (f < 32)      v = traj_hs[((size_t)7*NTOT + scene*64 + p)*32 + f];
    else if (f < 64) v = gh[(scene*64+p)*32 + (f-32)];
    else             v = zn[scene*16 + (f-64)];
    hd[idx] = (float)(((double)v - pinv[80+f]) * pinv[f]);
  }
  {
    const int M = PRED_LEN*NTOT*2;
    float l0 = als[0], l1 = als[1];
    float e0 = (float)fast_exp((double)l0), e1 = (float)fast_exp((double)l1);
    for (int i = tid; i < PRED_LEN*128*2; i += 512){
      int t = i >> 8; int rem = i & 255; int p2 = rem >> 1; int ch = rem & 1;
      int gi = (t*NTOT + scA*64 + p2)*2 + ch;
      out[M + gi]   = ch ? l1 : l0;
      out[2*M + gi] = ch ? e1 : e0;
    }
  }
  double cA[10], cB[10];
  #pragma unroll
  for (int j = 0; j < 10; ++j){ cA[j] = 0.0; cB[j] = 0.0; }
  double x0A = (double)obs[((size_t)7*NTOT + pedA)*2 + 0];
  double x1A = (double)obs[((size_t)7*NTOT + pedA)*2 + 1];
  double x0B = (double)obs[((size_t)7*NTOT + pedB)*2 + 0];
  double x1B = (double)obs[((size_t)7*NTOT + pedB)*2 + 1];
  double muA = 0.0, riA = 1.0, invriA = 1.0;
  double muB = 0.0, riB = 1.0, invriB = 1.0;
  const double Cgw0 = psc[0], Cgw1 = psc[1], Cbw0 = psc[2], Cbw1 = psc[3];
  float gwf0[10], gwf1[10];
  #pragma unroll
  for (int j = 0; j < 10; ++j){ gwf0[j] = (float)gw[ub+j]; gwf1[j] = (float)gw[80+ub+j]; }
  __syncthreads();

  for (int t = 0; t < PRED_LEN; ++t){
    float x0Af = (float)x0A, x1Af = (float)x1A, muAf = (float)muA, ivAf = (float)invriA;
    float x0Bf = (float)x0B, x1Bf = (float)x1B, muBf = (float)muB, ivBf = (float)invriB;
    f32x2 accA[20], accB[20];
    #pragma unroll
    for (int j = 0; j < 10; ++j){
      #pragma unroll
      for (int g = 0; g < 4; ++g){
        int r = g*80 + ub + j;
        float w0r = wihf[r*2+0], w1r = wihf[r*2+1], br = bdf[r], cr = cwf[r];
        float baseA = fmaf(w1r, x1Af, fmaf(w0r, x0Af, br));
        float baseB = fmaf(w1r, x1Bf, fmaf(w0r, x0Bf, br));
        int idx = j*4+g;
        accA[idx>>1][idx&1] = fmaf(baseA, ivAf, -muAf*cr);
        accB[idx>>1][idx&1] = fmaf(baseB, ivBf, -muBf*cr);
      }
    }
    #pragma unroll 4
    for (int k = 0; k < 80; ++k){
      float hkA = hd[k*128 + lane];
      float hkB = hd[k*128 + 64 + lane];
      f32x2 h2A; h2A[0] = hkA; h2A[1] = hkA;
      f32x2 h2B; h2B[0] = hkB; h2B[1] = hkB;
      const f32x4* w4 = (const f32x4*)&wlds[k*320 + ub*4];
      #pragma unroll
      for (int q4 = 0; q4 < 10; ++q4){
        f32x4 w = w4[q4];
        f32x2 wlo; wlo[0] = w[0]; wlo[1] = w[1];
        f32x2 whi; whi[0] = w[2]; whi[1] = w[3];
        pk_fma(accA[q4*2+0], wlo, h2A);
        pk_fma(accA[q4*2+1], whi, h2A);
        pk_fma(accB[q4*2+0], wlo, h2B);
        pk_fma(accB[q4*2+1], whi, h2B);
      }
    }
    float riAf = (float)riA, riBf = (float)riB;
    float hpA[10], hpB2[10];
    float s1A = 0.f, s2A = 0.f, sw0A = 0.f, sw1A = 0.f;
    float s1B = 0.f, s2B = 0.f, sw0B = 0.f, sw1B = 0.f;
    #pragma unroll
    for (int j = 0; j < 10; ++j){
      float igA = fsig32(riAf*accA[(j*4+0)>>1][(j*4+0)&1]);
      float fgA = fsig32(riAf*accA[(j*4+1)>>1][(j*4+1)&1]);
      float ggA = ftanh32(riAf*accA[(j*4+2)>>1][(j*4+2)&1]);
      float ogA = fsig32(riAf*accA[(j*4+3)>>1][(j*4+3)&1]);
      cA[j] = (double)fgA*cA[j] + (double)(igA*ggA);
      float hA = ogA*ftanh32((float)cA[j]);
      hpA[j] = hA;
      s1A += hA; s2A += hA*hA; sw0A += hA*gwf0[j]; sw1A += hA*gwf1[j];

      float igB = fsig32(riBf*accB[(j*4+0)>>1][(j*4+0)&1]);
      float fgB = fsig32(riBf*accB[(j*4+1)>>1][(j*4+1)&1]);
      float ggB = ftanh32(riBf*accB[(j*4+2)>>1][(j*4+2)&1]);
      float ogB = fsig32(riBf*accB[(j*4+3)>>1][(j*4+3)&1]);
      cB[j] = (double)fgB*cB[j] + (double)(igB*ggB);
      float hB = ogB*ftanh32((float)cB[j]);
      hpB2[j] = hB;
      s1B += hB; s2B += hB*hB; sw0B += hB*gwf0[j]; sw1B += hB*gwf1[j];
    }
    __syncthreads();
    #pragma unroll
    for (int j = 0; j < 10; ++j){
      hd[(ub+j)*128 + lane]      = hpA[j];
      hd[(ub+j)*128 + 64 + lane] = hpB2[j];
    }
    ps[wv*128 + lane] = s1A;  ps[wv*128 + 64 + lane] = s1B;
    pq[wv*128 + lane] = s2A;  pq[wv*128 + 64 + lane] = s2B;
    pw0[wv*128 + lane] = sw0A; pw0[wv*128 + 64 + lane] = sw0B;
    pw1[wv*128 + lane] = sw1A; pw1[wv*128 + 64 + lane] = sw1B;
    __syncthreads();
    double saA = 0, sqA = 0, t0A = 0, t1A = 0;
    double saB = 0, sqB = 0, t0B = 0, t1B = 0;
    #pragma unroll
    for (int w = 0; w < 8; ++w){
      saA += (double)ps[w*128 + lane];      sqA += (double)pq[w*128 + lane];
      t0A += (double)pw0[w*128 + lane];     t1A += (double)pw1[w*128 + lane];
      saB += (double)ps[w*128 + 64 + lane]; sqB += (double)pq[w*128 + 64 + lane];
      t0B += (double)pw0[w*128 + 64 + lane];t1B += (double)pw1[w*128 + 64 + lane];
    }
    muA = saA*(1.0/80.0);
    double vaA = sqA*(1.0/80.0) - muA*muA;
    riA = fast_rsqrt(vaA + EPS); invriA = (vaA + EPS)*riA;
    x0A = riA*__builtin_fma(-muA, Cgw0, t0A) + Cbw0;
    x1A = riA*__builtin_fma(-muA, Cgw1, t1A) + Cbw1;
    muB = saB*(1.0/80.0);
    double vaB = sqB*(1.0/80.0) - muB*muB;
    riB = fast_rsqrt(vaB + EPS); invriB = (vaB + EPS)*riB;
    x0B = riB*__builtin_fma(-muB, Cgw0, t0B) + Cbw0;
    x1B = riB*__builtin_fma(-muB, Cgw1, t1B) + Cbw1;
    if (wv == 0){
      out[((size_t)t*NTOT + pedA)*2 + 0] = (float)x0A;
      out[((size_t)t*NTOT + pedA)*2 + 1] = (float)x1A;
    } else if (wv == 1){
      out[((size_t)t*NTOT + pedB)*2 + 0] = (float)x0B;
      out[((size_t)t*NTOT + pedB)*2 + 1] = (float)x1B;
    }
  }
}

extern "C" void kernel_launch(void* const* d_in, const int* in_sizes, int n_in,
                              void* d_out, int out_size, void* d_ws, size_t ws_size,
                              hipStream_t stream)
{
  const float* obs   = (const float*)d_in[0];
  const float* zn    = (const float*)d_in[2];
  const float* th0   = (const float*)d_in[3];
  const float* tc0   = (const float*)d_in[4];
  const float* gh0   = (const float*)d_in[5];
  const float* gc0   = (const float*)d_in[6];
  const float* gw0   = (const float*)d_in[7];
  const float* gas0  = (const float*)d_in[8];
  const float* gad0  = (const float*)d_in[9];
  const float* gb0   = (const float*)d_in[10];
  const float* gw1   = (const float*)d_in[11];
  const float* gas1  = (const float*)d_in[12];
  const float* gad1  = (const float*)d_in[13];
  const float* gb1   = (const float*)d_in[14];
  const float* twih  = (const float*)d_in[15];
  const float* twhh  = (const float*)d_in[16];
  const float* tbih  = (const float*)d_in[17];
  const float* tbhh  = (const float*)d_in[18];
  const float* gwih  = (const float*)d_in[19];
  const float* gwhh  = (const float*)d_in[20];
  const float* gbih  = (const float*)d_in[21];
  const float* gbhh  = (const float*)d_in[22];
  const float* glng  = (const float*)d_in[23];
  const float* glnb  = (const float*)d_in[24];
  const float* pwih  = (const float*)d_in[25];
  const float* pwhh  = (const float*)d_in[26];
  const float* pbih  = (const float*)d_in[27];
  const float* pbhh  = (const float*)d_in[28];
  const float* plng  = (const float*)d_in[29];
  const float* plnb  = (const float*)d_in[30];
  const float* poww  = (const float*)d_in[31];
  const float* pob   = (const float*)d_in[32];
  const float* als   = (const float*)d_in[33];

  float* out = (float*)d_out;
  double* wsd = (double*)d_ws;
  float* wsf = (float*)(wsd + D_TOTAL);             // fp32 region
  float* traj_hs = wsf + F_TOTAL;                   // [8][NTOT][32]
  float* gin     = traj_hs + (size_t)8*NTOT*32;     // [8][NSC][32][64]
  float* gh      = gin + (size_t)8*NTOT*32;         // [NTOT][32]

  (void)hipFuncSetAttribute((const void*)k_pred,
                            hipFuncAttributeMaxDynamicSharedMemorySize,
                            PRED_LDS_BYTES);

  k_prep<<<dim3(104), dim3(256), 0, stream>>>(
      pwhh, pwih, pbih, pbhh, plng, plnb, poww, pob,
      twih, twhh, tbih, tbhh, gwih, gwhh, gbih, gbhh, glng, glnb,
      gw0, gas0, gad0, gb0, gw1, gas1, gad1, gb1, wsd, wsf);
  k_traj<<<dim3(512), dim3(256), 0, stream>>>(obs, th0, tc0, wsd, wsf, traj_hs);
  k_gat<<<dim3(4096), dim3(256), 0, stream>>>(traj_hs, wsd, wsf, gin);
  k_graph<<<dim3(512), dim3(256), 0, stream>>>(gin, gh0, gc0, wsd, wsf, gh);
  k_pred<<<dim3(256), dim3(512), PRED_LDS_BYTES, stream>>>(traj_hs, gh, zn, obs, wsd, wsf, als, out);
}

// Round 13
// 867.426 us; speedup vs baseline: 1.9339x; 1.0036x over previous
//
#include <hip/hip_runtime.h>
#include <math.h>

#define T_OBS 8
#define PRED_LEN 12
#define NSC 512
#define NPED 64
#define NTOT (NSC*NPED)
#define EPS 1e-5

typedef float f32x2 __attribute__((ext_vector_type(2)));
typedef float f32x4 __attribute__((ext_vector_type(4)));

// ---- wsd (fp64) offsets, in doubles ----
#define O_PGW    26880    // gw0[80], gw1[80]
#define O_PSC    27040    // Cgw0, Cgw1, Cbw0+bout0, Cbw1+bout1
#define O_PINV   27048    // invg[80], b[80]
#define O_GBD    39880    // graph bih+bhh+gCb [128]
#define O_GCW    40008    // gCw[r] [128]
#define O_GLNG   40136
#define O_GLNB   40168
#define O_GINV   40200    // ginvg[32], gb[32]
#define O_A0S    42312    // gat a0s fp64 [64]
#define O_A0D    42376
#define O_A1S    44504    // [32]
#define O_A1D    44536
#define D_TOTAL  44600
// ---- wsf (fp32) offsets, in floats ----
#define OF_PW2P   0        // pred whh^T g-folded fp32 PACKED [80 k][8 wv][40 j4]
#define OF_PBDF   25600    // fp32 bih+bhh+Cb [320]
#define OF_PCWF   25920    // fp32 Cw [320]
#define OF_PWIHF  26240    // fp32 wih [320][2]
#define OF_TWIHF  26880    // traj wih fp32 [128][2]
#define OF_TWHHTF 27136    // traj whh^T fp32 [32 k][128 r]
#define OF_TBF    31232    // traj bih+bhh fp32 [128]
#define OF_GWIHTF 31360    // graph wih^T fp32 [32][128]
#define OF_GW2F   35456    // graph whh^T g-folded fp32 [32][128]
#define OF_W0F    39936    // gat w0 fp32 [2048]
#define OF_B0F    42112    // gat b0 fp32 [16]
#define OF_W1F    42128    // gat w1 fp32 [2048]
#define OF_B1F    44240    // gat b1 fp32 [32]
#define F_TOTAL   44272

// dynamic-LDS for k_pred (2 scenes/block)
#define PRED_LDS_BYTES 159744

// ---------- fast fp64 math (validated bit-identical absmax R3-R12) ----------
__device__ __forceinline__ double fast_exp(double x){
  x = fmin(fmax(x, -708.0), 708.0);
  const double L2E  = 1.4426950408889634074;
  const double LN2H = 6.93147180369123816490e-01;
  const double LN2L = 1.90821492927058770002e-10;
  double t = x*L2E;
  double n = rint(t);
  int ni = (int)n;
  double r = __builtin_fma(-n, LN2H, x);
  r = __builtin_fma(-n, LN2L, r);
  double p = 2.08767569878681e-09;
  p = __builtin_fma(p, r, 2.505210838544172e-08);
  p = __builtin_fma(p, r, 2.755731922398589e-07);
  p = __builtin_fma(p, r, 2.755731922398589e-06);
  p = __builtin_fma(p, r, 2.480158730158730e-05);
  p = __builtin_fma(p, r, 1.984126984126984e-04);
  p = __builtin_fma(p, r, 1.388888888888889e-03);
  p = __builtin_fma(p, r, 8.333333333333333e-03);
  p = __builtin_fma(p, r, 4.166666666666667e-02);
  p = __builtin_fma(p, r, 1.666666666666667e-01);
  p = __builtin_fma(p, r, 0.5);
  p = __builtin_fma(p, r, 1.0);
  p = __builtin_fma(p, r, 1.0);
  double s = __hiloint2double((ni + 1023) << 20, 0);
  return p*s;
}
__device__ __forceinline__ double fast_rcp(double d){
#if __has_builtin(__builtin_amdgcn_rcp)
  double r = __builtin_amdgcn_rcp(d);
#else
  double r = 1.0/d;
#endif
  double e = __builtin_fma(-d, r, 1.0); r = __builtin_fma(r, e, r);
  e = __builtin_fma(-d, r, 1.0); r = __builtin_fma(r, e, r);
  e = __builtin_fma(-d, r, 1.0); r = __builtin_fma(r, e, r);
  return r;
}
__device__ __forceinline__ double fast_rsqrt(double d){
#if __has_builtin(__builtin_amdgcn_rsq)
  double r = __builtin_amdgcn_rsq(d);
#else
  double r = 1.0/sqrt(d);
#endif
  double hr = 0.5*d;
  r = r*__builtin_fma(-hr*r, r, 1.5);
  r = r*__builtin_fma(-hr*r, r, 1.5);
  r = r*__builtin_fma(-hr*r, r, 1.5);
  return r;
}
__device__ __forceinline__ double fsig(double x){
  double xc = fmin(fmax(x, -40.0), 40.0);
  return fast_rcp(1.0 + fast_exp(-xc));
}
__device__ __forceinline__ double ftanh(double x){
  double xc = fmin(fmax(x, -20.0), 20.0);
  return __builtin_fma(-2.0, fast_rcp(1.0 + fast_exp(2.0*xc)), 1.0);
}
// ---------- fp32 fast gates (k_pred only — validated at floor R7-R12) ----------
__device__ __forceinline__ float fsig32(float x){
  x = fminf(fmaxf(x, -30.f), 30.f);
  return 1.0f/(1.0f + __expf(-x));
}
__device__ __forceinline__ float ftanh32(float x){
  x = fminf(fmaxf(x, -15.f), 15.f);
  return 1.0f - 2.0f/(1.0f + __expf(2.f*x));
}
// packed dual-fp32 FMA (CDNA VOP3P)
__device__ __forceinline__ void pk_fma(f32x2 &a, f32x2 w, f32x2 h){
  asm("v_pk_fma_f32 %0, %1, %2, %0" : "+v"(a) : "v"(w), "v"(h));
}

// ---------------- prep (unchanged from R12) ----------------
__global__ void k_prep(
    const float* __restrict__ pwhh, const float* __restrict__ pwih,
    const float* __restrict__ pbih, const float* __restrict__ pbhh,
    const float* __restrict__ plng, const float* __restrict__ plnb,
    const float* __restrict__ pwout, const float* __restrict__ pbout,
    const float* __restrict__ twih, const float* __restrict__ twhh,
    const float* __restrict__ tbih, const float* __restrict__ tbhh,
    const float* __restrict__ gwih, const float* __restrict__ gwhh,
    const float* __restrict__ gbih, const float* __restrict__ gbhh,
    const float* __restrict__ glng, const float* __restrict__ glnb,
    const float* __restrict__ w0, const float* __restrict__ a0s,
    const float* __restrict__ a0d, const float* __restrict__ b0,
    const float* __restrict__ w1, const float* __restrict__ a1s,
    const float* __restrict__ a1d, const float* __restrict__ b1,
    double* __restrict__ wsd, float* __restrict__ wsf)
{
  int i = blockIdx.x*256 + threadIdx.x;
  if (i < 25600){
    int kk = i/320, rem = i - kk*320;
    int wv = rem/40, j4 = rem - wv*40;
    int j = j4>>2, g = j4&3;
    int r = g*80 + wv*10 + j;
    wsf[OF_PW2P + i] = (float)((double)pwhh[r*80 + kk] * (double)plng[kk]);
  }
  if (i < 640) wsf[OF_PWIHF + i] = pwih[i];
  if (i < 320){
    double s = 0, sb = 0;
    for (int k = 0; k < 80; ++k){
      double w = (double)pwhh[i*80 + k];
      s  += w*(double)plng[k];
      sb += w*(double)plnb[k];
    }
    wsf[OF_PCWF + i] = (float)s;
    wsf[OF_PBDF + i] = (float)((double)pbih[i] + (double)pbhh[i] + sb);
  }
  if (i < 160){
    if (i < 80) wsd[O_PGW + i] = (double)plng[i]*(double)pwout[i];
    else        wsd[O_PGW + i] = (double)plng[i-80]*(double)pwout[80 + (i-80)];
  }
  if (i < 4){
    double s = 0;
    if (i == 0){ for (int u = 0; u < 80; ++u) s += (double)plng[u]*(double)pwout[u]; }
    if (i == 1){ for (int u = 0; u < 80; ++u) s += (double)plng[u]*(double)pwout[80+u]; }
    if (i == 2){ for (int u = 0; u < 80; ++u) s += (double)plnb[u]*(double)pwout[u]; s += (double)pbout[0]; }
    if (i == 3){ for (int u = 0; u < 80; ++u) s += (double)plnb[u]*(double)pwout[80+u]; s += (double)pbout[1]; }
    wsd[O_PSC + i] = s;
  }
  if (i < 160){
    if (i < 80) wsd[O_PINV + i] = 1.0/(double)plng[i];
    else        wsd[O_PINV + i] = (double)plnb[i-80];
  }
  if (i < 256) wsf[OF_TWIHF + i] = twih[i];
  if (i < 4096){
    int r = i>>5, k = i&31;
    wsf[OF_TWHHTF + k*128 + r] = twhh[i];
    wsf[OF_GWIHTF + k*128 + r] = gwih[i];
    wsf[OF_GW2F   + k*128 + r] = (float)((double)gwhh[i]*(double)glng[k]);
  }
  if (i < 128){
    wsf[OF_TBF + i] = (float)((double)tbih[i] + (double)tbhh[i]);
    double s = 0, sb = 0;
    for (int k = 0; k < 32; ++k){
      double w = (double)gwhh[i*32 + k];
      s  += w*(double)glng[k];
      sb += w*(double)glnb[k];
    }
    wsd[O_GCW + i] = s;
    wsd[O_GBD + i] = (double)gbih[i] + (double)gbhh[i] + sb;
  }
  if (i < 32){
    wsd[O_GLNG + i] = (double)glng[i]; wsd[O_GLNB + i] = (double)glnb[i];
    wsd[O_GINV + i] = 1.0/(double)glng[i];
    wsd[O_GINV + 32 + i] = (double)glnb[i];
    wsd[O_A1S + i] = (double)a1s[i]; wsd[O_A1D + i] = (double)a1d[i];
    wsf[OF_B1F + i] = b1[i];
  }
  if (i < 2048){ wsf[OF_W0F + i] = w0[i]; wsf[OF_W1F + i] = w1[i]; }
  if (i < 64){ wsd[O_A0S + i] = (double)a0s[i]; wsd[O_A0D + i] = (double)a0d[i]; }
  if (i < 16) wsf[OF_B0F + i] = b0[i];
}

// ---------------- K1: traj LSTM — fp32 GEMV, fp64 gates (unchanged from R12) ----------------
__global__ __launch_bounds__(256) void k_traj(
    const float* __restrict__ obs, const float* __restrict__ h0,
    const float* __restrict__ c0, const double* __restrict__ wsd,
    const float* __restrict__ wsf, float* __restrict__ traj_hs)
{
  __shared__ float hdl[2][2048];
  const float* wih  = wsf + OF_TWIHF;
  const float* whhT = wsf + OF_TWHHTF;
  const float* bd   = wsf + OF_TBF;
  const int tid = threadIdx.x, lane = tid & 63;
  const int wv = __builtin_amdgcn_readfirstlane(tid >> 6);
  const int ub = wv*8;
  const int ped0 = blockIdx.x*64, ped = ped0 + lane;
  for (int idx = tid; idx < 2048; idx += 256){
    int f = idx>>6, p = idx&63;
    hdl[0][idx] = h0[(ped0+p)*32 + f];
  }
  double c[8];
  #pragma unroll
  for (int j = 0; j < 8; ++j) c[j] = (double)c0[ped*32 + ub + j];
  __syncthreads();

  for (int t = 0; t < T_OBS; ++t){
    const int p = t & 1;
    float x0 = obs[((size_t)t*NTOT + ped)*2 + 0];
    float x1 = obs[((size_t)t*NTOT + ped)*2 + 1];
    float acc[32];
    #pragma unroll
    for (int j = 0; j < 8; ++j){
      #pragma unroll
      for (int g = 0; g < 4; ++g){
        int r = g*32 + ub + j;
        acc[j*4+g] = fmaf(wih[r*2+1], x1, fmaf(wih[r*2+0], x0, bd[r]));
      }
    }
    for (int k = 0; k < 32; ++k){
      float hk = hdl[p][k*64 + lane];
      const float* wh = whhT + k*128;
      #pragma unroll
      for (int j = 0; j < 8; ++j){
        #pragma unroll
        for (int g = 0; g < 4; ++g) acc[j*4+g] = fmaf(wh[g*32 + ub + j], hk, acc[j*4+g]);
      }
    }
    #pragma unroll
    for (int j = 0; j < 8; ++j){
      double ig = fsig((double)acc[j*4+0]);
      double fg = fsig((double)acc[j*4+1]);
      double gg = ftanh((double)acc[j*4+2]);
      double og = fsig((double)acc[j*4+3]);
      c[j] = fg*c[j] + ig*gg;
      float hn = (float)(og*ftanh(c[j]));
      hdl[p^1][(ub+j)*64 + lane] = hn;
      traj_hs[((size_t)t*NTOT + ped)*32 + ub + j] = hn;
    }
    __syncthreads();
  }
}

// ---------------- K2: GAT — parallel inorms + pk_fma aggregates ----------------
__global__ __launch_bounds__(256) void k_gat(
    const float* __restrict__ ths, const double* __restrict__ wsd,
    const float* __restrict__ wsf, float* __restrict__ gout)
{
  __shared__ float xA[64*65];
  __shared__ float hpB[64*68];
  __shared__ double as0[256], ad0[256];   // logit dots / reduction partials
  __shared__ double as1[64], ad1[64], mn[64], rs[64];
  __shared__ float zS[256];

  const float*  w0  = wsf + OF_W0F;
  const double* a0s = wsd + O_A0S;
  const double* a0d = wsd + O_A0D;
  const float*  b0  = wsf + OF_B0F;
  const float*  w1  = wsf + OF_W1F;
  const double* a1s = wsd + O_A1S;
  const double* a1d = wsd + O_A1D;
  const float*  b1  = wsf + OF_B1F;

  const int tid = threadIdx.x;
  const int sb = blockIdx.x >> 3, tb = blockIdx.x & 7;
  const int n = tid & 63;
  const int q = __builtin_amdgcn_readfirstlane(tid >> 6);

  const float* xin = ths + ((size_t)tb*NTOT + sb*64)*32;
  for (int idx = tid; idx < 2048; idx += 256)
    xA[(idx>>5)*65 + (idx&31)] = xin[idx];
  __syncthreads();
  { // inorm1 partials: thread (f=tid&31, g=tid>>5) sums 8 peds
    int f = tid & 31, g = tid >> 5;
    double s1 = 0, s2 = 0;
    #pragma unroll
    for (int pp = 0; pp < 8; ++pp){
      double v = xA[(g*8+pp)*65 + f];
      s1 += v; s2 += v*v;
    }
    as0[g*32+f] = s1; ad0[g*32+f] = s2;
  }
  __syncthreads();
  if (tid < 32){
    double s1 = 0, s2 = 0;
    #pragma unroll
    for (int g = 0; g < 8; ++g){ s1 += as0[g*32+tid]; s2 += ad0[g*32+tid]; }
    double mu = s1*(1.0/64.0), va = s2*(1.0/64.0) - mu*mu;
    mn[tid] = mu; rs[tid] = fast_rsqrt(va + EPS);
  }
  __syncthreads();
  for (int idx = tid; idx < 2048; idx += 256){
    int p = idx>>5, f = idx&31;
    xA[p*65+f] = (float)(((double)xA[p*65+f] - mn[f])*rs[f]);
  }
  __syncthreads();
  { // hp0 fp32 GEMV + fp64 attn dots
    float acc[16];
    #pragma unroll
    for (int o = 0; o < 16; ++o) acc[o] = 0.f;
    for (int f = 0; f < 32; ++f){
      float xv = xA[n*65+f];
      const float* wr = w0 + (q*32+f)*16;
      #pragma unroll
      for (int o = 0; o < 16; ++o) acc[o] = fmaf(xv, wr[o], acc[o]);
    }
    double sa = 0, sd = 0;
    #pragma unroll
    for (int o = 0; o < 16; ++o){
      sa += (double)acc[o]*a0s[q*16+o];
      sd += (double)acc[o]*a0d[q*16+o];
      hpB[n*68 + q*16 + o] = acc[o];
    }
    as0[q*64+n] = sa; ad0[q*64+n] = sd;
  }
  __syncthreads();
  { // attn L0: fp32 exp (const shift cancels), pk_fma aggregate, bias, ELU
    float arow = (float)as0[q*64+n];
    f32x2 num2[8];
    #pragma unroll
    for (int o2 = 0; o2 < 8; ++o2){ num2[o2][0] = 0.f; num2[o2][1] = 0.f; }
    float Z = 0.f;
    for (int m2 = 0; m2 < 64; ++m2){
      float e = arow + (float)ad0[q*64+m2];
      float lr = e > 0.f ? e : 0.2f*e;
      float pv = __expf(lr - 30.0f);
      Z += pv;
      f32x2 p2; p2[0] = pv; p2[1] = pv;
      const f32x4* h4 = (const f32x4*)&hpB[m2*68 + q*16];
      #pragma unroll
      for (int o4 = 0; o4 < 4; ++o4){
        f32x4 v = h4[o4];
        f32x2 vlo; vlo[0] = v[0]; vlo[1] = v[1];
        f32x2 vhi; vhi[0] = v[2]; vhi[1] = v[3];
        pk_fma(num2[o4*2+0], vlo, p2);
        pk_fma(num2[o4*2+1], vhi, p2);
      }
    }
    float iZ = 1.0f/Z;
    #pragma unroll
    for (int o = 0; o < 16; ++o){
      float y = num2[o>>1][o&1]*iZ + b0[o];
      xA[n*65 + q*16 + o] = y > 0.f ? y : __expf(y)-1.0f;
    }
  }
  __syncthreads();
  { // inorm2 partials: thread (f=tid&63, g=tid>>6) sums 16 peds
    int f = tid & 63, g = tid >> 6;
    double s1 = 0, s2 = 0;
    #pragma unroll
    for (int pp = 0; pp < 16; ++pp){
      double v = xA[(g*16+pp)*65 + f];
      s1 += v; s2 += v*v;
    }
    as0[g*64+f] = s1; ad0[g*64+f] = s2;
  }
  __syncthreads();
  if (tid < 64){
    double s1 = as0[tid]+as0[64+tid]+as0[128+tid]+as0[192+tid];
    double s2 = ad0[tid]+ad0[64+tid]+ad0[128+tid]+ad0[192+tid];
    double mu = s1*(1.0/64.0), va = s2*(1.0/64.0) - mu*mu;
    mn[tid] = mu; rs[tid] = fast_rsqrt(va + EPS);
  }
  __syncthreads();
  for (int idx = tid; idx < 4096; idx += 256){
    int p = idx>>6, f = idx&63;
    xA[p*65+f] = (float)(((double)xA[p*65+f] - mn[f])*rs[f]);
  }
  __syncthreads();
  { // hp1 fp32 GEMV
    float a8[8];
    #pragma unroll
    for (int j = 0; j < 8; ++j) a8[j] = 0.f;
    for (int f = 0; f < 64; ++f){
      float xv = xA[n*65+f];
      const float* wr = w1 + f*32 + q*8;
      #pragma unroll
      for (int j = 0; j < 8; ++j) a8[j] = fmaf(xv, wr[j], a8[j]);
    }
    #pragma unroll
    for (int j = 0; j < 8; ++j) hpB[n*68 + q*8 + j] = a8[j];
  }
  __syncthreads();
  { // as1/ad1 partials (fp64 dots over fp32 hp)
    double sa = 0, sd = 0;
    #pragma unroll
    for (int o = 0; o < 8; ++o){
      double v = (double)hpB[n*68 + q*8 + o];
      sa += v*a1s[q*8+o]; sd += v*a1d[q*8+o];
    }
    as0[q*64+n] = sa; ad0[q*64+n] = sd;
  }
  __syncthreads();
  if (tid < 128){
    int n2 = tid & 63;
    if (tid < 64) as1[n2] = as0[n2]+as0[64+n2]+as0[128+n2]+as0[192+n2];
    else          ad1[n2] = ad0[n2]+ad0[64+n2]+ad0[128+n2]+ad0[192+n2];
  }
  __syncthreads();
  { // L1 softmax probs fp32
    float arow = (float)as1[n];
    float zp = 0.f;
    for (int m2 = q*16; m2 < q*16+16; ++m2){
      float e = arow + (float)ad1[m2];
      float lr = e > 0.f ? e : 0.2f*e;
      float pv = __expf(lr - 30.0f);
      zp += pv;
      xA[n*65+m2] = pv;
    }
    zS[q*64+n] = zp;
  }
  __syncthreads();
  { // aggregate L1 with pk_fma, write gin as [t][scene][f][ped]
    float Z = zS[n]+zS[64+n]+zS[128+n]+zS[192+n];
    float iZ = 1.0f/Z;
    f32x2 a2[4];
    #pragma unroll
    for (int j2 = 0; j2 < 4; ++j2){ a2[j2][0] = 0.f; a2[j2][1] = 0.f; }
    for (int m2 = 0; m2 < 64; ++m2){
      float av = xA[n*65+m2];
      f32x2 p2; p2[0] = av; p2[1] = av;
      const f32x4* h4 = (const f32x4*)&hpB[m2*68 + q*8];
      f32x4 v0 = h4[0], v1 = h4[1];
      f32x2 w00; w00[0] = v0[0]; w00[1] = v0[1];
      f32x2 w01; w01[0] = v0[2]; w01[1] = v0[3];
      f32x2 w10; w10[0] = v1[0]; w10[1] = v1[1];
      f32x2 w11; w11[0] = v1[2]; w11[1] = v1[3];
      pk_fma(a2[0], w00, p2);
      pk_fma(a2[1], w01, p2);
      pk_fma(a2[2], w10, p2);
      pk_fma(a2[3], w11, p2);
    }
    float* go = gout + ((size_t)(tb*NSC + sb)*32)*64;
    #pragma unroll
    for (int j = 0; j < 8; ++j)
      go[(q*8+j)*64 + n] = a2[j>>1][j&1]*iZ + b1[q*8+j];
  }
}

// ---------------- K3: graph LSTM — fp32 GEMVs, fp64 gates/LN (unchanged from R12) ----------------
__global__ __launch_bounds__(256) void k_graph(
    const float* __restrict__ gin, const float* __restrict__ h0,
    const float* __restrict__ c0, const double* __restrict__ wsd,
    const float* __restrict__ wsf, float* __restrict__ gh)
{
  __shared__ float hdl[2][2048];
  __shared__ float xld[2][2048];
  __shared__ double ps[256], pq[256];
  const float*  wihT = wsf + OF_GWIHTF;
  const float*  w2   = wsf + OF_GW2F;
  const double* bdp  = wsd + O_GBD;
  const double* gCw  = wsd + O_GCW;
  const double* lng  = wsd + O_GLNG;
  const double* lnb  = wsd + O_GLNB;
  const double* ginv = wsd + O_GINV;
  const int tid = threadIdx.x, lane = tid & 63;
  const int wv = __builtin_amdgcn_readfirstlane(tid >> 6);
  const int ub = wv*8;
  const int sb = blockIdx.x, ped0 = sb*64, ped = ped0 + lane;
  for (int idx = tid; idx < 2048; idx += 256){
    int f = idx>>6, p = idx&63;
    hdl[0][idx] = (float)(((double)h0[(ped0+p)*32 + f] - ginv[32+f]) * ginv[f]);
  }
  {
    const float* gb0p = gin + (size_t)(0*NSC + sb)*2048;
    for (int idx = tid; idx < 2048; idx += 256) xld[0][idx] = gb0p[idx];
  }
  double c[8];
  #pragma unroll
  for (int j = 0; j < 8; ++j) c[j] = (double)c0[ped*32 + ub + j];
  double mu = 0.0, ri = 1.0;
  __syncthreads();

  for (int t = 0; t < T_OBS; ++t){
    const int p = t & 1;
    if (t < T_OBS-1){
      const float* gbn = gin + (size_t)((t+1)*NSC + sb)*2048;
      for (int idx = tid; idx < 2048; idx += 256) xld[p^1][idx] = gbn[idx];
    }
    float accX[32], accH[32];
    #pragma unroll
    for (int j4 = 0; j4 < 32; ++j4){ accX[j4] = 0.f; accH[j4] = 0.f; }
    for (int k = 0; k < 32; ++k){
      float xk = xld[p][k*64 + lane];
      float hk = hdl[p][k*64 + lane];
      const float* wi = wihT + k*128;
      const float* wh = w2   + k*128;
      #pragma unroll
      for (int j = 0; j < 8; ++j){
        #pragma unroll
        for (int g = 0; g < 4; ++g){
          accX[j*4+g] = fmaf(wi[g*32 + ub + j], xk, accX[j*4+g]);
          accH[j*4+g] = fmaf(wh[g*32 + ub + j], hk, accH[j*4+g]);
        }
      }
    }
    double hp[8]; double s1 = 0, s2 = 0;
    #pragma unroll
    for (int j = 0; j < 8; ++j){
      double pre[4];
      #pragma unroll
      for (int g = 0; g < 4; ++g){
        int r = g*32 + ub + j;
        pre[g] = bdp[r] + (double)accX[j*4+g]
               + ri*__builtin_fma(-mu, gCw[r], (double)accH[j*4+g]);
      }
      double ig = fsig(pre[0]);
      double fg = fsig(pre[1]);
      double gg = ftanh(pre[2]);
      double og = fsig(pre[3]);
      c[j] = fg*c[j] + ig*gg;
      hp[j] = og*ftanh(c[j]);
      s1 += hp[j]; s2 += hp[j]*hp[j];
      hdl[p^1][(ub+j)*64 + lane] = (float)hp[j];
    }
    ps[wv*64+lane] = s1; pq[wv*64+lane] = s2;
    __syncthreads();
    double sa = ps[lane]+ps[64+lane]+ps[128+lane]+ps[192+lane];
    double sq = pq[lane]+pq[64+lane]+pq[128+lane]+pq[192+lane];
    mu = sa*(1.0/32.0);
    double va = sq*(1.0/32.0) - mu*mu;
    ri = fast_rsqrt(va + EPS);
    if (t == T_OBS-1){
      #pragma unroll
      for (int j = 0; j < 8; ++j){
        int u = ub + j;
        gh[ped*32 + u] = (float)((hp[j]-mu)*ri*lng[u] + lnb[u]);
      }
    }
  }
}

// ---------------- K4: pred LSTM — 2 scenes/block, persistent-LDS weights (unchanged from R12) ----------------
__global__ __launch_bounds__(512) void k_pred(
    const float* __restrict__ traj_hs, const float* __restrict__ gh,
    const float* __restrict__ zn, const float* __restrict__ obs,
    const double* __restrict__ wsd, const float* __restrict__ wsf,
    const float* __restrict__ als, float* __restrict__ out)
{
  extern __shared__ char smem[];
  float* wlds = (float*)smem;            // [25600] persistent weights
  float* hd   = wlds + 25600;            // [80][2][64]
  float* ps   = hd + 10240;
  float* pq   = ps + 1024;
  float* pw0  = pq + 1024;
  float* pw1  = pw0 + 1024;

  const float*  w2p  = wsf + OF_PW2P;
  const float*  bdf  = wsf + OF_PBDF;
  const float*  cwf  = wsf + OF_PCWF;
  const float*  wihf = wsf + OF_PWIHF;
  const double* gw   = wsd + O_PGW;
  const double* psc  = wsd + O_PSC;
  const double* pinv = wsd + O_PINV;
  const int tid = threadIdx.x, lane = tid & 63;
  const int wv = __builtin_amdgcn_readfirstlane(tid >> 6);
  const int ub = wv*10;
  const int scA = blockIdx.x*2, scB = scA + 1;
  const int pedA = scA*64 + lane, pedB = scB*64 + lane;

  for (int i = tid; i < 25600; i += 512) wlds[i] = w2p[i];
  for (int idx = tid; idx < 10240; idx += 512){
    int f = idx>>7, rem = idx&127, s = rem>>6, p = rem&63;
    int scene = scA + s;
    float v;
    if (f < 32)      v = traj_hs[((size_t)7*NTOT + scene*64 + p)*32 + f];
    else if (f < 64) v = gh[(scene*64+p)*32 + (f-32)];
    else             v = zn[scene*16 + (f-64)];
    hd[idx] = (float)(((double)v - pinv[80+f]) * pinv[f]);
  }
  {
    const int M = PRED_LEN*NTOT*2;
    float l0 = als[0], l1 = als[1];
    float e0 = (float)fast_exp((double)l0), e1 = (float)fast_exp((double)l1);
    for (int i = tid; i < PRED_LEN*128*2; i += 512){
      int t = i >> 8; int rem = i & 255; int p2 = rem >> 1; int ch = rem & 1;
      int gi = (t*NTOT + scA*64 + p2)*2 + ch;
      out[M + gi]   = ch ? l1 : l0;
      out[2*M + gi] = ch ? e1 : e0;
    }
  }
  double cA[10], cB[10];
  #pragma unroll
  for (int j = 0; j < 10; ++j){ cA[j] = 0.0; cB[j] = 0.0; }
  double x0A = (double)obs[((size_t)7*NTOT + pedA)*2 + 0];
  double x1A = (double)obs[((size_t)7*NTOT + pedA)*2 + 1];
  double x0B = (double)obs[((size_t)7*NTOT + pedB)*2 + 0];
  double x1B = (double)obs[((size_t)7*NTOT + pedB)*2 + 1];
  double muA = 0.0, riA = 1.0, invriA = 1.0;
  double muB = 0.0, riB = 1.0, invriB = 1.0;
  const double Cgw0 = psc[0], Cgw1 = psc[1], Cbw0 = psc[2], Cbw1 = psc[3];
  float gwf0[10], gwf1[10];
  #pragma unroll
  for (int j = 0; j < 10; ++j){ gwf0[j] = (float)gw[ub+j]; gwf1[j] = (float)gw[80+ub+j]; }
  __syncthreads();

  for (int t = 0; t < PRED_LEN; ++t){
    float x0Af = (float)x0A, x1Af = (float)x1A, muAf = (float)muA, ivAf = (float)invriA;
    float x0Bf = (float)x0B, x1Bf = (float)x1B, muBf = (float)muB, ivBf = (float)invriB;
    f32x2 accA[20], accB[20];
    #pragma unroll
    for (int j = 0; j < 10; ++j){
      #pragma unroll
      for (int g = 0; g < 4; ++g){
        int r = g*80 + ub + j;
        float w0r = wihf[r*2+0], w1r = wihf[r*2+1], br = bdf[r], cr = cwf[r];
        float baseA = fmaf(w1r, x1Af, fmaf(w0r, x0Af, br));
        float baseB = fmaf(w1r, x1Bf, fmaf(w0r, x0Bf, br));
        int idx = j*4+g;
        accA[idx>>1][idx&1] = fmaf(baseA, ivAf, -muAf*cr);
        accB[idx>>1][idx&1] = fmaf(baseB, ivBf, -muBf*cr);
      }
    }
    #pragma unroll 4
    for (int k = 0; k < 80; ++k){
      float hkA = hd[k*128 + lane];
      float hkB = hd[k*128 + 64 + lane];
      f32x2 h2A; h2A[0] = hkA; h2A[1] = hkA;
      f32x2 h2B; h2B[0] = hkB; h2B[1] = hkB;
      const f32x4* w4 = (const f32x4*)&wlds[k*320 + ub*4];
      #pragma unroll
      for (int q4 = 0; q4 < 10; ++q4){
        f32x4 w = w4[q4];
        f32x2 wlo; wlo[0] = w[0]; wlo[1] = w[1];
        f32x2 whi; whi[0] = w[2]; whi[1] = w[3];
        pk_fma(accA[q4*2+0], wlo, h2A);
        pk_fma(accA[q4*2+1], whi, h2A);
        pk_fma(accB[q4*2+0], wlo, h2B);
        pk_fma(accB[q4*2+1], whi, h2B);
      }
    }
    float riAf = (float)riA, riBf = (float)riB;
    float hpA[10], hpB2[10];
    float s1A = 0.f, s2A = 0.f, sw0A = 0.f, sw1A = 0.f;
    float s1B = 0.f, s2B = 0.f, sw0B = 0.f, sw1B = 0.f;
    #pragma unroll
    for (int j = 0; j < 10; ++j){
      float igA = fsig32(riAf*accA[(j*4+0)>>1][(j*4+0)&1]);
      float fgA = fsig32(riAf*accA[(j*4+1)>>1][(j*4+1)&1]);
      float ggA = ftanh32(riAf*accA[(j*4+2)>>1][(j*4+2)&1]);
      float ogA = fsig32(riAf*accA[(j*4+3)>>1][(j*4+3)&1]);
      cA[j] = (double)fgA*cA[j] + (double)(igA*ggA);
      float hA = ogA*ftanh32((float)cA[j]);
      hpA[j] = hA;
      s1A += hA; s2A += hA*hA; sw0A += hA*gwf0[j]; sw1A += hA*gwf1[j];

      float igB = fsig32(riBf*accB[(j*4+0)>>1][(j*4+0)&1]);
      float fgB = fsig32(riBf*accB[(j*4+1)>>1][(j*4+1)&1]);
      float ggB = ftanh32(riBf*accB[(j*4+2)>>1][(j*4+2)&1]);
      float ogB = fsig32(riBf*accB[(j*4+3)>>1][(j*4+3)&1]);
      cB[j] = (double)fgB*cB[j] + (double)(igB*ggB);
      float hB = ogB*ftanh32((float)cB[j]);
      hpB2[j] = hB;
      s1B += hB; s2B += hB*hB; sw0B += hB*gwf0[j]; sw1B += hB*gwf1[j];
    }
    __syncthreads();
    #pragma unroll
    for (int j = 0; j < 10; ++j){
      hd[(ub+j)*128 + lane]      = hpA[j];
      hd[(ub+j)*128 + 64 + lane] = hpB2[j];
    }
    ps[wv*128 + lane] = s1A;  ps[wv*128 + 64 + lane] = s1B;
    pq[wv*128 + lane] = s2A;  pq[wv*128 + 64 + lane] = s2B;
    pw0[wv*128 + lane] = sw0A; pw0[wv*128 + 64 + lane] = sw0B;
    pw1[wv*128 + lane] = sw1A; pw1[wv*128 + 64 + lane] = sw1B;
    __syncthreads();
    double saA = 0, sqA = 0, t0A = 0, t1A = 0;
    double saB = 0, sqB = 0, t0B = 0, t1B = 0;
    #pragma unroll
    for (int w = 0; w < 8; ++w){
      saA += (double)ps[w*128 + lane];      sqA += (double)pq[w*128 + lane];
      t0A += (double)pw0[w*128 + lane];     t1A += (double)pw1[w*128 + lane];
      saB += (double)ps[w*128 + 64 + lane]; sqB += (double)pq[w*128 + 64 + lane];
      t0B += (double)pw0[w*128 + 64 + lane];t1B += (double)pw1[w*128 + 64 + lane];
    }
    muA = saA*(1.0/80.0);
    double vaA = sqA*(1.0/80.0) - muA*muA;
    riA = fast_rsqrt(vaA + EPS); invriA = (vaA + EPS)*riA;
    x0A = riA*__builtin_fma(-muA, Cgw0, t0A) + Cbw0;
    x1A = riA*__builtin_fma(-muA, Cgw1, t1A) + Cbw1;
    muB = saB*(1.0/80.0);
    double vaB = sqB*(1.0/80.0) - muB*muB;
    riB = fast_rsqrt(vaB + EPS); invriB = (vaB + EPS)*riB;
    x0B = riB*__builtin_fma(-muB, Cgw0, t0B) + Cbw0;
    x1B = riB*__builtin_fma(-muB, Cgw1, t1B) + Cbw1;
    if (wv == 0){
      out[((size_t)t*NTOT + pedA)*2 + 0] = (float)x0A;
      out[((size_t)t*NTOT + pedA)*2 + 1] = (float)x1A;
    } else if (wv == 1){
      out[((size_t)t*NTOT + pedB)*2 + 0] = (float)x0B;
      out[((size_t)t*NTOT + pedB)*2 + 1] = (float)x1B;
    }
  }
}

extern "C" void kernel_launch(void* const* d_in, const int* in_sizes, int n_in,
                              void* d_out, int out_size, void* d_ws, size_t ws_size,
                              hipStream_t stream)
{
  const float* obs   = (const float*)d_in[0];
  const float* zn    = (const float*)d_in[2];
  const float* th0   = (const float*)d_in[3];
  const float* tc0   = (const float*)d_in[4];
  const float* gh0   = (const float*)d_in[5];
  const float* gc0   = (const float*)d_in[6];
  const float* gw0   = (const float*)d_in[7];
  const float* gas0  = (const float*)d_in[8];
  const float* gad0  = (const float*)d_in[9];
  const float* gb0   = (const float*)d_in[10];
  const float* gw1   = (const float*)d_in[11];
  const float* gas1  = (const float*)d_in[12];
  const float* gad1  = (const float*)d_in[13];
  const float* gb1   = (const float*)d_in[14];
  const float* twih  = (const float*)d_in[15];
  const float* twhh  = (const float*)d_in[16];
  const float* tbih  = (const float*)d_in[17];
  const float* tbhh  = (const float*)d_in[18];
  const float* gwih  = (const float*)d_in[19];
  const float* gwhh  = (const float*)d_in[20];
  const float* gbih  = (const float*)d_in[21];
  const float* gbhh  = (const float*)d_in[22];
  const float* glng  = (const float*)d_in[23];
  const float* glnb  = (const float*)d_in[24];
  const float* pwih  = (const float*)d_in[25];
  const float* pwhh  = (const float*)d_in[26];
  const float* pbih  = (const float*)d_in[27];
  const float* pbhh  = (const float*)d_in[28];
  const float* plng  = (const float*)d_in[29];
  const float* plnb  = (const float*)d_in[30];
  const float* poww  = (const float*)d_in[31];
  const float* pob   = (const float*)d_in[32];
  const float* als   = (const float*)d_in[33];

  float* out = (float*)d_out;
  double* wsd = (double*)d_ws;
  float* wsf = (float*)(wsd + D_TOTAL);             // fp32 region
  float* traj_hs = wsf + F_TOTAL;                   // [8][NTOT][32]
  float* gin     = traj_hs + (size_t)8*NTOT*32;     // [8][NSC][32][64]
  float* gh      = gin + (size_t)8*NTOT*32;         // [NTOT][32]

  (void)hipFuncSetAttribute((const void*)k_pred,
                            hipFuncAttributeMaxDynamicSharedMemorySize,
                            PRED_LDS_BYTES);

  k_prep<<<dim3(104), dim3(256), 0, stream>>>(
      pwhh, pwih, pbih, pbhh, plng, plnb, poww, pob,
      twih, twhh, tbih, tbhh, gwih, gwhh, gbih, gbhh, glng, glnb,
      gw0, gas0, gad0, gb0, gw1, gas1, gad1, gb1, wsd, wsf);
  k_traj<<<dim3(512), dim3(256), 0, stream>>>(obs, th0, tc0, wsd, wsf, traj_hs);
  k_gat<<<dim3(4096), dim3(256), 0, stream>>>(traj_hs, wsd, wsf, gin);
  k_graph<<<dim3(512), dim3(256), 0, stream>>>(gin, gh0, gc0, wsd, wsf, gh);
  k_pred<<<dim3(256), dim3(512), PRED_LDS_BYTES, stream>>>(traj_hs, gh, zn, obs, wsd, wsf, als, out);
}

// Round 14
// 830.246 us; speedup vs baseline: 2.0205x; 1.0448x over previous
//
#include <hip/hip_runtime.h>
#include <math.h>

#define T_OBS 8
#define PRED_LEN 12
#define NSC 512
#define NPED 64
#define NTOT (NSC*NPED)
#define EPS 1e-5

typedef float f32x2 __attribute__((ext_vector_type(2)));
typedef float f32x4 __attribute__((ext_vector_type(4)));

// ---- wsd (fp64) offsets, in doubles ----
#define O_PGW    26880    // gw0[80], gw1[80]
#define O_PSC    27040    // Cgw0, Cgw1, Cbw0+bout0, Cbw1+bout1
#define O_PINV   27048    // invg[80], b[80]
#define O_GBD    39880    // graph bih+bhh+gCb [128]
#define O_GCW    40008    // gCw[r] [128]
#define O_GLNG   40136
#define O_GLNB   40168
#define O_GINV   40200    // ginvg[32], gb[32]
#define O_A0S    42312    // gat a0s fp64 [64]
#define O_A0D    42376
#define O_A1S    44504    // [32]
#define O_A1D    44536
#define D_TOTAL  44600
// ---- wsf (fp32) offsets, in floats ----
#define OF_PW2P   0        // pred whh^T g-folded fp32 PACKED [80 k][8 wv][40 j4]
#define OF_PBDF   25600    // fp32 bih+bhh+Cb [320]
#define OF_PCWF   25920    // fp32 Cw [320]
#define OF_PWIHF  26240    // fp32 wih [320][2]
#define OF_TWIHF  26880    // traj wih fp32 [128][2]
#define OF_TWHHTF 27136    // traj whh^T fp32 [32 k][128 r]
#define OF_TBF    31232    // traj bih+bhh fp32 [128]
#define OF_GWIHTF 31360    // graph wih^T fp32 [32][128]
#define OF_GW2F   35456    // graph whh^T g-folded fp32 [32][128]
#define OF_W0F    39936    // gat w0 fp32 [2048]
#define OF_B0F    42112    // gat b0 fp32 [16]
#define OF_W1F    42128    // gat w1 fp32 [2048]
#define OF_B1F    44240    // gat b1 fp32 [32]
#define F_TOTAL   44272

// dynamic-LDS for k_pred (2 scenes/block)
#define PRED_LDS_BYTES 159744

// ---------- fast fp64 math (validated bit-identical absmax R3-R13) ----------
__device__ __forceinline__ double fast_exp(double x){
  x = fmin(fmax(x, -708.0), 708.0);
  const double L2E  = 1.4426950408889634074;
  const double LN2H = 6.93147180369123816490e-01;
  const double LN2L = 1.90821492927058770002e-10;
  double t = x*L2E;
  double n = rint(t);
  int ni = (int)n;
  double r = __builtin_fma(-n, LN2H, x);
  r = __builtin_fma(-n, LN2L, r);
  double p = 2.08767569878681e-09;
  p = __builtin_fma(p, r, 2.505210838544172e-08);
  p = __builtin_fma(p, r, 2.755731922398589e-07);
  p = __builtin_fma(p, r, 2.755731922398589e-06);
  p = __builtin_fma(p, r, 2.480158730158730e-05);
  p = __builtin_fma(p, r, 1.984126984126984e-04);
  p = __builtin_fma(p, r, 1.388888888888889e-03);
  p = __builtin_fma(p, r, 8.333333333333333e-03);
  p = __builtin_fma(p, r, 4.166666666666667e-02);
  p = __builtin_fma(p, r, 1.666666666666667e-01);
  p = __builtin_fma(p, r, 0.5);
  p = __builtin_fma(p, r, 1.0);
  p = __builtin_fma(p, r, 1.0);
  double s = __hiloint2double((ni + 1023) << 20, 0);
  return p*s;
}
__device__ __forceinline__ double fast_rcp(double d){
#if __has_builtin(__builtin_amdgcn_rcp)
  double r = __builtin_amdgcn_rcp(d);
#else
  double r = 1.0/d;
#endif
  double e = __builtin_fma(-d, r, 1.0); r = __builtin_fma(r, e, r);
  e = __builtin_fma(-d, r, 1.0); r = __builtin_fma(r, e, r);
  e = __builtin_fma(-d, r, 1.0); r = __builtin_fma(r, e, r);
  return r;
}
__device__ __forceinline__ double fast_rsqrt(double d){
#if __has_builtin(__builtin_amdgcn_rsq)
  double r = __builtin_amdgcn_rsq(d);
#else
  double r = 1.0/sqrt(d);
#endif
  double hr = 0.5*d;
  r = r*__builtin_fma(-hr*r, r, 1.5);
  r = r*__builtin_fma(-hr*r, r, 1.5);
  r = r*__builtin_fma(-hr*r, r, 1.5);
  return r;
}
__device__ __forceinline__ double fsig(double x){
  double xc = fmin(fmax(x, -40.0), 40.0);
  return fast_rcp(1.0 + fast_exp(-xc));
}
__device__ __forceinline__ double ftanh(double x){
  double xc = fmin(fmax(x, -20.0), 20.0);
  return __builtin_fma(-2.0, fast_rcp(1.0 + fast_exp(2.0*xc)), 1.0);
}
// ---------- mixed-precision gates (encoder LSTMs): fp32 hw exp, fp64 rcp ----------
// abs error ~2.5e-8 on gate value — same class as fp32 h-storage rounding.
__device__ __forceinline__ double fsig_m(double x){
  float xf = (float)fmin(fmax(x, -30.0), 30.0);
  double e = (double)__expf(-xf);
  return fast_rcp(1.0 + e);
}
__device__ __forceinline__ double ftanh_m(double x){
  float xf = (float)fmin(fmax(x, -15.0), 15.0);
  double e = (double)__expf(2.0f*xf);
  return __builtin_fma(-2.0, fast_rcp(1.0 + e), 1.0);
}
// ---------- fp32 fast gates (k_pred only — validated at floor R7-R13) ----------
__device__ __forceinline__ float fsig32(float x){
  x = fminf(fmaxf(x, -30.f), 30.f);
  return 1.0f/(1.0f + __expf(-x));
}
__device__ __forceinline__ float ftanh32(float x){
  x = fminf(fmaxf(x, -15.f), 15.f);
  return 1.0f - 2.0f/(1.0f + __expf(2.f*x));
}
// packed dual-fp32 FMA (CDNA VOP3P)
__device__ __forceinline__ void pk_fma(f32x2 &a, f32x2 w, f32x2 h){
  asm("v_pk_fma_f32 %0, %1, %2, %0" : "+v"(a) : "v"(w), "v"(h));
}

// ---------------- prep (unchanged from R13) ----------------
__global__ void k_prep(
    const float* __restrict__ pwhh, const float* __restrict__ pwih,
    const float* __restrict__ pbih, const float* __restrict__ pbhh,
    const float* __restrict__ plng, const float* __restrict__ plnb,
    const float* __restrict__ pwout, const float* __restrict__ pbout,
    const float* __restrict__ twih, const float* __restrict__ twhh,
    const float* __restrict__ tbih, const float* __restrict__ tbhh,
    const float* __restrict__ gwih, const float* __restrict__ gwhh,
    const float* __restrict__ gbih, const float* __restrict__ gbhh,
    const float* __restrict__ glng, const float* __restrict__ glnb,
    const float* __restrict__ w0, const float* __restrict__ a0s,
    const float* __restrict__ a0d, const float* __restrict__ b0,
    const float* __restrict__ w1, const float* __restrict__ a1s,
    const float* __restrict__ a1d, const float* __restrict__ b1,
    double* __restrict__ wsd, float* __restrict__ wsf)
{
  int i = blockIdx.x*256 + threadIdx.x;
  if (i < 25600){
    int kk = i/320, rem = i - kk*320;
    int wv = rem/40, j4 = rem - wv*40;
    int j = j4>>2, g = j4&3;
    int r = g*80 + wv*10 + j;
    wsf[OF_PW2P + i] = (float)((double)pwhh[r*80 + kk] * (double)plng[kk]);
  }
  if (i < 640) wsf[OF_PWIHF + i] = pwih[i];
  if (i < 320){
    double s = 0, sb = 0;
    for (int k = 0; k < 80; ++k){
      double w = (double)pwhh[i*80 + k];
      s  += w*(double)plng[k];
      sb += w*(double)plnb[k];
    }
    wsf[OF_PCWF + i] = (float)s;
    wsf[OF_PBDF + i] = (float)((double)pbih[i] + (double)pbhh[i] + sb);
  }
  if (i < 160){
    if (i < 80) wsd[O_PGW + i] = (double)plng[i]*(double)pwout[i];
    else        wsd[O_PGW + i] = (double)plng[i-80]*(double)pwout[80 + (i-80)];
  }
  if (i < 4){
    double s = 0;
    if (i == 0){ for (int u = 0; u < 80; ++u) s += (double)plng[u]*(double)pwout[u]; }
    if (i == 1){ for (int u = 0; u < 80; ++u) s += (double)plng[u]*(double)pwout[80+u]; }
    if (i == 2){ for (int u = 0; u < 80; ++u) s += (double)plnb[u]*(double)pwout[u]; s += (double)pbout[0]; }
    if (i == 3){ for (int u = 0; u < 80; ++u) s += (double)plnb[u]*(double)pwout[80+u]; s += (double)pbout[1]; }
    wsd[O_PSC + i] = s;
  }
  if (i < 160){
    if (i < 80) wsd[O_PINV + i] = 1.0/(double)plng[i];
    else        wsd[O_PINV + i] = (double)plnb[i-80];
  }
  if (i < 256) wsf[OF_TWIHF + i] = twih[i];
  if (i < 4096){
    int r = i>>5, k = i&31;
    wsf[OF_TWHHTF + k*128 + r] = twhh[i];
    wsf[OF_GWIHTF + k*128 + r] = gwih[i];
    wsf[OF_GW2F   + k*128 + r] = (float)((double)gwhh[i]*(double)glng[k]);
  }
  if (i < 128){
    wsf[OF_TBF + i] = (float)((double)tbih[i] + (double)tbhh[i]);
    double s = 0, sb = 0;
    for (int k = 0; k < 32; ++k){
      double w = (double)gwhh[i*32 + k];
      s  += w*(double)glng[k];
      sb += w*(double)glnb[k];
    }
    wsd[O_GCW + i] = s;
    wsd[O_GBD + i] = (double)gbih[i] + (double)gbhh[i] + sb;
  }
  if (i < 32){
    wsd[O_GLNG + i] = (double)glng[i]; wsd[O_GLNB + i] = (double)glnb[i];
    wsd[O_GINV + i] = 1.0/(double)glng[i];
    wsd[O_GINV + 32 + i] = (double)glnb[i];
    wsd[O_A1S + i] = (double)a1s[i]; wsd[O_A1D + i] = (double)a1d[i];
    wsf[OF_B1F + i] = b1[i];
  }
  if (i < 2048){ wsf[OF_W0F + i] = w0[i]; wsf[OF_W1F + i] = w1[i]; }
  if (i < 64){ wsd[O_A0S + i] = (double)a0s[i]; wsd[O_A0D + i] = (double)a0d[i]; }
  if (i < 16) wsf[OF_B0F + i] = b0[i];
}

// ---------------- K1: traj LSTM — fp32 GEMV, mixed gates ----------------
__global__ __launch_bounds__(256) void k_traj(
    const float* __restrict__ obs, const float* __restrict__ h0,
    const float* __restrict__ c0, const double* __restrict__ wsd,
    const float* __restrict__ wsf, float* __restrict__ traj_hs)
{
  __shared__ float hdl[2][2048];
  const float* wih  = wsf + OF_TWIHF;
  const float* whhT = wsf + OF_TWHHTF;
  const float* bd   = wsf + OF_TBF;
  const int tid = threadIdx.x, lane = tid & 63;
  const int wv = __builtin_amdgcn_readfirstlane(tid >> 6);
  const int ub = wv*8;
  const int ped0 = blockIdx.x*64, ped = ped0 + lane;
  for (int idx = tid; idx < 2048; idx += 256){
    int f = idx>>6, p = idx&63;
    hdl[0][idx] = h0[(ped0+p)*32 + f];
  }
  double c[8];
  #pragma unroll
  for (int j = 0; j < 8; ++j) c[j] = (double)c0[ped*32 + ub + j];
  __syncthreads();

  for (int t = 0; t < T_OBS; ++t){
    const int p = t & 1;
    float x0 = obs[((size_t)t*NTOT + ped)*2 + 0];
    float x1 = obs[((size_t)t*NTOT + ped)*2 + 1];
    float acc[32];
    #pragma unroll
    for (int j = 0; j < 8; ++j){
      #pragma unroll
      for (int g = 0; g < 4; ++g){
        int r = g*32 + ub + j;
        acc[j*4+g] = fmaf(wih[r*2+1], x1, fmaf(wih[r*2+0], x0, bd[r]));
      }
    }
    for (int k = 0; k < 32; ++k){
      float hk = hdl[p][k*64 + lane];
      const float* wh = whhT + k*128;
      #pragma unroll
      for (int j = 0; j < 8; ++j){
        #pragma unroll
        for (int g = 0; g < 4; ++g) acc[j*4+g] = fmaf(wh[g*32 + ub + j], hk, acc[j*4+g]);
      }
    }
    #pragma unroll
    for (int j = 0; j < 8; ++j){
      double ig = fsig_m((double)acc[j*4+0]);
      double fg = fsig_m((double)acc[j*4+1]);
      double gg = ftanh_m((double)acc[j*4+2]);
      double og = fsig_m((double)acc[j*4+3]);
      c[j] = fg*c[j] + ig*gg;
      float hn = (float)(og*ftanh_m(c[j]));
      hdl[p^1][(ub+j)*64 + lane] = hn;
      traj_hs[((size_t)t*NTOT + ped)*32 + ub + j] = hn;
    }
    __syncthreads();
  }
}

// ---------------- K2: GAT (unchanged from R13) ----------------
__global__ __launch_bounds__(256) void k_gat(
    const float* __restrict__ ths, const double* __restrict__ wsd,
    const float* __restrict__ wsf, float* __restrict__ gout)
{
  __shared__ float xA[64*65];
  __shared__ float hpB[64*68];
  __shared__ double as0[256], ad0[256];
  __shared__ double as1[64], ad1[64], mn[64], rs[64];
  __shared__ float zS[256];

  const float*  w0  = wsf + OF_W0F;
  const double* a0s = wsd + O_A0S;
  const double* a0d = wsd + O_A0D;
  const float*  b0  = wsf + OF_B0F;
  const float*  w1  = wsf + OF_W1F;
  const double* a1s = wsd + O_A1S;
  const double* a1d = wsd + O_A1D;
  const float*  b1  = wsf + OF_B1F;

  const int tid = threadIdx.x;
  const int sb = blockIdx.x >> 3, tb = blockIdx.x & 7;
  const int n = tid & 63;
  const int q = __builtin_amdgcn_readfirstlane(tid >> 6);

  const float* xin = ths + ((size_t)tb*NTOT + sb*64)*32;
  for (int idx = tid; idx < 2048; idx += 256)
    xA[(idx>>5)*65 + (idx&31)] = xin[idx];
  __syncthreads();
  {
    int f = tid & 31, g = tid >> 5;
    double s1 = 0, s2 = 0;
    #pragma unroll
    for (int pp = 0; pp < 8; ++pp){
      double v = xA[(g*8+pp)*65 + f];
      s1 += v; s2 += v*v;
    }
    as0[g*32+f] = s1; ad0[g*32+f] = s2;
  }
  __syncthreads();
  if (tid < 32){
    double s1 = 0, s2 = 0;
    #pragma unroll
    for (int g = 0; g < 8; ++g){ s1 += as0[g*32+tid]; s2 += ad0[g*32+tid]; }
    double mu = s1*(1.0/64.0), va = s2*(1.0/64.0) - mu*mu;
    mn[tid] = mu; rs[tid] = fast_rsqrt(va + EPS);
  }
  __syncthreads();
  for (int idx = tid; idx < 2048; idx += 256){
    int p = idx>>5, f = idx&31;
    xA[p*65+f] = (float)(((double)xA[p*65+f] - mn[f])*rs[f]);
  }
  __syncthreads();
  {
    float acc[16];
    #pragma unroll
    for (int o = 0; o < 16; ++o) acc[o] = 0.f;
    for (int f = 0; f < 32; ++f){
      float xv = xA[n*65+f];
      const float* wr = w0 + (q*32+f)*16;
      #pragma unroll
      for (int o = 0; o < 16; ++o) acc[o] = fmaf(xv, wr[o], acc[o]);
    }
    double sa = 0, sd = 0;
    #pragma unroll
    for (int o = 0; o < 16; ++o){
      sa += (double)acc[o]*a0s[q*16+o];
      sd += (double)acc[o]*a0d[q*16+o];
      hpB[n*68 + q*16 + o] = acc[o];
    }
    as0[q*64+n] = sa; ad0[q*64+n] = sd;
  }
  __syncthreads();
  {
    float arow = (float)as0[q*64+n];
    f32x2 num2[8];
    #pragma unroll
    for (int o2 = 0; o2 < 8; ++o2){ num2[o2][0] = 0.f; num2[o2][1] = 0.f; }
    float Z = 0.f;
    for (int m2 = 0; m2 < 64; ++m2){
      float e = arow + (float)ad0[q*64+m2];
      float lr = e > 0.f ? e : 0.2f*e;
      float pv = __expf(lr - 30.0f);
      Z += pv;
      f32x2 p2; p2[0] = pv; p2[1] = pv;
      const f32x4* h4 = (const f32x4*)&hpB[m2*68 + q*16];
      #pragma unroll
      for (int o4 = 0; o4 < 4; ++o4){
        f32x4 v = h4[o4];
        f32x2 vlo; vlo[0] = v[0]; vlo[1] = v[1];
        f32x2 vhi; vhi[0] = v[2]; vhi[1] = v[3];
        pk_fma(num2[o4*2+0], vlo, p2);
        pk_fma(num2[o4*2+1], vhi, p2);
      }
    }
    float iZ = 1.0f/Z;
    #pragma unroll
    for (int o = 0; o < 16; ++o){
      float y = num2[o>>1][o&1]*iZ + b0[o];
      xA[n*65 + q*16 + o] = y > 0.f ? y : __expf(y)-1.0f;
    }
  }
  __syncthreads();
  {
    int f = tid & 63, g = tid >> 6;
    double s1 = 0, s2 = 0;
    #pragma unroll
    for (int pp = 0; pp < 16; ++pp){
      double v = xA[(g*16+pp)*65 + f];
      s1 += v; s2 += v*v;
    }
    as0[g*64+f] = s1; ad0[g*64+f] = s2;
  }
  __syncthreads();
  if (tid < 64){
    double s1 = as0[tid]+as0[64+tid]+as0[128+tid]+as0[192+tid];
    double s2 = ad0[tid]+ad0[64+tid]+ad0[128+tid]+ad0[192+tid];
    double mu = s1*(1.0/64.0), va = s2*(1.0/64.0) - mu*mu;
    mn[tid] = mu; rs[tid] = fast_rsqrt(va + EPS);
  }
  __syncthreads();
  for (int idx = tid; idx < 4096; idx += 256){
    int p = idx>>6, f = idx&63;
    xA[p*65+f] = (float)(((double)xA[p*65+f] - mn[f])*rs[f]);
  }
  __syncthreads();
  {
    float a8[8];
    #pragma unroll
    for (int j = 0; j < 8; ++j) a8[j] = 0.f;
    for (int f = 0; f < 64; ++f){
      float xv = xA[n*65+f];
      const float* wr = w1 + f*32 + q*8;
      #pragma unroll
      for (int j = 0; j < 8; ++j) a8[j] = fmaf(xv, wr[j], a8[j]);
    }
    #pragma unroll
    for (int j = 0; j < 8; ++j) hpB[n*68 + q*8 + j] = a8[j];
  }
  __syncthreads();
  {
    double sa = 0, sd = 0;
    #pragma unroll
    for (int o = 0; o < 8; ++o){
      double v = (double)hpB[n*68 + q*8 + o];
      sa += v*a1s[q*8+o]; sd += v*a1d[q*8+o];
    }
    as0[q*64+n] = sa; ad0[q*64+n] = sd;
  }
  __syncthreads();
  if (tid < 128){
    int n2 = tid & 63;
    if (tid < 64) as1[n2] = as0[n2]+as0[64+n2]+as0[128+n2]+as0[192+n2];
    else          ad1[n2] = ad0[n2]+ad0[64+n2]+ad0[128+n2]+ad0[192+n2];
  }
  __syncthreads();
  {
    float arow = (float)as1[n];
    float zp = 0.f;
    for (int m2 = q*16; m2 < q*16+16; ++m2){
      float e = arow + (float)ad1[m2];
      float lr = e > 0.f ? e : 0.2f*e;
      float pv = __expf(lr - 30.0f);
      zp += pv;
      xA[n*65+m2] = pv;
    }
    zS[q*64+n] = zp;
  }
  __syncthreads();
  {
    float Z = zS[n]+zS[64+n]+zS[128+n]+zS[192+n];
    float iZ = 1.0f/Z;
    f32x2 a2[4];
    #pragma unroll
    for (int j2 = 0; j2 < 4; ++j2){ a2[j2][0] = 0.f; a2[j2][1] = 0.f; }
    for (int m2 = 0; m2 < 64; ++m2){
      float av = xA[n*65+m2];
      f32x2 p2; p2[0] = av; p2[1] = av;
      const f32x4* h4 = (const f32x4*)&hpB[m2*68 + q*8];
      f32x4 v0 = h4[0], v1 = h4[1];
      f32x2 w00; w00[0] = v0[0]; w00[1] = v0[1];
      f32x2 w01; w01[0] = v0[2]; w01[1] = v0[3];
      f32x2 w10; w10[0] = v1[0]; w10[1] = v1[1];
      f32x2 w11; w11[0] = v1[2]; w11[1] = v1[3];
      pk_fma(a2[0], w00, p2);
      pk_fma(a2[1], w01, p2);
      pk_fma(a2[2], w10, p2);
      pk_fma(a2[3], w11, p2);
    }
    float* go = gout + ((size_t)(tb*NSC + sb)*32)*64;
    #pragma unroll
    for (int j = 0; j < 8; ++j)
      go[(q*8+j)*64 + n] = a2[j>>1][j&1]*iZ + b1[q*8+j];
  }
}

// ---------------- K3: graph LSTM — fp32 GEMVs, mixed gates, fp64 LN ----------------
__global__ __launch_bounds__(256) void k_graph(
    const float* __restrict__ gin, const float* __restrict__ h0,
    const float* __restrict__ c0, const double* __restrict__ wsd,
    const float* __restrict__ wsf, float* __restrict__ gh)
{
  __shared__ float hdl[2][2048];
  __shared__ float xld[2][2048];
  __shared__ double ps[256], pq[256];
  const float*  wihT = wsf + OF_GWIHTF;
  const float*  w2   = wsf + OF_GW2F;
  const double* bdp  = wsd + O_GBD;
  const double* gCw  = wsd + O_GCW;
  const double* lng  = wsd + O_GLNG;
  const double* lnb  = wsd + O_GLNB;
  const double* ginv = wsd + O_GINV;
  const int tid = threadIdx.x, lane = tid & 63;
  const int wv = __builtin_amdgcn_readfirstlane(tid >> 6);
  const int ub = wv*8;
  const int sb = blockIdx.x, ped0 = sb*64, ped = ped0 + lane;
  for (int idx = tid; idx < 2048; idx += 256){
    int f = idx>>6, p = idx&63;
    hdl[0][idx] = (float)(((double)h0[(ped0+p)*32 + f] - ginv[32+f]) * ginv[f]);
  }
  {
    const float* gb0p = gin + (size_t)(0*NSC + sb)*2048;
    for (int idx = tid; idx < 2048; idx += 256) xld[0][idx] = gb0p[idx];
  }
  double c[8];
  #pragma unroll
  for (int j = 0; j < 8; ++j) c[j] = (double)c0[ped*32 + ub + j];
  double mu = 0.0, ri = 1.0;
  __syncthreads();

  for (int t = 0; t < T_OBS; ++t){
    const int p = t & 1;
    if (t < T_OBS-1){
      const float* gbn = gin + (size_t)((t+1)*NSC + sb)*2048;
      for (int idx = tid; idx < 2048; idx += 256) xld[p^1][idx] = gbn[idx];
    }
    float accX[32], accH[32];
    #pragma unroll
    for (int j4 = 0; j4 < 32; ++j4){ accX[j4] = 0.f; accH[j4] = 0.f; }
    for (int k = 0; k < 32; ++k){
      float xk = xld[p][k*64 + lane];
      float hk = hdl[p][k*64 + lane];
      const float* wi = wihT + k*128;
      const float* wh = w2   + k*128;
      #pragma unroll
      for (int j = 0; j < 8; ++j){
        #pragma unroll
        for (int g = 0; g < 4; ++g){
          accX[j*4+g] = fmaf(wi[g*32 + ub + j], xk, accX[j*4+g]);
          accH[j*4+g] = fmaf(wh[g*32 + ub + j], hk, accH[j*4+g]);
        }
      }
    }
    double hp[8]; double s1 = 0, s2 = 0;
    #pragma unroll
    for (int j = 0; j < 8; ++j){
      double pre[4];
      #pragma unroll
      for (int g = 0; g < 4; ++g){
        int r = g*32 + ub + j;
        pre[g] = bdp[r] + (double)accX[j*4+g]
               + ri*__builtin_fma(-mu, gCw[r], (double)accH[j*4+g]);
      }
      double ig = fsig_m(pre[0]);
      double fg = fsig_m(pre[1]);
      double gg = ftanh_m(pre[2]);
      double og = fsig_m(pre[3]);
      c[j] = fg*c[j] + ig*gg;
      hp[j] = og*ftanh_m(c[j]);
      s1 += hp[j]; s2 += hp[j]*hp[j];
      hdl[p^1][(ub+j)*64 + lane] = (float)hp[j];
    }
    ps[wv*64+lane] = s1; pq[wv*64+lane] = s2;
    __syncthreads();
    double sa = ps[lane]+ps[64+lane]+ps[128+lane]+ps[192+lane];
    double sq = pq[lane]+pq[64+lane]+pq[128+lane]+pq[192+lane];
    mu = sa*(1.0/32.0);
    double va = sq*(1.0/32.0) - mu*mu;
    ri = fast_rsqrt(va + EPS);
    if (t == T_OBS-1){
      #pragma unroll
      for (int j = 0; j < 8; ++j){
        int u = ub + j;
        gh[ped*32 + u] = (float)((hp[j]-mu)*ri*lng[u] + lnb[u]);
      }
    }
  }
}

// ---------------- K4: pred LSTM — 2 scenes/block, persistent-LDS weights (unchanged) ----------------
__global__ __launch_bounds__(512) void k_pred(
    const float* __restrict__ traj_hs, const float* __restrict__ gh,
    const float* __restrict__ zn, const float* __restrict__ obs,
    const double* __restrict__ wsd, const float* __restrict__ wsf,
    const float* __restrict__ als, float* __restrict__ out)
{
  extern __shared__ char smem[];
  float* wlds = (float*)smem;            // [25600] persistent weights
  float* hd   = wlds + 25600;            // [80][2][64]
  float* ps   = hd + 10240;
  float* pq   = ps + 1024;
  float* pw0  = pq + 1024;
  float* pw1  = pw0 + 1024;

  const float*  w2p  = wsf + OF_PW2P;
  const float*  bdf  = wsf + OF_PBDF;
  const float*  cwf  = wsf + OF_PCWF;
  const float*  wihf = wsf + OF_PWIHF;
  const double* gw   = wsd + O_PGW;
  const double* psc  = wsd + O_PSC;
  const double* pinv = wsd + O_PINV;
  const int tid = threadIdx.x, lane = tid & 63;
  const int wv = __builtin_amdgcn_readfirstlane(tid >> 6);
  const int ub = wv*10;
  const int scA = blockIdx.x*2, scB = scA + 1;
  const int pedA = scA*64 + lane, pedB = scB*64 + lane;

  for (int i = tid; i < 25600; i += 512) wlds[i] = w2p[i];
  for (int idx = tid; idx < 10240; idx += 512){
    int f = idx>>7, rem = idx&127, s = rem>>6, p = rem&63;
    int scene = scA + s;
    float v;
    if (f < 32)      v = traj_hs[((size_t)7*NTOT + scene*64 + p)*32 + f];
    else if (f < 64) v = gh[(scene*64+p)*32 + (f-32)];
    else             v = zn[scene*16 + (f-64)];
    hd[idx] = (float)(((double)v - pinv[80+f]) * pinv[f]);
  }
  {
    const int M = PRED_LEN*NTOT*2;
    float l0 = als[0], l1 = als[1];
    float e0 = (float)fast_exp((double)l0), e1 = (float)fast_exp((double)l1);
    for (int i = tid; i < PRED_LEN*128*2; i += 512){
      int t = i >> 8; int rem = i & 255; int p2 = rem >> 1; int ch = rem & 1;
      int gi = (t*NTOT + scA*64 + p2)*2 + ch;
      out[M + gi]   = ch ? l1 : l0;
      out[2*M + gi] = ch ? e1 : e0;
    }
  }
  double cA[10], cB[10];
  #pragma unroll
  for (int j = 0; j < 10; ++j){ cA[j] = 0.0; cB[j] = 0.0; }
  double x0A = (double)obs[((size_t)7*NTOT + pedA)*2 + 0];
  double x1A = (double)obs[((size_t)7*NTOT + pedA)*2 + 1];
  double x0B = (double)obs[((size_t)7*NTOT + pedB)*2 + 0];
  double x1B = (double)obs[((size_t)7*NTOT + pedB)*2 + 1];
  double muA = 0.0, riA = 1.0, invriA = 1.0;
  double muB = 0.0, riB = 1.0, invriB = 1.0;
  const double Cgw0 = psc[0], Cgw1 = psc[1], Cbw0 = psc[2], Cbw1 = psc[3];
  float gwf0[10], gwf1[10];
  #pragma unroll
  for (int j = 0; j < 10; ++j){ gwf0[j] = (float)gw[ub+j]; gwf1[j] = (float)gw[80+ub+j]; }
  __syncthreads();

  for (int t = 0; t < PRED_LEN; ++t){
    float x0Af = (float)x0A, x1Af = (float)x1A, muAf = (float)muA, ivAf = (float)invriA;
    float x0Bf = (float)x0B, x1Bf = (float)x1B, muBf = (float)muB, ivBf = (float)invriB;
    f32x2 accA[20], accB[20];
    #pragma unroll
    for (int j = 0; j < 10; ++j){
      #pragma unroll
      for (int g = 0; g < 4; ++g){
        int r = g*80 + ub + j;
        float w0r = wihf[r*2+0], w1r = wihf[r*2+1], br = bdf[r], cr = cwf[r];
        float baseA = fmaf(w1r, x1Af, fmaf(w0r, x0Af, br));
        float baseB = fmaf(w1r, x1Bf, fmaf(w0r, x0Bf, br));
        int idx = j*4+g;
        accA[idx>>1][idx&1] = fmaf(baseA, ivAf, -muAf*cr);
        accB[idx>>1][idx&1] = fmaf(baseB, ivBf, -muBf*cr);
      }
    }
    #pragma unroll 4
    for (int k = 0; k < 80; ++k){
      float hkA = hd[k*128 + lane];
      float hkB = hd[k*128 + 64 + lane];
      f32x2 h2A; h2A[0] = hkA; h2A[1] = hkA;
      f32x2 h2B; h2B[0] = hkB; h2B[1] = hkB;
      const f32x4* w4 = (const f32x4*)&wlds[k*320 + ub*4];
      #pragma unroll
      for (int q4 = 0; q4 < 10; ++q4){
        f32x4 w = w4[q4];
        f32x2 wlo; wlo[0] = w[0]; wlo[1] = w[1];
        f32x2 whi; whi[0] = w[2]; whi[1] = w[3];
        pk_fma(accA[q4*2+0], wlo, h2A);
        pk_fma(accA[q4*2+1], whi, h2A);
        pk_fma(accB[q4*2+0], wlo, h2B);
        pk_fma(accB[q4*2+1], whi, h2B);
      }
    }
    float riAf = (float)riA, riBf = (float)riB;
    float hpA[10], hpB2[10];
    float s1A = 0.f, s2A = 0.f, sw0A = 0.f, sw1A = 0.f;
    float s1B = 0.f, s2B = 0.f, sw0B = 0.f, sw1B = 0.f;
    #pragma unroll
    for (int j = 0; j < 10; ++j){
      float igA = fsig32(riAf*accA[(j*4+0)>>1][(j*4+0)&1]);
      float fgA = fsig32(riAf*accA[(j*4+1)>>1][(j*4+1)&1]);
      float ggA = ftanh32(riAf*accA[(j*4+2)>>1][(j*4+2)&1]);
      float ogA = fsig32(riAf*accA[(j*4+3)>>1][(j*4+3)&1]);
      cA[j] = (double)fgA*cA[j] + (double)(igA*ggA);
      float hA = ogA*ftanh32((float)cA[j]);
      hpA[j] = hA;
      s1A += hA; s2A += hA*hA; sw0A += hA*gwf0[j]; sw1A += hA*gwf1[j];

      float igB = fsig32(riBf*accB[(j*4+0)>>1][(j*4+0)&1]);
      float fgB = fsig32(riBf*accB[(j*4+1)>>1][(j*4+1)&1]);
      float ggB = ftanh32(riBf*accB[(j*4+2)>>1][(j*4+2)&1]);
      float ogB = fsig32(riBf*accB[(j*4+3)>>1][(j*4+3)&1]);
      cB[j] = (double)fgB*cB[j] + (double)(igB*ggB);
      float hB = ogB*ftanh32((float)cB[j]);
      hpB2[j] = hB;
      s1B += hB; s2B += hB*hB; sw0B += hB*gwf0[j]; sw1B += hB*gwf1[j];
    }
    __syncthreads();
    #pragma unroll
    for (int j = 0; j < 10; ++j){
      hd[(ub+j)*128 + lane]      = hpA[j];
      hd[(ub+j)*128 + 64 + lane] = hpB2[j];
    }
    ps[wv*128 + lane] = s1A;  ps[wv*128 + 64 + lane] = s1B;
    pq[wv*128 + lane] = s2A;  pq[wv*128 + 64 + lane] = s2B;
    pw0[wv*128 + lane] = sw0A; pw0[wv*128 + 64 + lane] = sw0B;
    pw1[wv*128 + lane] = sw1A; pw1[wv*128 + 64 + lane] = sw1B;
    __syncthreads();
    double saA = 0, sqA = 0, t0A = 0, t1A = 0;
    double saB = 0, sqB = 0, t0B = 0, t1B = 0;
    #pragma unroll
    for (int w = 0; w < 8; ++w){
      saA += (double)ps[w*128 + lane];      sqA += (double)pq[w*128 + lane];
      t0A += (double)pw0[w*128 + lane];     t1A += (double)pw1[w*128 + lane];
      saB += (double)ps[w*128 + 64 + lane]; sqB += (double)pq[w*128 + 64 + lane];
      t0B += (double)pw0[w*128 + 64 + lane];t1B += (double)pw1[w*128 + 64 + lane];
    }
    muA = saA*(1.0/80.0);
    double vaA = sqA*(1.0/80.0) - muA*muA;
    riA = fast_rsqrt(vaA + EPS); invriA = (vaA + EPS)*riA;
    x0A = riA*__builtin_fma(-muA, Cgw0, t0A) + Cbw0;
    x1A = riA*__builtin_fma(-muA, Cgw1, t1A) + Cbw1;
    muB = saB*(1.0/80.0);
    double vaB = sqB*(1.0/80.0) - muB*muB;
    riB = fast_rsqrt(vaB + EPS); invriB = (vaB + EPS)*riB;
    x0B = riB*__builtin_fma(-muB, Cgw0, t0B) + Cbw0;
    x1B = riB*__builtin_fma(-muB, Cgw1, t1B) + Cbw1;
    if (wv == 0){
      out[((size_t)t*NTOT + pedA)*2 + 0] = (float)x0A;
      out[((size_t)t*NTOT + pedA)*2 + 1] = (float)x1A;
    } else if (wv == 1){
      out[((size_t)t*NTOT + pedB)*2 + 0] = (float)x0B;
      out[((size_t)t*NTOT + pedB)*2 + 1] = (float)x1B;
    }
  }
}

extern "C" void kernel_launch(void* const* d_in, const int* in_sizes, int n_in,
                              void* d_out, int out_size, void* d_ws, size_t ws_size,
                              hipStream_t stream)
{
  const float* obs   = (const float*)d_in[0];
  const float* zn    = (const float*)d_in[2];
  const float* th0   = (const float*)d_in[3];
  const float* tc0   = (const float*)d_in[4];
  const float* gh0   = (const float*)d_in[5];
  const float* gc0   = (const float*)d_in[6];
  const float* gw0   = (const float*)d_in[7];
  const float* gas0  = (const float*)d_in[8];
  const float* gad0  = (const float*)d_in[9];
  const float* gb0   = (const float*)d_in[10];
  const float* gw1   = (const float*)d_in[11];
  const float* gas1  = (const float*)d_in[12];
  const float* gad1  = (const float*)d_in[13];
  const float* gb1   = (const float*)d_in[14];
  const float* twih  = (const float*)d_in[15];
  const float* twhh  = (const float*)d_in[16];
  const float* tbih  = (const float*)d_in[17];
  const float* tbhh  = (const float*)d_in[18];
  const float* gwih  = (const float*)d_in[19];
  const float* gwhh  = (const float*)d_in[20];
  const float* gbih  = (const float*)d_in[21];
  const float* gbhh  = (const float*)d_in[22];
  const float* glng  = (const float*)d_in[23];
  const float* glnb  = (const float*)d_in[24];
  const float* pwih  = (const float*)d_in[25];
  const float* pwhh  = (const float*)d_in[26];
  const float* pbih  = (const float*)d_in[27];
  const float* pbhh  = (const float*)d_in[28];
  const float* plng  = (const float*)d_in[29];
  const float* plnb  = (const float*)d_in[30];
  const float* poww  = (const float*)d_in[31];
  const float* pob   = (const float*)d_in[32];
  const float* als   = (const float*)d_in[33];

  float* out = (float*)d_out;
  double* wsd = (double*)d_ws;
  float* wsf = (float*)(wsd + D_TOTAL);             // fp32 region
  float* traj_hs = wsf + F_TOTAL;                   // [8][NTOT][32]
  float* gin     = traj_hs + (size_t)8*NTOT*32;     // [8][NSC][32][64]
  float* gh      = gin + (size_t)8*NTOT*32;         // [NTOT][32]

  (void)hipFuncSetAttribute((const void*)k_pred,
                            hipFuncAttributeMaxDynamicSharedMemorySize,
                            PRED_LDS_BYTES);

  k_prep<<<dim3(104), dim3(256), 0, stream>>>(
      pwhh, pwih, pbih, pbhh, plng, plnb, poww, pob,
      twih, twhh, tbih, tbhh, gwih, gwhh, gbih, gbhh, glng, glnb,
      gw0, gas0, gad0, gb0, gw1, gas1, gad1, gb1, wsd, wsf);
  k_traj<<<dim3(512), dim3(256), 0, stream>>>(obs, th0, tc0, wsd, wsf, traj_hs);
  k_gat<<<dim3(4096), dim3(256), 0, stream>>>(traj_hs, wsd, wsf, gin);
  k_graph<<<dim3(512), dim3(256), 0, stream>>>(gin, gh0, gc0, wsd, wsf, gh);
  k_pred<<<dim3(256), dim3(512), PRED_LDS_BYTES, stream>>>(traj_hs, gh, zn, obs, wsd, wsf, als, out);
}